// Round 7
// baseline (404.842 us; speedup 1.0000x reference)
//
#include <hip/hip_runtime.h>
#include <math.h>

#define T_LEN 256
#define BATCH 32
#define HID   768
#define GH    384   // 3*LSTM_H
#define LH    128   // LSTM_H
#define NLAB  9
#define M_TOT (T_LEN*BATCH)  // 8192

typedef float v2f __attribute__((ext_vector_type(2)));
typedef _Float16 h8 __attribute__((ext_vector_type(8)));
typedef float f4 __attribute__((ext_vector_type(4)));

#define LO_SCALE 1024.f
#define LO_INV   (1.f/1024.f)

// Immediate-pattern lane broadcast within 32-lane half: every lane reads lane i.
#define BC(x, i) __int_as_float(__builtin_amdgcn_ds_swizzle(__float_as_int(x), (i) << 5))

// Raw barrier with LDS-only drain (no vmcnt stall on in-flight prefetch/stores).
#define BAR_LGKM() do {                                   \
    asm volatile("s_waitcnt lgkmcnt(0)" ::: "memory");    \
    __builtin_amdgcn_s_barrier();                         \
    asm volatile("" ::: "memory");                        \
  } while (0)

// ---------------- K1: xp = emb[ids] @ [Wih_f;Wih_b]^T + bias  (MFMA v6) -----
__global__ __launch_bounds__(256, 2) void k_gemm_xp(
    const int* __restrict__ ids, const float* __restrict__ emb,
    const float* __restrict__ Wf, const float* __restrict__ Wb,
    const float* __restrict__ bihf, const float* __restrict__ bihb,
    float* __restrict__ xp)
{
  __shared__ __align__(16) _Float16 Ah[128*40];
  __shared__ __align__(16) _Float16 Al[128*40];
  __shared__ __align__(16) _Float16 Bh[128*40];
  __shared__ __align__(16) _Float16 Bl[128*40];

  const int tid  = threadIdx.x;
  const int lane = tid & 63, w = tid >> 6;
  const int m0 = blockIdx.y * 128, n0 = blockIdx.x * 128;

  const int srow = tid >> 1, sk = (tid & 1) * 16;
  const int gm = m0 + srow;
  const int tok = ids[(gm & 31) * T_LEN + (gm >> 5)];
  const float* aG = emb + (size_t)tok * HID + sk;
  const int gn = n0 + srow;
  const float* bG = (gn < GH ? Wf + (size_t)gn * HID
                             : Wb + (size_t)(gn - GH) * HID) + sk;

  const int fr = lane & 15, fq = lane >> 4;
  const int mrow = (w & 1) * 64;
  const int ncol = (w >> 1) * 64;

  f4 acc[4][4];
  f4 acc2[4][4];
#pragma unroll
  for (int i = 0; i < 4; ++i)
#pragma unroll
    for (int j = 0; j < 4; ++j) { acc[i][j] = f4{0,0,0,0}; acc2[i][j] = f4{0,0,0,0}; }

  const int sb = srow * 40 + sk;

  float4 ra[4], rb[4];
#pragma unroll
  for (int c = 0; c < 4; ++c) {
    ra[c] = *reinterpret_cast<const float4*>(aG + 4 * c);
    rb[c] = *reinterpret_cast<const float4*>(bG + 4 * c);
  }

  for (int kt = 0; kt < HID / 32; ++kt) {
    BAR_LGKM();
#pragma unroll
    for (int m = 0; m < 2; ++m) {
      const float4* src = m ? rb : ra;
      _Float16* dsth = m ? Bh : Ah;
      _Float16* dstl = m ? Bl : Al;
#pragma unroll
      for (int seg = 0; seg < 2; ++seg) {
        float xs[8] = {src[2*seg].x, src[2*seg].y, src[2*seg].z, src[2*seg].w,
                       src[2*seg+1].x, src[2*seg+1].y, src[2*seg+1].z, src[2*seg+1].w};
        h8 hi, lo;
#pragma unroll
        for (int c = 0; c < 8; ++c) {
          _Float16 h = (_Float16)xs[c];
          hi[c] = h;
          lo[c] = (_Float16)((xs[c] - (float)h) * LO_SCALE);
        }
        *reinterpret_cast<h8*>(&dsth[sb + seg * 8]) = hi;
        *reinterpret_cast<h8*>(&dstl[sb + seg * 8]) = lo;
      }
    }
    if (kt + 1 < HID / 32) {
      const float* pa = aG + (kt + 1) * 32;
      const float* pb = bG + (kt + 1) * 32;
#pragma unroll
      for (int c = 0; c < 4; ++c) {
        ra[c] = *reinterpret_cast<const float4*>(pa + 4 * c);
        rb[c] = *reinterpret_cast<const float4*>(pb + 4 * c);
      }
    }
    BAR_LGKM();

    h8 fbh[4], fbl[4];
#pragma unroll
    for (int j = 0; j < 4; ++j) {
      const int off = (ncol + j * 16 + fr) * 40 + fq * 8;
      fbh[j] = *reinterpret_cast<const h8*>(&Bh[off]);
      fbl[j] = *reinterpret_cast<const h8*>(&Bl[off]);
    }
#pragma unroll
    for (int i = 0; i < 4; ++i) {
      const int off = (mrow + i * 16 + fr) * 40 + fq * 8;
      h8 fah = *reinterpret_cast<const h8*>(&Ah[off]);
      h8 fal = *reinterpret_cast<const h8*>(&Al[off]);
#pragma unroll
      for (int j = 0; j < 4; ++j) {
        acc[i][j]  = __builtin_amdgcn_mfma_f32_16x16x32_f16(fah, fbh[j], acc[i][j],  0, 0, 0);
        acc2[i][j] = __builtin_amdgcn_mfma_f32_16x16x32_f16(fah, fbl[j], acc2[i][j], 0, 0, 0);
        acc2[i][j] = __builtin_amdgcn_mfma_f32_16x16x32_f16(fal, fbh[j], acc2[i][j], 0, 0, 0);
      }
    }
  }

  float bcol[4];
#pragma unroll
  for (int j = 0; j < 4; ++j) {
    const int c = n0 + ncol + j * 16 + fr;
    bcol[j] = (c < GH) ? bihf[c] : bihb[c - GH];
  }
#pragma unroll
  for (int i = 0; i < 4; ++i)
#pragma unroll
    for (int j = 0; j < 4; ++j) {
      const int col = n0 + ncol + j * 16 + fr;
#pragma unroll
      for (int r = 0; r < 4; ++r) {
        const int row = m0 + mrow + i * 16 + fq * 4 + r;
        xp[(size_t)row * HID + col] = acc[i][j][r] + acc2[i][j][r] * LO_INV + bcol[j];
      }
    }
}

// ---------------- K2: bidirectional GRU recurrence (v10 — 2-deep prefetch) --
// Round-6 falsified the AGPR-shuttle theory: zero-shuttle asm = 160µs vs v4's
// 151µs. Both structures pin at ~1450-1500 cy/step while VALU+LDS work is only
// ~500-600 cy. The shared binding constraint: x(t) was global-loaded only
// ~0.6 step before consumption; scattered 4B loads have 500-900cy latency, so
// steady state forces step >= latency/0.6 ~= 1500cy — matching measurement.
// v10: parity-unrolled loop with TWO-step x prefetch. Each body consumes one
// trio (even: v104-106, odd: v107-109) and issues loads for t+2 into the trio
// it just consumed -> ~1.9-step window >> latency.
// vmcnt discipline: every body issues exactly 3 loads + 1 store (pointer
// advance is guarded in the last 2 steps, loads still issue at a stale but
// in-bounds address) -> vmcnt(4) at body top proves the 2-step-old trio
// arrived; prologue primes both trios, waits vmcnt(3) (covers weights + E).
__global__ __attribute__((amdgpu_flat_work_group_size(512, 512),
                          amdgpu_waves_per_eu(2, 2)))
void k_gru(
    const float* __restrict__ xp,
    const float* __restrict__ Whhf, const float* __restrict__ Whhb,
    const float* __restrict__ bhhf, const float* __restrict__ bhhb,
    float* __restrict__ hbuf, float* __restrict__ lossp)
{
  __shared__ __align__(1024) float hsp[2][256];
  const int tid = threadIdx.x;
  const int g   = tid >> 2;       // hidden unit 0..127
  const int q   = tid & 3;        // 32-elem segment 0..3
  const int bd  = blockIdx.x;
  const int dir = bd >> 5, b = bd & 31;
  const float* Whh = dir ? Whhb : Whhf;
  const float* bhh = dir ? bhhb : bhhf;

  if (bd == 0 && tid == 0) *lossp = 0.f;

  const float br = bhh[g], bz = bhh[g + LH], bn = bhh[g + 2*LH];
  const float* wg0 = Whh + (size_t)(0*LH + g) * LH + q * 32;
  const float* wg1 = Whh + (size_t)(1*LH + g) * LH + q * 32;
  const float* wg2 = Whh + (size_t)(2*LH + g) * LH + q * 32;

  const int t0 = dir ? (T_LEN - 1) : 0;
  const int dt = dir ? -1 : 1;
  const float* px = xp + (size_t)t0 * BATCH * HID + b * HID + dir * GH + g;
  float*       ph = hbuf + (size_t)t0 * BATCH * 256 + b * 256 + dir * LH + g;

  const long long xs = (long long)dt * BATCH * HID * 4;   // xp t-stride, bytes
  const long long hs = (long long)dt * BATCH * 256 * 4;   // hbuf t-stride, bytes
  const unsigned xslo = (unsigned)(xs & 0xffffffffll);
  const int      xshi = (int)(xs >> 32);
  const unsigned hslo = (unsigned)(hs & 0xffffffffll);
  const int      hshi = (int)(hs >> 32);
  const unsigned xlo = (unsigned)(uintptr_t)px, xhi = (unsigned)((uintptr_t)px >> 32);
  const unsigned hlo = (unsigned)(uintptr_t)ph, hhi = (unsigned)((uintptr_t)ph >> 32);
  // generic AS0 shared pointers: low 32 bits = LDS byte offset
  const unsigned rd0 = (unsigned)(uintptr_t)(&hsp[0][36 * q]);
  const unsigned wr0 = (unsigned)(uintptr_t)(&hsp[1][36 * (g >> 5) + (g & 31)]);

  if (tid < LH) hsp[0][36 * (tid >> 5) + (tid & 31)] = 0.f;
  BAR_LGKM();

// One recurrence step. XA0/XA1/XA2 = the x-trio consumed this step; the same
// trio is reloaded (for t+2) after its last read. 3 loads + 1 store per body,
// always, keeping vmcnt accounting uniform.
#define GRU_BODY(XA0, XA1, XA2) \
    "s_waitcnt vmcnt(4)\n\t" \
    "ds_read_b128 v[224:227], v100\n\t" \
    "ds_read_b128 v[228:231], v100 offset:16\n\t" \
    "ds_read_b128 v[232:235], v100 offset:32\n\t" \
    "ds_read_b128 v[236:239], v100 offset:48\n\t" \
    "ds_read_b128 v[240:243], v100 offset:64\n\t" \
    "ds_read_b128 v[244:247], v100 offset:80\n\t" \
    "ds_read_b128 v[248:251], v100 offset:96\n\t" \
    "ds_read_b128 v[252:255], v100 offset:112\n\t" \
    "s_waitcnt lgkmcnt(0)\n\t" \
    "v_pk_mul_f32 v[116:117], v[128:129], v[224:225]\n\t" \
    "v_pk_mul_f32 v[118:119], v[130:131], v[226:227]\n\t" \
    "v_pk_fma_f32 v[116:117], v[132:133], v[228:229], v[116:117]\n\t" \
    "v_pk_fma_f32 v[118:119], v[134:135], v[230:231], v[118:119]\n\t" \
    "v_pk_fma_f32 v[116:117], v[136:137], v[232:233], v[116:117]\n\t" \
    "v_pk_fma_f32 v[118:119], v[138:139], v[234:235], v[118:119]\n\t" \
    "v_pk_fma_f32 v[116:117], v[140:141], v[236:237], v[116:117]\n\t" \
    "v_pk_fma_f32 v[118:119], v[142:143], v[238:239], v[118:119]\n\t" \
    "v_pk_fma_f32 v[116:117], v[144:145], v[240:241], v[116:117]\n\t" \
    "v_pk_fma_f32 v[118:119], v[146:147], v[242:243], v[118:119]\n\t" \
    "v_pk_fma_f32 v[116:117], v[148:149], v[244:245], v[116:117]\n\t" \
    "v_pk_fma_f32 v[118:119], v[150:151], v[246:247], v[118:119]\n\t" \
    "v_pk_fma_f32 v[116:117], v[152:153], v[248:249], v[116:117]\n\t" \
    "v_pk_fma_f32 v[118:119], v[154:155], v[250:251], v[118:119]\n\t" \
    "v_pk_fma_f32 v[116:117], v[156:157], v[252:253], v[116:117]\n\t" \
    "v_pk_fma_f32 v[118:119], v[158:159], v[254:255], v[118:119]\n\t" \
    "v_pk_mul_f32 v[120:121], v[160:161], v[224:225]\n\t" \
    "v_pk_mul_f32 v[122:123], v[162:163], v[226:227]\n\t" \
    "v_pk_fma_f32 v[120:121], v[164:165], v[228:229], v[120:121]\n\t" \
    "v_pk_fma_f32 v[122:123], v[166:167], v[230:231], v[122:123]\n\t" \
    "v_pk_fma_f32 v[120:121], v[168:169], v[232:233], v[120:121]\n\t" \
    "v_pk_fma_f32 v[122:123], v[170:171], v[234:235], v[122:123]\n\t" \
    "v_pk_fma_f32 v[120:121], v[172:173], v[236:237], v[120:121]\n\t" \
    "v_pk_fma_f32 v[122:123], v[174:175], v[238:239], v[122:123]\n\t" \
    "v_pk_fma_f32 v[120:121], v[176:177], v[240:241], v[120:121]\n\t" \
    "v_pk_fma_f32 v[122:123], v[178:179], v[242:243], v[122:123]\n\t" \
    "v_pk_fma_f32 v[120:121], v[180:181], v[244:245], v[120:121]\n\t" \
    "v_pk_fma_f32 v[122:123], v[182:183], v[246:247], v[122:123]\n\t" \
    "v_pk_fma_f32 v[120:121], v[184:185], v[248:249], v[120:121]\n\t" \
    "v_pk_fma_f32 v[122:123], v[186:187], v[250:251], v[122:123]\n\t" \
    "v_pk_fma_f32 v[120:121], v[188:189], v[252:253], v[120:121]\n\t" \
    "v_pk_fma_f32 v[122:123], v[190:191], v[254:255], v[122:123]\n\t" \
    "v_pk_mul_f32 v[124:125], v[192:193], v[224:225]\n\t" \
    "v_pk_mul_f32 v[126:127], v[194:195], v[226:227]\n\t" \
    "v_pk_fma_f32 v[124:125], v[196:197], v[228:229], v[124:125]\n\t" \
    "v_pk_fma_f32 v[126:127], v[198:199], v[230:231], v[126:127]\n\t" \
    "v_pk_fma_f32 v[124:125], v[200:201], v[232:233], v[124:125]\n\t" \
    "v_pk_fma_f32 v[126:127], v[202:203], v[234:235], v[126:127]\n\t" \
    "v_pk_fma_f32 v[124:125], v[204:205], v[236:237], v[124:125]\n\t" \
    "v_pk_fma_f32 v[126:127], v[206:207], v[238:239], v[126:127]\n\t" \
    "v_pk_fma_f32 v[124:125], v[208:209], v[240:241], v[124:125]\n\t" \
    "v_pk_fma_f32 v[126:127], v[210:211], v[242:243], v[126:127]\n\t" \
    "v_pk_fma_f32 v[124:125], v[212:213], v[244:245], v[124:125]\n\t" \
    "v_pk_fma_f32 v[126:127], v[214:215], v[246:247], v[126:127]\n\t" \
    "v_pk_fma_f32 v[124:125], v[216:217], v[248:249], v[124:125]\n\t" \
    "v_pk_fma_f32 v[126:127], v[218:219], v[250:251], v[126:127]\n\t" \
    "v_pk_fma_f32 v[124:125], v[220:221], v[252:253], v[124:125]\n\t" \
    "v_pk_fma_f32 v[126:127], v[222:223], v[254:255], v[126:127]\n\t" \
    "v_add_f32 v116, v116, v117\n\t" \
    "v_add_f32 v118, v118, v119\n\t" \
    "v_add_f32 v116, v116, v118\n\t" \
    "v_add_f32 v120, v120, v121\n\t" \
    "v_add_f32 v122, v122, v123\n\t" \
    "v_add_f32 v120, v120, v122\n\t" \
    "v_add_f32 v124, v124, v125\n\t" \
    "v_add_f32 v126, v126, v127\n\t" \
    "v_add_f32 v124, v124, v126\n\t" \
    "ds_swizzle_b32 v111, v116 offset:0x041F\n\t" \
    "ds_swizzle_b32 v112, v120 offset:0x041F\n\t" \
    "ds_swizzle_b32 v113, v124 offset:0x041F\n\t" \
    "s_waitcnt lgkmcnt(0)\n\t" \
    "v_add_f32 v116, v116, v111\n\t" \
    "v_add_f32 v120, v120, v112\n\t" \
    "v_add_f32 v124, v124, v113\n\t" \
    "ds_swizzle_b32 v111, v116 offset:0x081F\n\t" \
    "ds_swizzle_b32 v112, v120 offset:0x081F\n\t" \
    "ds_swizzle_b32 v113, v124 offset:0x081F\n\t" \
    "s_waitcnt lgkmcnt(0)\n\t" \
    "v_add_f32 v116, v116, v111\n\t" \
    "v_add_f32 v120, v120, v112\n\t" \
    "v_add_f32 v124, v124, v113\n\t" \
    "v_add_f32 v111, " XA0 ", v116\n\t" \
    "v_add_f32 v112, " XA1 ", v120\n\t" \
    "v_add_f32 v113, v124, %[bn]\n\t" \
    "v_add_f32 v111, v111, %[br]\n\t" \
    "v_add_f32 v112, v112, %[bz]\n\t" \
    "v_mul_f32 v111, 0xbfb8aa3b, v111\n\t" \
    "v_mul_f32 v112, 0xbfb8aa3b, v112\n\t" \
    "v_exp_f32 v111, v111\n\t" \
    "v_exp_f32 v112, v112\n\t" \
    "s_nop 0\n\t" \
    "v_add_f32 v111, 1.0, v111\n\t" \
    "v_add_f32 v112, 1.0, v112\n\t" \
    "v_rcp_f32 v111, v111\n\t" \
    "v_rcp_f32 v112, v112\n\t" \
    "s_nop 0\n\t" \
    "v_fmac_f32 " XA2 ", v111, v113\n\t" \
    "v_mul_f32 v113, 0x4038aa3b, " XA2 "\n\t" \
    "v_exp_f32 v113, v113\n\t" \
    "v_sub_f32 v115, 1.0, v112\n\t" \
    "s_nop 0\n\t" \
    "v_add_f32 v114, -1.0, v113\n\t" \
    "v_add_f32 v113, 1.0, v113\n\t" \
    "v_rcp_f32 v113, v113\n\t" \
    "s_nop 1\n\t" \
    "v_mul_f32 v114, v114, v113\n\t" \
    "v_mul_f32 v115, v115, v114\n\t" \
    "v_fmac_f32 v115, v112, v110\n\t" \
    "v_mov_b32 v110, v115\n\t" \
    "s_cmp_gt_u32 %[cnt], 2\n\t" \
    "s_cbranch_scc0 3f\n\t" \
    "v_add_co_u32 v96, vcc, %[xslo], v96\n\t" \
    "v_addc_co_u32 v97, vcc, %[xshi], v97, vcc\n\t" \
    "3:\n\t" \
    "global_load_dword " XA0 ", v[96:97], off\n\t" \
    "global_load_dword " XA1 ", v[96:97], off offset:512\n\t" \
    "global_load_dword " XA2 ", v[96:97], off offset:1024\n\t" \
    "ds_write_b32 v101, v115\n\t" \
    "global_store_dword v[98:99], v115, off\n\t" \
    "v_add_co_u32 v98, vcc, %[hslo], v98\n\t" \
    "v_addc_co_u32 v99, vcc, %[hshi], v99, vcc\n\t" \
    "v_xor_b32 v100, 0x400, v100\n\t" \
    "v_xor_b32 v101, 0x400, v101\n\t" \
    "s_waitcnt lgkmcnt(0)\n\t" \
    "s_barrier\n\t" \
    "s_sub_u32 %[cnt], %[cnt], 1\n\t"

  int cnt = T_LEN;
  asm volatile(
    // ---- prologue: weights -> v[128:223]; prime x(t0)->E, x(t1)->O ----
    "global_load_dwordx4 v[128:131], %[wg0], off\n\t"
    "global_load_dwordx4 v[132:135], %[wg0], off offset:16\n\t"
    "global_load_dwordx4 v[136:139], %[wg0], off offset:32\n\t"
    "global_load_dwordx4 v[140:143], %[wg0], off offset:48\n\t"
    "global_load_dwordx4 v[144:147], %[wg0], off offset:64\n\t"
    "global_load_dwordx4 v[148:151], %[wg0], off offset:80\n\t"
    "global_load_dwordx4 v[152:155], %[wg0], off offset:96\n\t"
    "global_load_dwordx4 v[156:159], %[wg0], off offset:112\n\t"
    "global_load_dwordx4 v[160:163], %[wg1], off\n\t"
    "global_load_dwordx4 v[164:167], %[wg1], off offset:16\n\t"
    "global_load_dwordx4 v[168:171], %[wg1], off offset:32\n\t"
    "global_load_dwordx4 v[172:175], %[wg1], off offset:48\n\t"
    "global_load_dwordx4 v[176:179], %[wg1], off offset:64\n\t"
    "global_load_dwordx4 v[180:183], %[wg1], off offset:80\n\t"
    "global_load_dwordx4 v[184:187], %[wg1], off offset:96\n\t"
    "global_load_dwordx4 v[188:191], %[wg1], off offset:112\n\t"
    "global_load_dwordx4 v[192:195], %[wg2], off\n\t"
    "global_load_dwordx4 v[196:199], %[wg2], off offset:16\n\t"
    "global_load_dwordx4 v[200:203], %[wg2], off offset:32\n\t"
    "global_load_dwordx4 v[204:207], %[wg2], off offset:48\n\t"
    "global_load_dwordx4 v[208:211], %[wg2], off offset:64\n\t"
    "global_load_dwordx4 v[212:215], %[wg2], off offset:80\n\t"
    "global_load_dwordx4 v[216:219], %[wg2], off offset:96\n\t"
    "global_load_dwordx4 v[220:223], %[wg2], off offset:112\n\t"
    "v_mov_b32 v96, %[xlo]\n\t"
    "v_mov_b32 v97, %[xhi]\n\t"
    "v_mov_b32 v98, %[hlo]\n\t"
    "v_mov_b32 v99, %[hhi]\n\t"
    "v_mov_b32 v100, %[rd0]\n\t"
    "v_mov_b32 v101, %[wr0]\n\t"
    "global_load_dword v104, v[96:97], off\n\t"
    "global_load_dword v105, v[96:97], off offset:512\n\t"
    "global_load_dword v106, v[96:97], off offset:1024\n\t"
    "v_add_co_u32 v96, vcc, %[xslo], v96\n\t"
    "v_addc_co_u32 v97, vcc, %[xshi], v97, vcc\n\t"
    "global_load_dword v107, v[96:97], off\n\t"
    "global_load_dword v108, v[96:97], off offset:512\n\t"
    "global_load_dword v109, v[96:97], off offset:1024\n\t"
    "v_mov_b32 v110, 0\n\t"
    "s_waitcnt vmcnt(3)\n\t"            // weights + E trio arrived; O may fly
    // ---- main loop: 128 iterations of (even, odd) step pair ----
    "0:\n\t"
    GRU_BODY("v104", "v105", "v106")
    GRU_BODY("v107", "v108", "v109")
    "s_cmp_lg_u32 %[cnt], 0\n\t"
    "s_cbranch_scc1 0b\n\t"
    : [cnt]"+s"(cnt)
    : [wg0]"v"(wg0), [wg1]"v"(wg1), [wg2]"v"(wg2),
      [xlo]"v"(xlo), [xhi]"v"(xhi), [hlo]"v"(hlo), [hhi]"v"(hhi),
      [rd0]"v"(rd0), [wr0]"v"(wr0),
      [br]"v"(br), [bz]"v"(bz), [bn]"v"(bn),
      [xslo]"s"(xslo), [xshi]"v"(xshi), [hslo]"s"(hslo), [hshi]"v"(hshi)
    : "memory", "vcc", "scc",
      "v96","v97","v98","v99","v100","v101","v102","v103","v104","v105",
      "v106","v107","v108","v109","v110","v111","v112","v113","v114","v115",
      "v116","v117","v118","v119","v120","v121","v122","v123","v124","v125",
      "v126","v127","v128","v129","v130","v131","v132","v133","v134","v135",
      "v136","v137","v138","v139","v140","v141","v142","v143","v144","v145",
      "v146","v147","v148","v149","v150","v151","v152","v153","v154","v155",
      "v156","v157","v158","v159","v160","v161","v162","v163","v164","v165",
      "v166","v167","v168","v169","v170","v171","v172","v173","v174","v175",
      "v176","v177","v178","v179","v180","v181","v182","v183","v184","v185",
      "v186","v187","v188","v189","v190","v191","v192","v193","v194","v195",
      "v196","v197","v198","v199","v200","v201","v202","v203","v204","v205",
      "v206","v207","v208","v209","v210","v211","v212","v213","v214","v215",
      "v216","v217","v218","v219","v220","v221","v222","v223","v224","v225",
      "v226","v227","v228","v229","v230","v231","v232","v233","v234","v235",
      "v236","v237","v238","v239","v240","v241","v242","v243","v244","v245",
      "v246","v247","v248","v249","v250","v251","v252","v253","v254","v255");
#undef GRU_BODY
}

// ---------------- K3: fused emissions + Viterbi + CRF-LLH (v2) --------------
__global__ __launch_bounds__(256, 1) void k_crf_fused(
    const float* __restrict__ hbuf, const float* __restrict__ Wlin,
    const float* __restrict__ blin, const int* __restrict__ labels,
    const float* __restrict__ trans, const float* __restrict__ start,
    const float* __restrict__ endv, float* __restrict__ dec_out,
    float* __restrict__ lossp)
{
  __shared__ float el[T_LEN * 10];
  __shared__ __align__(16) unsigned char bp8[(T_LEN - 1) * 16];
  const int b    = blockIdx.x;
  const int tid  = threadIdx.x;
  const int lane = tid & 63, w = tid >> 6;
  const int sub  = lane >> 4, l16 = lane & 15;

  float4 wreg[NLAB][4];
#pragma unroll
  for (int j = 0; j < NLAB; ++j)
#pragma unroll
    for (int c = 0; c < 4; ++c)
      wreg[j][c] = *reinterpret_cast<const float4*>(Wlin + j * 256 + l16 * 16 + c * 4);

  // ---- phase 1: emissions ----
  for (int k = 0; k < 16; ++k) {
    const int t = w * 64 + k * 4 + sub;
    const float* hp = hbuf + ((size_t)t * BATCH + b) * 256 + l16 * 16;
    const float4 h0 = *reinterpret_cast<const float4*>(hp);
    const float4 h1 = *reinterpret_cast<const float4*>(hp + 4);
    const float4 h2 = *reinterpret_cast<const float4*>(hp + 8);
    const float4 h3 = *reinterpret_cast<const float4*>(hp + 12);
    float acc[NLAB];
#pragma unroll
    for (int j = 0; j < NLAB; ++j) {
      const float4 w0 = wreg[j][0], w1 = wreg[j][1], w2 = wreg[j][2], w3 = wreg[j][3];
      float s0 = h0.x*w0.x + h0.y*w0.y + h0.z*w0.z + h0.w*w0.w;
      float s1 = h1.x*w1.x + h1.y*w1.y + h1.z*w1.z + h1.w*w1.w;
      float s2 = h2.x*w2.x + h2.y*w2.y + h2.z*w2.z + h2.w*w2.w;
      float s3 = h3.x*w3.x + h3.y*w3.y + h3.z*w3.z + h3.w*w3.w;
      acc[j] = (s0 + s1) + (s2 + s3);
    }
#pragma unroll
    for (int j = 0; j < NLAB; ++j) {
#pragma unroll
      for (int off = 1; off < 16; off <<= 1)
        acc[j] += __shfl_xor(acc[j], off);
    }
    if (l16 < NLAB) {
      float v = acc[0];
#pragma unroll
      for (int j = 1; j < NLAB; ++j) v = (l16 == j) ? acc[j] : v;
      el[t * 10 + l16] = v + blin[l16];
    }
  }
  __syncthreads();

  if (w == 0) {
    // ---- Viterbi ----
    float tcol[NLAB];
#pragma unroll
    for (int i = 0; i < NLAB; ++i)
      tcol[i] = (lane < NLAB) ? trans[i * NLAB + lane] : 0.f;
    float alpha = (lane < NLAB) ? (start[lane] + el[lane]) : -3e38f;
    float et_next = (lane < NLAB) ? el[10 + lane] : 0.f;
    for (int s = 0; s < T_LEN - 1; ++s) {
      const float et = et_next;
      if (s < T_LEN - 2)
        et_next = (lane < NLAB) ? el[(s + 2) * 10 + lane] : 0.f;
      float v[NLAB];
      v[0] = BC(alpha, 0) + tcol[0];
      v[1] = BC(alpha, 1) + tcol[1];
      v[2] = BC(alpha, 2) + tcol[2];
      v[3] = BC(alpha, 3) + tcol[3];
      v[4] = BC(alpha, 4) + tcol[4];
      v[5] = BC(alpha, 5) + tcol[5];
      v[6] = BC(alpha, 6) + tcol[6];
      v[7] = BC(alpha, 7) + tcol[7];
      v[8] = BC(alpha, 8) + tcol[8];
      float v01 = (v[0] >= v[1]) ? v[0] : v[1];  int i01 = (v[0] >= v[1]) ? 0 : 1;
      float v23 = (v[2] >= v[3]) ? v[2] : v[3];  int i23 = (v[2] >= v[3]) ? 2 : 3;
      float v45 = (v[4] >= v[5]) ? v[4] : v[5];  int i45 = (v[4] >= v[5]) ? 4 : 5;
      float v67 = (v[6] >= v[7]) ? v[6] : v[7];  int i67 = (v[6] >= v[7]) ? 6 : 7;
      float va = (v01 >= v23) ? v01 : v23;       int ia = (v01 >= v23) ? i01 : i23;
      float vb = (v45 >= v67) ? v45 : v67;       int ib = (v45 >= v67) ? i45 : i67;
      float vc = (va >= vb) ? va : vb;           int ic = (va >= vb) ? ia : ib;
      float best = (vc >= v[8]) ? vc : v[8];     int bi = (vc >= v[8]) ? ic : 8;
      alpha = best + et;
      if (lane < NLAB) bp8[s * 16 + lane] = (unsigned char)bi;
    }
    float fin = alpha + ((lane < NLAB) ? endv[lane] : 0.f);
    float fv[NLAB];
    fv[0] = BC(fin, 0); fv[1] = BC(fin, 1); fv[2] = BC(fin, 2);
    fv[3] = BC(fin, 3); fv[4] = BC(fin, 4); fv[5] = BC(fin, 5);
    fv[6] = BC(fin, 6); fv[7] = BC(fin, 7); fv[8] = BC(fin, 8);
    float f01 = (fv[0] >= fv[1]) ? fv[0] : fv[1];  int j01 = (fv[0] >= fv[1]) ? 0 : 1;
    float f23 = (fv[2] >= fv[3]) ? fv[2] : fv[3];  int j23 = (fv[2] >= fv[3]) ? 2 : 3;
    float f45 = (fv[4] >= fv[5]) ? fv[4] : fv[5];  int j45 = (fv[4] >= fv[5]) ? 4 : 5;
    float f67 = (fv[6] >= fv[7]) ? fv[6] : fv[7];  int j67 = (fv[6] >= fv[7]) ? 6 : 7;
    float fa = (f01 >= f23) ? f01 : f23;           int ja = (f01 >= f23) ? j01 : j23;
    float fb = (f45 >= f67) ? f45 : f67;           int jb = (f45 >= f67) ? j45 : j67;
    float fc = (fa >= fb) ? fa : fb;               int jc = (fa >= fb) ? ja : jb;
    int last = (fc >= fv[8]) ? jc : 8;
    if (lane == 0) {
      int y = last;
      dec_out[b * T_LEN + (T_LEN - 1)] = (float)y;
      uint4 row = *reinterpret_cast<const uint4*>(&bp8[(T_LEN - 2) * 16]);
      for (int s = T_LEN - 2; s >= 0; --s) {
        uint4 nrow = row;
        if (s > 0) nrow = *reinterpret_cast<const uint4*>(&bp8[(s - 1) * 16]);
        unsigned wsel = (y < 4) ? row.x : ((y < 8) ? row.y : row.z);
        y = (int)((wsel >> ((y & 3) * 8)) & 0xffu);
        dec_out[b * T_LEN + s] = (float)y;
        row = nrow;
      }
    }
  } else if (w == 1) {
    // ---- CRF log-likelihood ----
    float tcol[NLAB];
#pragma unroll
    for (int i = 0; i < NLAB; ++i)
      tcol[i] = (lane < NLAB) ? trans[i * NLAB + lane] : 0.f;
    float ca = (lane < NLAB) ? (start[lane] + el[lane]) : -3e38f;
    float et_next = (lane < NLAB) ? el[10 + lane] : 0.f;
    for (int s = 0; s < T_LEN - 1; ++s) {
      const float et = et_next;
      if (s < T_LEN - 2)
        et_next = (lane < NLAB) ? el[(s + 2) * 10 + lane] : 0.f;
      float c[NLAB];
      c[0] = BC(ca, 0) + tcol[0];
      c[1] = BC(ca, 1) + tcol[1];
      c[2] = BC(ca, 2) + tcol[2];
      c[3] = BC(ca, 3) + tcol[3];
      c[4] = BC(ca, 4) + tcol[4];
      c[5] = BC(ca, 5) + tcol[5];
      c[6] = BC(ca, 6) + tcol[6];
      c[7] = BC(ca, 7) + tcol[7];
      c[8] = BC(ca, 8) + tcol[8];
      float m01 = fmaxf(c[0], c[1]), m23 = fmaxf(c[2], c[3]);
      float m45 = fmaxf(c[4], c[5]), m67 = fmaxf(c[6], c[7]);
      float m = fmaxf(fmaxf(fmaxf(m01, m23), fmaxf(m45, m67)), c[8]);
      float p0 = __expf(c[0]-m) + __expf(c[1]-m), p1 = __expf(c[2]-m) + __expf(c[3]-m);
      float p2 = __expf(c[4]-m) + __expf(c[5]-m), p3 = __expf(c[6]-m) + __expf(c[7]-m);
      float p = ((p0 + p1) + (p2 + p3)) + __expf(c[8]-m);
      ca = m + __logf(p) + et;
    }
    float fv[NLAB];
    fv[0] = BC(ca, 0) + endv[0];
    fv[1] = BC(ca, 1) + endv[1];
    fv[2] = BC(ca, 2) + endv[2];
    fv[3] = BC(ca, 3) + endv[3];
    fv[4] = BC(ca, 4) + endv[4];
    fv[5] = BC(ca, 5) + endv[5];
    fv[6] = BC(ca, 6) + endv[6];
    fv[7] = BC(ca, 7) + endv[7];
    fv[8] = BC(ca, 8) + endv[8];
    float mx = -3e38f;
#pragma unroll
    for (int j = 0; j < NLAB; ++j) mx = fmaxf(mx, fv[j]);
    float ps = 0.f;
#pragma unroll
    for (int j = 0; j < NLAB; ++j) ps += __expf(fv[j] - mx);
    float denom = mx + __logf(ps);

    const int* lb = labels + b * T_LEN;
    float part = 0.f;
    for (int t4 = 0; t4 < 4; ++t4) {
      int t = lane * 4 + t4;
      int l = lb[t];
      part += el[t * 10 + l];
      if (t > 0) part += trans[lb[t - 1] * NLAB + l];
    }
#pragma unroll
    for (int off = 32; off > 0; off >>= 1) part += __shfl_xor(part, off);
    if (lane == 0) {
      float num = part + start[lb[0]] + endv[lb[T_LEN - 1]];
      float llh = num - denom;
      atomicAdd(lossp, -llh * (1.0f / BATCH));
    }
  }
}

extern "C" void kernel_launch(void* const* d_in, const int* in_sizes, int n_in,
                              void* d_out, int out_size, void* d_ws, size_t ws_size,
                              hipStream_t stream) {
  const int*   ids    = (const int*)d_in[0];
  const int*   labels = (const int*)d_in[2];
  const float* emb    = (const float*)d_in[3];
  const float* Wihf   = (const float*)d_in[4];
  const float* Whhf   = (const float*)d_in[5];
  const float* bihf   = (const float*)d_in[6];
  const float* bhhf   = (const float*)d_in[7];
  const float* Wihb   = (const float*)d_in[8];
  const float* Whhb   = (const float*)d_in[9];
  const float* bihb   = (const float*)d_in[10];
  const float* bhhb   = (const float*)d_in[11];
  const float* Wlin   = (const float*)d_in[12];
  const float* blin   = (const float*)d_in[13];
  const float* trans  = (const float*)d_in[14];
  const float* start  = (const float*)d_in[15];
  const float* endv   = (const float*)d_in[16];

  float* xp    = (float*)d_ws;                       // [T][B][768]
  float* hbuf  = xp + (size_t)M_TOT * HID;           // [T][B][256]
  float* out   = (float*)d_out;                      // decoded as floats
  float* lossp = out + M_TOT;                        // loss scalar

  k_gemm_xp<<<dim3(6, 64), 256, 0, stream>>>(ids, emb, Wihf, Wihb, bihf, bihb, xp);
  k_gru<<<64, 512, 0, stream>>>(xp, Whhf, Whhb, bhhf, bhhb, hbuf, lossp);
  k_crf_fused<<<BATCH, 256, 0, stream>>>(hbuf, Wlin, blin, labels, trans,
                                         start, endv, out, lossp);
}

// Round 8
// 384.402 us; speedup vs baseline: 1.0532x; 1.0532x over previous
//
#include <hip/hip_runtime.h>
#include <math.h>

#define T_LEN 256
#define BATCH 32
#define HID   768
#define GH    384   // 3*LSTM_H
#define LH    128   // LSTM_H
#define NLAB  9
#define M_TOT (T_LEN*BATCH)  // 8192

typedef float v2f __attribute__((ext_vector_type(2)));
typedef _Float16 h8 __attribute__((ext_vector_type(8)));
typedef float f4 __attribute__((ext_vector_type(4)));

#define LO_SCALE 1024.f
#define LO_INV   (1.f/1024.f)

// Immediate-pattern lane broadcast within 32-lane half: every lane reads lane i.
#define BC(x, i) __int_as_float(__builtin_amdgcn_ds_swizzle(__float_as_int(x), (i) << 5))

// Raw barrier with LDS-only drain (no vmcnt stall on in-flight prefetch/stores).
#define BAR_LGKM() do {                                   \
    asm volatile("s_waitcnt lgkmcnt(0)" ::: "memory");    \
    __builtin_amdgcn_s_barrier();                         \
    asm volatile("" ::: "memory");                        \
  } while (0)

// ---------------- K1: xp = emb[ids] @ [Wih_f;Wih_b]^T + bias  (MFMA v6) -----
__global__ __launch_bounds__(256, 2) void k_gemm_xp(
    const int* __restrict__ ids, const float* __restrict__ emb,
    const float* __restrict__ Wf, const float* __restrict__ Wb,
    const float* __restrict__ bihf, const float* __restrict__ bihb,
    float* __restrict__ xp)
{
  __shared__ __align__(16) _Float16 Ah[128*40];
  __shared__ __align__(16) _Float16 Al[128*40];
  __shared__ __align__(16) _Float16 Bh[128*40];
  __shared__ __align__(16) _Float16 Bl[128*40];

  const int tid  = threadIdx.x;
  const int lane = tid & 63, w = tid >> 6;
  const int m0 = blockIdx.y * 128, n0 = blockIdx.x * 128;

  const int srow = tid >> 1, sk = (tid & 1) * 16;
  const int gm = m0 + srow;
  const int tok = ids[(gm & 31) * T_LEN + (gm >> 5)];
  const float* aG = emb + (size_t)tok * HID + sk;
  const int gn = n0 + srow;
  const float* bG = (gn < GH ? Wf + (size_t)gn * HID
                             : Wb + (size_t)(gn - GH) * HID) + sk;

  const int fr = lane & 15, fq = lane >> 4;
  const int mrow = (w & 1) * 64;
  const int ncol = (w >> 1) * 64;

  f4 acc[4][4];
  f4 acc2[4][4];
#pragma unroll
  for (int i = 0; i < 4; ++i)
#pragma unroll
    for (int j = 0; j < 4; ++j) { acc[i][j] = f4{0,0,0,0}; acc2[i][j] = f4{0,0,0,0}; }

  const int sb = srow * 40 + sk;

  float4 ra[4], rb[4];
#pragma unroll
  for (int c = 0; c < 4; ++c) {
    ra[c] = *reinterpret_cast<const float4*>(aG + 4 * c);
    rb[c] = *reinterpret_cast<const float4*>(bG + 4 * c);
  }

  for (int kt = 0; kt < HID / 32; ++kt) {
    BAR_LGKM();
#pragma unroll
    for (int m = 0; m < 2; ++m) {
      const float4* src = m ? rb : ra;
      _Float16* dsth = m ? Bh : Ah;
      _Float16* dstl = m ? Bl : Al;
#pragma unroll
      for (int seg = 0; seg < 2; ++seg) {
        float xs[8] = {src[2*seg].x, src[2*seg].y, src[2*seg].z, src[2*seg].w,
                       src[2*seg+1].x, src[2*seg+1].y, src[2*seg+1].z, src[2*seg+1].w};
        h8 hi, lo;
#pragma unroll
        for (int c = 0; c < 8; ++c) {
          _Float16 h = (_Float16)xs[c];
          hi[c] = h;
          lo[c] = (_Float16)((xs[c] - (float)h) * LO_SCALE);
        }
        *reinterpret_cast<h8*>(&dsth[sb + seg * 8]) = hi;
        *reinterpret_cast<h8*>(&dstl[sb + seg * 8]) = lo;
      }
    }
    if (kt + 1 < HID / 32) {
      const float* pa = aG + (kt + 1) * 32;
      const float* pb = bG + (kt + 1) * 32;
#pragma unroll
      for (int c = 0; c < 4; ++c) {
        ra[c] = *reinterpret_cast<const float4*>(pa + 4 * c);
        rb[c] = *reinterpret_cast<const float4*>(pb + 4 * c);
      }
    }
    BAR_LGKM();

    h8 fbh[4], fbl[4];
#pragma unroll
    for (int j = 0; j < 4; ++j) {
      const int off = (ncol + j * 16 + fr) * 40 + fq * 8;
      fbh[j] = *reinterpret_cast<const h8*>(&Bh[off]);
      fbl[j] = *reinterpret_cast<const h8*>(&Bl[off]);
    }
#pragma unroll
    for (int i = 0; i < 4; ++i) {
      const int off = (mrow + i * 16 + fr) * 40 + fq * 8;
      h8 fah = *reinterpret_cast<const h8*>(&Ah[off]);
      h8 fal = *reinterpret_cast<const h8*>(&Al[off]);
#pragma unroll
      for (int j = 0; j < 4; ++j) {
        acc[i][j]  = __builtin_amdgcn_mfma_f32_16x16x32_f16(fah, fbh[j], acc[i][j],  0, 0, 0);
        acc2[i][j] = __builtin_amdgcn_mfma_f32_16x16x32_f16(fah, fbl[j], acc2[i][j], 0, 0, 0);
        acc2[i][j] = __builtin_amdgcn_mfma_f32_16x16x32_f16(fal, fbh[j], acc2[i][j], 0, 0, 0);
      }
    }
  }

  float bcol[4];
#pragma unroll
  for (int j = 0; j < 4; ++j) {
    const int c = n0 + ncol + j * 16 + fr;
    bcol[j] = (c < GH) ? bihf[c] : bihb[c - GH];
  }
#pragma unroll
  for (int i = 0; i < 4; ++i)
#pragma unroll
    for (int j = 0; j < 4; ++j) {
      const int col = n0 + ncol + j * 16 + fr;
#pragma unroll
      for (int r = 0; r < 4; ++r) {
        const int row = m0 + mrow + i * 16 + fq * 4 + r;
        xp[(size_t)row * HID + col] = acc[i][j][r] + acc2[i][j][r] * LO_INV + bcol[j];
      }
    }
}

// ---------------- K2: bidirectional GRU recurrence (v11 — f16 LDS + dot2) ---
// Theory evolution: r6 falsified AGPR-shuttle (zero-shuttle asm = same perf);
// r7 falsified x-load latency (2-deep prefetch = worse). The invariant across
// v4/v9/v10 (~1450-1575 cy/step) is LDS traffic: register-fill of h is
// units*elems = 128*128 floats/step/block = 64 ds_read_b128 wave-instrs
// (~770cy on the shared LDS pipe) + 48 ds_swizzle (~290cy) -> the recurrence
// is LDS-THROUGHPUT-bound.
// v11: h stored in LDS as f16 -> 4 b128/lane (32 instr/step, ~385cy). Matvec
// via v_dot2_f32_f16 (f16 pairs, f32 accumulate, 2 MAC/instr): same 48-instr
// VALU cost, weights now 48 packed regs (converted once via v_cvt_pkrtz in
// prologue). hbuf keeps f32. Swizzle reduce + gate section verbatim from v9
// (hazard-proven). LDS dbuf stride 512B -> XOR 0x200.
// Regs: v96-101 ptrs/LDS addrs, v104-109 x trios, v110 hprev, v111-115 temps,
// v116-121 dot2 accs, v128-175 f16 weights (prologue stages f32 in v128-223),
// v176-191 h f16 fragment.
__global__ __attribute__((amdgpu_flat_work_group_size(512, 512),
                          amdgpu_waves_per_eu(2, 2)))
void k_gru(
    const float* __restrict__ xp,
    const float* __restrict__ Whhf, const float* __restrict__ Whhb,
    const float* __restrict__ bhhf, const float* __restrict__ bhhb,
    float* __restrict__ hbuf, float* __restrict__ lossp)
{
  __shared__ __align__(1024) _Float16 hsp[2][256];
  const int tid = threadIdx.x;
  const int g   = tid >> 2;       // hidden unit 0..127
  const int q   = tid & 3;        // 32-elem segment 0..3
  const int bd  = blockIdx.x;
  const int dir = bd >> 5, b = bd & 31;
  const float* Whh = dir ? Whhb : Whhf;
  const float* bhh = dir ? bhhb : bhhf;

  if (bd == 0 && tid == 0) *lossp = 0.f;

  const float br = bhh[g], bz = bhh[g + LH], bn = bhh[g + 2*LH];
  const float* wg0 = Whh + (size_t)(0*LH + g) * LH + q * 32;
  const float* wg1 = Whh + (size_t)(1*LH + g) * LH + q * 32;
  const float* wg2 = Whh + (size_t)(2*LH + g) * LH + q * 32;

  const int t0 = dir ? (T_LEN - 1) : 0;
  const int dt = dir ? -1 : 1;
  const float* px = xp + (size_t)t0 * BATCH * HID + b * HID + dir * GH + g;
  float*       ph = hbuf + (size_t)t0 * BATCH * 256 + b * 256 + dir * LH + g;

  const long long xs = (long long)dt * BATCH * HID * 4;   // xp t-stride, bytes
  const long long hs = (long long)dt * BATCH * 256 * 4;   // hbuf t-stride, bytes
  const unsigned xslo = (unsigned)(xs & 0xffffffffll);
  const int      xshi = (int)(xs >> 32);
  const unsigned hslo = (unsigned)(hs & 0xffffffffll);
  const int      hshi = (int)(hs >> 32);
  const unsigned xlo = (unsigned)(uintptr_t)px, xhi = (unsigned)((uintptr_t)px >> 32);
  const unsigned hlo = (unsigned)(uintptr_t)ph, hhi = (unsigned)((uintptr_t)ph >> 32);
  // generic AS0 shared pointers: low 32 bits = LDS byte offset.
  // read base: buf0 + q*64B (16 f16 = 4x b128); write: buf1 + g*2B (b16).
  const unsigned rd0 = (unsigned)(uintptr_t)(&hsp[0][q * 32]);
  const unsigned wr0 = (unsigned)(uintptr_t)(&hsp[1][g]);

  if (tid < 128) reinterpret_cast<unsigned*>(&hsp[0][0])[tid] = 0u;  // zero buf0
  BAR_LGKM();

  int cnt = T_LEN;
  asm volatile(
    // ---- prologue: stage f32 weights -> v[128:223], x(t0) -> v[107:109] ----
    "global_load_dwordx4 v[128:131], %[wg0], off\n\t"
    "global_load_dwordx4 v[132:135], %[wg0], off offset:16\n\t"
    "global_load_dwordx4 v[136:139], %[wg0], off offset:32\n\t"
    "global_load_dwordx4 v[140:143], %[wg0], off offset:48\n\t"
    "global_load_dwordx4 v[144:147], %[wg0], off offset:64\n\t"
    "global_load_dwordx4 v[148:151], %[wg0], off offset:80\n\t"
    "global_load_dwordx4 v[152:155], %[wg0], off offset:96\n\t"
    "global_load_dwordx4 v[156:159], %[wg0], off offset:112\n\t"
    "global_load_dwordx4 v[160:163], %[wg1], off\n\t"
    "global_load_dwordx4 v[164:167], %[wg1], off offset:16\n\t"
    "global_load_dwordx4 v[168:171], %[wg1], off offset:32\n\t"
    "global_load_dwordx4 v[172:175], %[wg1], off offset:48\n\t"
    "global_load_dwordx4 v[176:179], %[wg1], off offset:64\n\t"
    "global_load_dwordx4 v[180:183], %[wg1], off offset:80\n\t"
    "global_load_dwordx4 v[184:187], %[wg1], off offset:96\n\t"
    "global_load_dwordx4 v[188:191], %[wg1], off offset:112\n\t"
    "global_load_dwordx4 v[192:195], %[wg2], off\n\t"
    "global_load_dwordx4 v[196:199], %[wg2], off offset:16\n\t"
    "global_load_dwordx4 v[200:203], %[wg2], off offset:32\n\t"
    "global_load_dwordx4 v[204:207], %[wg2], off offset:48\n\t"
    "global_load_dwordx4 v[208:211], %[wg2], off offset:64\n\t"
    "global_load_dwordx4 v[212:215], %[wg2], off offset:80\n\t"
    "global_load_dwordx4 v[216:219], %[wg2], off offset:96\n\t"
    "global_load_dwordx4 v[220:223], %[wg2], off offset:112\n\t"
    "v_mov_b32 v96, %[xlo]\n\t"
    "v_mov_b32 v97, %[xhi]\n\t"
    "v_mov_b32 v98, %[hlo]\n\t"
    "v_mov_b32 v99, %[hhi]\n\t"
    "v_mov_b32 v100, %[rd0]\n\t"
    "v_mov_b32 v101, %[wr0]\n\t"
    "global_load_dword v107, v[96:97], off\n\t"
    "global_load_dword v108, v[96:97], off offset:512\n\t"
    "global_load_dword v109, v[96:97], off offset:1024\n\t"
    "s_waitcnt vmcnt(3)\n\t"           // all 24 weight loads retired
    // pack 96 f32 -> 48 f16-pair regs in place: v(128+i) = pk(v(128+2i), v(129+2i))
    "v_cvt_pkrtz_f16_f32 v128, v128, v129\n\t"
    "v_cvt_pkrtz_f16_f32 v129, v130, v131\n\t"
    "v_cvt_pkrtz_f16_f32 v130, v132, v133\n\t"
    "v_cvt_pkrtz_f16_f32 v131, v134, v135\n\t"
    "v_cvt_pkrtz_f16_f32 v132, v136, v137\n\t"
    "v_cvt_pkrtz_f16_f32 v133, v138, v139\n\t"
    "v_cvt_pkrtz_f16_f32 v134, v140, v141\n\t"
    "v_cvt_pkrtz_f16_f32 v135, v142, v143\n\t"
    "v_cvt_pkrtz_f16_f32 v136, v144, v145\n\t"
    "v_cvt_pkrtz_f16_f32 v137, v146, v147\n\t"
    "v_cvt_pkrtz_f16_f32 v138, v148, v149\n\t"
    "v_cvt_pkrtz_f16_f32 v139, v150, v151\n\t"
    "v_cvt_pkrtz_f16_f32 v140, v152, v153\n\t"
    "v_cvt_pkrtz_f16_f32 v141, v154, v155\n\t"
    "v_cvt_pkrtz_f16_f32 v142, v156, v157\n\t"
    "v_cvt_pkrtz_f16_f32 v143, v158, v159\n\t"
    "v_cvt_pkrtz_f16_f32 v144, v160, v161\n\t"
    "v_cvt_pkrtz_f16_f32 v145, v162, v163\n\t"
    "v_cvt_pkrtz_f16_f32 v146, v164, v165\n\t"
    "v_cvt_pkrtz_f16_f32 v147, v166, v167\n\t"
    "v_cvt_pkrtz_f16_f32 v148, v168, v169\n\t"
    "v_cvt_pkrtz_f16_f32 v149, v170, v171\n\t"
    "v_cvt_pkrtz_f16_f32 v150, v172, v173\n\t"
    "v_cvt_pkrtz_f16_f32 v151, v174, v175\n\t"
    "v_cvt_pkrtz_f16_f32 v152, v176, v177\n\t"
    "v_cvt_pkrtz_f16_f32 v153, v178, v179\n\t"
    "v_cvt_pkrtz_f16_f32 v154, v180, v181\n\t"
    "v_cvt_pkrtz_f16_f32 v155, v182, v183\n\t"
    "v_cvt_pkrtz_f16_f32 v156, v184, v185\n\t"
    "v_cvt_pkrtz_f16_f32 v157, v186, v187\n\t"
    "v_cvt_pkrtz_f16_f32 v158, v188, v189\n\t"
    "v_cvt_pkrtz_f16_f32 v159, v190, v191\n\t"
    "v_cvt_pkrtz_f16_f32 v160, v192, v193\n\t"
    "v_cvt_pkrtz_f16_f32 v161, v194, v195\n\t"
    "v_cvt_pkrtz_f16_f32 v162, v196, v197\n\t"
    "v_cvt_pkrtz_f16_f32 v163, v198, v199\n\t"
    "v_cvt_pkrtz_f16_f32 v164, v200, v201\n\t"
    "v_cvt_pkrtz_f16_f32 v165, v202, v203\n\t"
    "v_cvt_pkrtz_f16_f32 v166, v204, v205\n\t"
    "v_cvt_pkrtz_f16_f32 v167, v206, v207\n\t"
    "v_cvt_pkrtz_f16_f32 v168, v208, v209\n\t"
    "v_cvt_pkrtz_f16_f32 v169, v210, v211\n\t"
    "v_cvt_pkrtz_f16_f32 v170, v212, v213\n\t"
    "v_cvt_pkrtz_f16_f32 v171, v214, v215\n\t"
    "v_cvt_pkrtz_f16_f32 v172, v216, v217\n\t"
    "v_cvt_pkrtz_f16_f32 v173, v218, v219\n\t"
    "v_cvt_pkrtz_f16_f32 v174, v220, v221\n\t"
    "v_cvt_pkrtz_f16_f32 v175, v222, v223\n\t"
    "v_mov_b32 v110, 0\n\t"
    "s_waitcnt vmcnt(0)\n\t"           // x(t0) trio arrived
    // ---- main loop: one step per iteration ----
    "0:\n\t"
    "s_waitcnt vmcnt(1)\n\t"           // prev-issued x trio retired (store may fly)
    "v_mov_b32 v104, v107\n\t"
    "v_mov_b32 v105, v108\n\t"
    "v_mov_b32 v106, v109\n\t"
    "ds_read_b128 v[176:179], v100\n\t"
    "ds_read_b128 v[180:183], v100 offset:16\n\t"
    "ds_read_b128 v[184:187], v100 offset:32\n\t"
    "ds_read_b128 v[188:191], v100 offset:48\n\t"
    "s_cmp_gt_u32 %[cnt], 1\n\t"       // skip pointer advance on last step
    "s_cbranch_scc0 3f\n\t"
    "v_add_co_u32 v96, vcc, %[xslo], v96\n\t"
    "v_addc_co_u32 v97, vcc, %[xshi], v97, vcc\n\t"
    "3:\n\t"
    "global_load_dword v107, v[96:97], off\n\t"
    "global_load_dword v108, v[96:97], off offset:512\n\t"
    "global_load_dword v109, v[96:97], off offset:1024\n\t"
    "s_waitcnt lgkmcnt(0)\n\t"
    // dot2 matvec: 48 v_dot2_f32_f16, 2 accs/gate, gates interleaved (ILP)
    "v_mov_b32 v116, 0\n\t"
    "v_mov_b32 v117, 0\n\t"
    "v_mov_b32 v118, 0\n\t"
    "v_mov_b32 v119, 0\n\t"
    "v_mov_b32 v120, 0\n\t"
    "v_mov_b32 v121, 0\n\t"
    "v_dot2_f32_f16 v116, v128, v176, v116\n\t"
    "v_dot2_f32_f16 v118, v144, v176, v118\n\t"
    "v_dot2_f32_f16 v120, v160, v176, v120\n\t"
    "v_dot2_f32_f16 v117, v129, v177, v117\n\t"
    "v_dot2_f32_f16 v119, v145, v177, v119\n\t"
    "v_dot2_f32_f16 v121, v161, v177, v121\n\t"
    "v_dot2_f32_f16 v116, v130, v178, v116\n\t"
    "v_dot2_f32_f16 v118, v146, v178, v118\n\t"
    "v_dot2_f32_f16 v120, v162, v178, v120\n\t"
    "v_dot2_f32_f16 v117, v131, v179, v117\n\t"
    "v_dot2_f32_f16 v119, v147, v179, v119\n\t"
    "v_dot2_f32_f16 v121, v163, v179, v121\n\t"
    "v_dot2_f32_f16 v116, v132, v180, v116\n\t"
    "v_dot2_f32_f16 v118, v148, v180, v118\n\t"
    "v_dot2_f32_f16 v120, v164, v180, v120\n\t"
    "v_dot2_f32_f16 v117, v133, v181, v117\n\t"
    "v_dot2_f32_f16 v119, v149, v181, v119\n\t"
    "v_dot2_f32_f16 v121, v165, v181, v121\n\t"
    "v_dot2_f32_f16 v116, v134, v182, v116\n\t"
    "v_dot2_f32_f16 v118, v150, v182, v118\n\t"
    "v_dot2_f32_f16 v120, v166, v182, v120\n\t"
    "v_dot2_f32_f16 v117, v135, v183, v117\n\t"
    "v_dot2_f32_f16 v119, v151, v183, v119\n\t"
    "v_dot2_f32_f16 v121, v167, v183, v121\n\t"
    "v_dot2_f32_f16 v116, v136, v184, v116\n\t"
    "v_dot2_f32_f16 v118, v152, v184, v118\n\t"
    "v_dot2_f32_f16 v120, v168, v184, v120\n\t"
    "v_dot2_f32_f16 v117, v137, v185, v117\n\t"
    "v_dot2_f32_f16 v119, v153, v185, v119\n\t"
    "v_dot2_f32_f16 v121, v169, v185, v121\n\t"
    "v_dot2_f32_f16 v116, v138, v186, v116\n\t"
    "v_dot2_f32_f16 v118, v154, v186, v118\n\t"
    "v_dot2_f32_f16 v120, v170, v186, v120\n\t"
    "v_dot2_f32_f16 v117, v139, v187, v117\n\t"
    "v_dot2_f32_f16 v119, v155, v187, v119\n\t"
    "v_dot2_f32_f16 v121, v171, v187, v121\n\t"
    "v_dot2_f32_f16 v116, v140, v188, v116\n\t"
    "v_dot2_f32_f16 v118, v156, v188, v118\n\t"
    "v_dot2_f32_f16 v120, v172, v188, v120\n\t"
    "v_dot2_f32_f16 v117, v141, v189, v117\n\t"
    "v_dot2_f32_f16 v119, v157, v189, v119\n\t"
    "v_dot2_f32_f16 v121, v173, v189, v121\n\t"
    "v_dot2_f32_f16 v116, v142, v190, v116\n\t"
    "v_dot2_f32_f16 v118, v158, v190, v118\n\t"
    "v_dot2_f32_f16 v120, v174, v190, v120\n\t"
    "v_dot2_f32_f16 v117, v143, v191, v117\n\t"
    "v_dot2_f32_f16 v119, v159, v191, v119\n\t"
    "v_dot2_f32_f16 v121, v175, v191, v121\n\t"
    // horizontal: r->v116, z->v118, n->v120
    "v_add_f32 v116, v116, v117\n\t"
    "v_add_f32 v118, v118, v119\n\t"
    "v_add_f32 v120, v120, v121\n\t"
    // quad butterfly: xor1, xor2 (proven v9 pattern)
    "ds_swizzle_b32 v111, v116 offset:0x041F\n\t"
    "ds_swizzle_b32 v112, v118 offset:0x041F\n\t"
    "ds_swizzle_b32 v113, v120 offset:0x041F\n\t"
    "s_waitcnt lgkmcnt(0)\n\t"
    "v_add_f32 v116, v116, v111\n\t"
    "v_add_f32 v118, v118, v112\n\t"
    "v_add_f32 v120, v120, v113\n\t"
    "ds_swizzle_b32 v111, v116 offset:0x081F\n\t"
    "ds_swizzle_b32 v112, v118 offset:0x081F\n\t"
    "ds_swizzle_b32 v113, v120 offset:0x081F\n\t"
    "s_waitcnt lgkmcnt(0)\n\t"
    "v_add_f32 v116, v116, v111\n\t"
    "v_add_f32 v118, v118, v112\n\t"
    "v_add_f32 v120, v120, v113\n\t"
    // ---- gates (verbatim v9 hazard-safe interleave; z=v118, n=v120) ----
    "v_add_f32 v111, v104, v116\n\t"
    "v_add_f32 v112, v105, v118\n\t"
    "v_add_f32 v113, v120, %[bn]\n\t"
    "v_add_f32 v111, v111, %[br]\n\t"
    "v_add_f32 v112, v112, %[bz]\n\t"
    "v_mul_f32 v111, 0xbfb8aa3b, v111\n\t"
    "v_mul_f32 v112, 0xbfb8aa3b, v112\n\t"
    "v_exp_f32 v111, v111\n\t"
    "v_exp_f32 v112, v112\n\t"
    "s_nop 0\n\t"
    "v_add_f32 v111, 1.0, v111\n\t"
    "v_add_f32 v112, 1.0, v112\n\t"
    "v_rcp_f32 v111, v111\n\t"
    "v_rcp_f32 v112, v112\n\t"
    "s_nop 0\n\t"
    "v_fmac_f32 v106, v111, v113\n\t"
    "v_mul_f32 v113, 0x4038aa3b, v106\n\t"
    "v_exp_f32 v113, v113\n\t"
    "v_sub_f32 v115, 1.0, v112\n\t"
    "s_nop 0\n\t"
    "v_add_f32 v114, -1.0, v113\n\t"
    "v_add_f32 v113, 1.0, v113\n\t"
    "v_rcp_f32 v113, v113\n\t"
    "s_nop 1\n\t"
    "v_mul_f32 v114, v114, v113\n\t"
    "v_mul_f32 v115, v115, v114\n\t"
    "v_fmac_f32 v115, v112, v110\n\t"
    "v_mov_b32 v110, v115\n\t"
    // store h: f16 -> LDS (next parity), f32 -> hbuf
    "v_cvt_f16_f32 v114, v115\n\t"
    "global_store_dword v[98:99], v115, off\n\t"
    "v_add_co_u32 v98, vcc, %[hslo], v98\n\t"
    "v_addc_co_u32 v99, vcc, %[hshi], v99, vcc\n\t"
    "ds_write_b16 v101, v114\n\t"
    "v_xor_b32 v100, 0x200, v100\n\t"
    "v_xor_b32 v101, 0x200, v101\n\t"
    "s_waitcnt lgkmcnt(0)\n\t"
    "s_barrier\n\t"
    "s_sub_u32 %[cnt], %[cnt], 1\n\t"
    "s_cmp_lg_u32 %[cnt], 0\n\t"
    "s_cbranch_scc1 0b\n\t"
    : [cnt]"+s"(cnt)
    : [wg0]"v"(wg0), [wg1]"v"(wg1), [wg2]"v"(wg2),
      [xlo]"v"(xlo), [xhi]"v"(xhi), [hlo]"v"(hlo), [hhi]"v"(hhi),
      [rd0]"v"(rd0), [wr0]"v"(wr0),
      [br]"v"(br), [bz]"v"(bz), [bn]"v"(bn),
      [xslo]"s"(xslo), [xshi]"v"(xshi), [hslo]"s"(hslo), [hshi]"v"(hshi)
    : "memory", "vcc", "scc",
      "v96","v97","v98","v99","v100","v101","v102","v103","v104","v105",
      "v106","v107","v108","v109","v110","v111","v112","v113","v114","v115",
      "v116","v117","v118","v119","v120","v121","v122","v123","v124","v125",
      "v126","v127","v128","v129","v130","v131","v132","v133","v134","v135",
      "v136","v137","v138","v139","v140","v141","v142","v143","v144","v145",
      "v146","v147","v148","v149","v150","v151","v152","v153","v154","v155",
      "v156","v157","v158","v159","v160","v161","v162","v163","v164","v165",
      "v166","v167","v168","v169","v170","v171","v172","v173","v174","v175",
      "v176","v177","v178","v179","v180","v181","v182","v183","v184","v185",
      "v186","v187","v188","v189","v190","v191","v192","v193","v194","v195",
      "v196","v197","v198","v199","v200","v201","v202","v203","v204","v205",
      "v206","v207","v208","v209","v210","v211","v212","v213","v214","v215",
      "v216","v217","v218","v219","v220","v221","v222","v223");
}

// ---------------- K3: fused emissions + Viterbi + CRF-LLH (v2) --------------
__global__ __launch_bounds__(256, 1) void k_crf_fused(
    const float* __restrict__ hbuf, const float* __restrict__ Wlin,
    const float* __restrict__ blin, const int* __restrict__ labels,
    const float* __restrict__ trans, const float* __restrict__ start,
    const float* __restrict__ endv, float* __restrict__ dec_out,
    float* __restrict__ lossp)
{
  __shared__ float el[T_LEN * 10];
  __shared__ __align__(16) unsigned char bp8[(T_LEN - 1) * 16];
  const int b    = blockIdx.x;
  const int tid  = threadIdx.x;
  const int lane = tid & 63, w = tid >> 6;
  const int sub  = lane >> 4, l16 = lane & 15;

  float4 wreg[NLAB][4];
#pragma unroll
  for (int j = 0; j < NLAB; ++j)
#pragma unroll
    for (int c = 0; c < 4; ++c)
      wreg[j][c] = *reinterpret_cast<const float4*>(Wlin + j * 256 + l16 * 16 + c * 4);

  // ---- phase 1: emissions ----
  for (int k = 0; k < 16; ++k) {
    const int t = w * 64 + k * 4 + sub;
    const float* hp = hbuf + ((size_t)t * BATCH + b) * 256 + l16 * 16;
    const float4 h0 = *reinterpret_cast<const float4*>(hp);
    const float4 h1 = *reinterpret_cast<const float4*>(hp + 4);
    const float4 h2 = *reinterpret_cast<const float4*>(hp + 8);
    const float4 h3 = *reinterpret_cast<const float4*>(hp + 12);
    float acc[NLAB];
#pragma unroll
    for (int j = 0; j < NLAB; ++j) {
      const float4 w0 = wreg[j][0], w1 = wreg[j][1], w2 = wreg[j][2], w3 = wreg[j][3];
      float s0 = h0.x*w0.x + h0.y*w0.y + h0.z*w0.z + h0.w*w0.w;
      float s1 = h1.x*w1.x + h1.y*w1.y + h1.z*w1.z + h1.w*w1.w;
      float s2 = h2.x*w2.x + h2.y*w2.y + h2.z*w2.z + h2.w*w2.w;
      float s3 = h3.x*w3.x + h3.y*w3.y + h3.z*w3.z + h3.w*w3.w;
      acc[j] = (s0 + s1) + (s2 + s3);
    }
#pragma unroll
    for (int j = 0; j < NLAB; ++j) {
#pragma unroll
      for (int off = 1; off < 16; off <<= 1)
        acc[j] += __shfl_xor(acc[j], off);
    }
    if (l16 < NLAB) {
      float v = acc[0];
#pragma unroll
      for (int j = 1; j < NLAB; ++j) v = (l16 == j) ? acc[j] : v;
      el[t * 10 + l16] = v + blin[l16];
    }
  }
  __syncthreads();

  if (w == 0) {
    // ---- Viterbi ----
    float tcol[NLAB];
#pragma unroll
    for (int i = 0; i < NLAB; ++i)
      tcol[i] = (lane < NLAB) ? trans[i * NLAB + lane] : 0.f;
    float alpha = (lane < NLAB) ? (start[lane] + el[lane]) : -3e38f;
    float et_next = (lane < NLAB) ? el[10 + lane] : 0.f;
    for (int s = 0; s < T_LEN - 1; ++s) {
      const float et = et_next;
      if (s < T_LEN - 2)
        et_next = (lane < NLAB) ? el[(s + 2) * 10 + lane] : 0.f;
      float v[NLAB];
      v[0] = BC(alpha, 0) + tcol[0];
      v[1] = BC(alpha, 1) + tcol[1];
      v[2] = BC(alpha, 2) + tcol[2];
      v[3] = BC(alpha, 3) + tcol[3];
      v[4] = BC(alpha, 4) + tcol[4];
      v[5] = BC(alpha, 5) + tcol[5];
      v[6] = BC(alpha, 6) + tcol[6];
      v[7] = BC(alpha, 7) + tcol[7];
      v[8] = BC(alpha, 8) + tcol[8];
      float v01 = (v[0] >= v[1]) ? v[0] : v[1];  int i01 = (v[0] >= v[1]) ? 0 : 1;
      float v23 = (v[2] >= v[3]) ? v[2] : v[3];  int i23 = (v[2] >= v[3]) ? 2 : 3;
      float v45 = (v[4] >= v[5]) ? v[4] : v[5];  int i45 = (v[4] >= v[5]) ? 4 : 5;
      float v67 = (v[6] >= v[7]) ? v[6] : v[7];  int i67 = (v[6] >= v[7]) ? 6 : 7;
      float va = (v01 >= v23) ? v01 : v23;       int ia = (v01 >= v23) ? i01 : i23;
      float vb = (v45 >= v67) ? v45 : v67;       int ib = (v45 >= v67) ? i45 : i67;
      float vc = (va >= vb) ? va : vb;           int ic = (va >= vb) ? ia : ib;
      float best = (vc >= v[8]) ? vc : v[8];     int bi = (vc >= v[8]) ? ic : 8;
      alpha = best + et;
      if (lane < NLAB) bp8[s * 16 + lane] = (unsigned char)bi;
    }
    float fin = alpha + ((lane < NLAB) ? endv[lane] : 0.f);
    float fv[NLAB];
    fv[0] = BC(fin, 0); fv[1] = BC(fin, 1); fv[2] = BC(fin, 2);
    fv[3] = BC(fin, 3); fv[4] = BC(fin, 4); fv[5] = BC(fin, 5);
    fv[6] = BC(fin, 6); fv[7] = BC(fin, 7); fv[8] = BC(fin, 8);
    float f01 = (fv[0] >= fv[1]) ? fv[0] : fv[1];  int j01 = (fv[0] >= fv[1]) ? 0 : 1;
    float f23 = (fv[2] >= fv[3]) ? fv[2] : fv[3];  int j23 = (fv[2] >= fv[3]) ? 2 : 3;
    float f45 = (fv[4] >= fv[5]) ? fv[4] : fv[5];  int j45 = (fv[4] >= fv[5]) ? 4 : 5;
    float f67 = (fv[6] >= fv[7]) ? fv[6] : fv[7];  int j67 = (fv[6] >= fv[7]) ? 6 : 7;
    float fa = (f01 >= f23) ? f01 : f23;           int ja = (f01 >= f23) ? j01 : j23;
    float fb = (f45 >= f67) ? f45 : f67;           int jb = (f45 >= f67) ? j45 : j67;
    float fc = (fa >= fb) ? fa : fb;               int jc = (fa >= fb) ? ja : jb;
    int last = (fc >= fv[8]) ? jc : 8;
    if (lane == 0) {
      int y = last;
      dec_out[b * T_LEN + (T_LEN - 1)] = (float)y;
      uint4 row = *reinterpret_cast<const uint4*>(&bp8[(T_LEN - 2) * 16]);
      for (int s = T_LEN - 2; s >= 0; --s) {
        uint4 nrow = row;
        if (s > 0) nrow = *reinterpret_cast<const uint4*>(&bp8[(s - 1) * 16]);
        unsigned wsel = (y < 4) ? row.x : ((y < 8) ? row.y : row.z);
        y = (int)((wsel >> ((y & 3) * 8)) & 0xffu);
        dec_out[b * T_LEN + s] = (float)y;
        row = nrow;
      }
    }
  } else if (w == 1) {
    // ---- CRF log-likelihood ----
    float tcol[NLAB];
#pragma unroll
    for (int i = 0; i < NLAB; ++i)
      tcol[i] = (lane < NLAB) ? trans[i * NLAB + lane] : 0.f;
    float ca = (lane < NLAB) ? (start[lane] + el[lane]) : -3e38f;
    float et_next = (lane < NLAB) ? el[10 + lane] : 0.f;
    for (int s = 0; s < T_LEN - 1; ++s) {
      const float et = et_next;
      if (s < T_LEN - 2)
        et_next = (lane < NLAB) ? el[(s + 2) * 10 + lane] : 0.f;
      float c[NLAB];
      c[0] = BC(ca, 0) + tcol[0];
      c[1] = BC(ca, 1) + tcol[1];
      c[2] = BC(ca, 2) + tcol[2];
      c[3] = BC(ca, 3) + tcol[3];
      c[4] = BC(ca, 4) + tcol[4];
      c[5] = BC(ca, 5) + tcol[5];
      c[6] = BC(ca, 6) + tcol[6];
      c[7] = BC(ca, 7) + tcol[7];
      c[8] = BC(ca, 8) + tcol[8];
      float m01 = fmaxf(c[0], c[1]), m23 = fmaxf(c[2], c[3]);
      float m45 = fmaxf(c[4], c[5]), m67 = fmaxf(c[6], c[7]);
      float m = fmaxf(fmaxf(fmaxf(m01, m23), fmaxf(m45, m67)), c[8]);
      float p0 = __expf(c[0]-m) + __expf(c[1]-m), p1 = __expf(c[2]-m) + __expf(c[3]-m);
      float p2 = __expf(c[4]-m) + __expf(c[5]-m), p3 = __expf(c[6]-m) + __expf(c[7]-m);
      float p = ((p0 + p1) + (p2 + p3)) + __expf(c[8]-m);
      ca = m + __logf(p) + et;
    }
    float fv[NLAB];
    fv[0] = BC(ca, 0) + endv[0];
    fv[1] = BC(ca, 1) + endv[1];
    fv[2] = BC(ca, 2) + endv[2];
    fv[3] = BC(ca, 3) + endv[3];
    fv[4] = BC(ca, 4) + endv[4];
    fv[5] = BC(ca, 5) + endv[5];
    fv[6] = BC(ca, 6) + endv[6];
    fv[7] = BC(ca, 7) + endv[7];
    fv[8] = BC(ca, 8) + endv[8];
    float mx = -3e38f;
#pragma unroll
    for (int j = 0; j < NLAB; ++j) mx = fmaxf(mx, fv[j]);
    float ps = 0.f;
#pragma unroll
    for (int j = 0; j < NLAB; ++j) ps += __expf(fv[j] - mx);
    float denom = mx + __logf(ps);

    const int* lb = labels + b * T_LEN;
    float part = 0.f;
    for (int t4 = 0; t4 < 4; ++t4) {
      int t = lane * 4 + t4;
      int l = lb[t];
      part += el[t * 10 + l];
      if (t > 0) part += trans[lb[t - 1] * NLAB + l];
    }
#pragma unroll
    for (int off = 32; off > 0; off >>= 1) part += __shfl_xor(part, off);
    if (lane == 0) {
      float num = part + start[lb[0]] + endv[lb[T_LEN - 1]];
      float llh = num - denom;
      atomicAdd(lossp, -llh * (1.0f / BATCH));
    }
  }
}

extern "C" void kernel_launch(void* const* d_in, const int* in_sizes, int n_in,
                              void* d_out, int out_size, void* d_ws, size_t ws_size,
                              hipStream_t stream) {
  const int*   ids    = (const int*)d_in[0];
  const int*   labels = (const int*)d_in[2];
  const float* emb    = (const float*)d_in[3];
  const float* Wihf   = (const float*)d_in[4];
  const float* Whhf   = (const float*)d_in[5];
  const float* bihf   = (const float*)d_in[6];
  const float* bhhf   = (const float*)d_in[7];
  const float* Wihb   = (const float*)d_in[8];
  const float* Whhb   = (const float*)d_in[9];
  const float* bihb   = (const float*)d_in[10];
  const float* bhhb   = (const float*)d_in[11];
  const float* Wlin   = (const float*)d_in[12];
  const float* blin   = (const float*)d_in[13];
  const float* trans  = (const float*)d_in[14];
  const float* start  = (const float*)d_in[15];
  const float* endv   = (const float*)d_in[16];

  float* xp    = (float*)d_ws;                       // [T][B][768]
  float* hbuf  = xp + (size_t)M_TOT * HID;           // [T][B][256]
  float* out   = (float*)d_out;                      // decoded as floats
  float* lossp = out + M_TOT;                        // loss scalar

  k_gemm_xp<<<dim3(6, 64), 256, 0, stream>>>(ids, emb, Wihf, Wihb, bihf, bihb, xp);
  k_gru<<<64, 512, 0, stream>>>(xp, Whhf, Whhb, bhhf, bhhb, hbuf, lossp);
  k_crf_fused<<<BATCH, 256, 0, stream>>>(hbuf, Wlin, blin, labels, trans,
                                         start, endv, out, lossp);
}

// Round 9
// 375.325 us; speedup vs baseline: 1.0786x; 1.0242x over previous
//
#include <hip/hip_runtime.h>
#include <math.h>

#define T_LEN 256
#define BATCH 32
#define HID   768
#define GH    384   // 3*LSTM_H
#define LH    128   // LSTM_H
#define NLAB  9
#define M_TOT (T_LEN*BATCH)  // 8192

typedef float v2f __attribute__((ext_vector_type(2)));
typedef _Float16 h8 __attribute__((ext_vector_type(8)));
typedef float f4 __attribute__((ext_vector_type(4)));

// Immediate-pattern lane broadcast within 32-lane half: every lane reads lane i.
#define BC(x, i) __int_as_float(__builtin_amdgcn_ds_swizzle(__float_as_int(x), (i) << 5))

// Raw barrier with LDS-only drain (no vmcnt stall on in-flight prefetch/stores).
#define BAR_LGKM() do {                                   \
    asm volatile("s_waitcnt lgkmcnt(0)" ::: "memory");    \
    __builtin_amdgcn_s_barrier();                         \
    asm volatile("" ::: "memory");                        \
  } while (0)

// ---------------- K1: xp = emb[ids] @ [Wih_f;Wih_b]^T + bias  (v7 pure f16) -
// v7: hi/lo split REMOVED. Rationale (budget analysis, r8): total - k_gru =
// 235µs constant across all rounds; K1's hi/lo path does 3 MFMA per output +
// 2x LDS staging for f32-grade precision the outputs don't need (argmax decode
// + loss threshold 11.28; K2's matvec is already pure-f16 and passed absmax 0).
// Pure f16: 16 MFMA/k-tile (was 48), half the LDS stores/reads, half the
// convert VALU. Expected xp abs error ~1e-5 (inputs scale 0.02, f16 eps 5e-4).
__global__ __launch_bounds__(256, 2) void k_gemm_xp(
    const int* __restrict__ ids, const float* __restrict__ emb,
    const float* __restrict__ Wf, const float* __restrict__ Wb,
    const float* __restrict__ bihf, const float* __restrict__ bihb,
    float* __restrict__ xp)
{
  __shared__ __align__(16) _Float16 Ah[128*40];
  __shared__ __align__(16) _Float16 Bh[128*40];

  const int tid  = threadIdx.x;
  const int lane = tid & 63, w = tid >> 6;
  const int m0 = blockIdx.y * 128, n0 = blockIdx.x * 128;

  const int srow = tid >> 1, sk = (tid & 1) * 16;
  const int gm = m0 + srow;
  const int tok = ids[(gm & 31) * T_LEN + (gm >> 5)];
  const float* aG = emb + (size_t)tok * HID + sk;
  const int gn = n0 + srow;
  const float* bG = (gn < GH ? Wf + (size_t)gn * HID
                             : Wb + (size_t)(gn - GH) * HID) + sk;

  const int fr = lane & 15, fq = lane >> 4;
  const int mrow = (w & 1) * 64;
  const int ncol = (w >> 1) * 64;

  f4 acc[4][4];
#pragma unroll
  for (int i = 0; i < 4; ++i)
#pragma unroll
    for (int j = 0; j < 4; ++j) acc[i][j] = f4{0,0,0,0};

  const int sb = srow * 40 + sk;

  float4 ra[4], rb[4];
#pragma unroll
  for (int c = 0; c < 4; ++c) {
    ra[c] = *reinterpret_cast<const float4*>(aG + 4 * c);
    rb[c] = *reinterpret_cast<const float4*>(bG + 4 * c);
  }

  for (int kt = 0; kt < HID / 32; ++kt) {
    BAR_LGKM();
    // convert current regs -> LDS (f16, round-to-nearest via cast)
#pragma unroll
    for (int m = 0; m < 2; ++m) {
      const float4* src = m ? rb : ra;
      _Float16* dsth = m ? Bh : Ah;
#pragma unroll
      for (int seg = 0; seg < 2; ++seg) {
        float xs[8] = {src[2*seg].x, src[2*seg].y, src[2*seg].z, src[2*seg].w,
                       src[2*seg+1].x, src[2*seg+1].y, src[2*seg+1].z, src[2*seg+1].w};
        h8 hi;
#pragma unroll
        for (int c = 0; c < 8; ++c) hi[c] = (_Float16)xs[c];
        *reinterpret_cast<h8*>(&dsth[sb + seg * 8]) = hi;
      }
    }
    // prefetch next tile — stays in flight across BAR_LGKM (no vmcnt drain)
    if (kt + 1 < HID / 32) {
      const float* pa = aG + (kt + 1) * 32;
      const float* pb = bG + (kt + 1) * 32;
#pragma unroll
      for (int c = 0; c < 4; ++c) {
        ra[c] = *reinterpret_cast<const float4*>(pa + 4 * c);
        rb[c] = *reinterpret_cast<const float4*>(pb + 4 * c);
      }
    }
    BAR_LGKM();

    h8 fbh[4];
#pragma unroll
    for (int j = 0; j < 4; ++j) {
      const int off = (ncol + j * 16 + fr) * 40 + fq * 8;
      fbh[j] = *reinterpret_cast<const h8*>(&Bh[off]);
    }
#pragma unroll
    for (int i = 0; i < 4; ++i) {
      const int off = (mrow + i * 16 + fr) * 40 + fq * 8;
      h8 fah = *reinterpret_cast<const h8*>(&Ah[off]);
#pragma unroll
      for (int j = 0; j < 4; ++j)
        acc[i][j] = __builtin_amdgcn_mfma_f32_16x16x32_f16(fah, fbh[j], acc[i][j], 0, 0, 0);
    }
  }

  float bcol[4];
#pragma unroll
  for (int j = 0; j < 4; ++j) {
    const int c = n0 + ncol + j * 16 + fr;
    bcol[j] = (c < GH) ? bihf[c] : bihb[c - GH];
  }
#pragma unroll
  for (int i = 0; i < 4; ++i)
#pragma unroll
    for (int j = 0; j < 4; ++j) {
      const int col = n0 + ncol + j * 16 + fr;
#pragma unroll
      for (int r = 0; r < 4; ++r) {
        const int row = m0 + mrow + i * 16 + fq * 4 + r;
        xp[(size_t)row * HID + col] = acc[i][j][r] + bcol[j];
      }
    }
}

// ---------------- K2: bidirectional GRU recurrence (v11 — f16 LDS + dot2) ---
// Best measured variant (149.6µs). r6/r7/r8 falsified AGPR-shuttle, x-latency,
// and LDS-throughput theories; the residual ~900cy/step is the exposed serial
// chain (barrier-synced waves stall together). Kept frozen this round.
__global__ __attribute__((amdgpu_flat_work_group_size(512, 512),
                          amdgpu_waves_per_eu(2, 2)))
void k_gru(
    const float* __restrict__ xp,
    const float* __restrict__ Whhf, const float* __restrict__ Whhb,
    const float* __restrict__ bhhf, const float* __restrict__ bhhb,
    float* __restrict__ hbuf, float* __restrict__ lossp)
{
  __shared__ __align__(1024) _Float16 hsp[2][256];
  const int tid = threadIdx.x;
  const int g   = tid >> 2;       // hidden unit 0..127
  const int q   = tid & 3;        // 32-elem segment 0..3
  const int bd  = blockIdx.x;
  const int dir = bd >> 5, b = bd & 31;
  const float* Whh = dir ? Whhb : Whhf;
  const float* bhh = dir ? bhhb : bhhf;

  if (bd == 0 && tid == 0) *lossp = 0.f;

  const float br = bhh[g], bz = bhh[g + LH], bn = bhh[g + 2*LH];
  const float* wg0 = Whh + (size_t)(0*LH + g) * LH + q * 32;
  const float* wg1 = Whh + (size_t)(1*LH + g) * LH + q * 32;
  const float* wg2 = Whh + (size_t)(2*LH + g) * LH + q * 32;

  const int t0 = dir ? (T_LEN - 1) : 0;
  const int dt = dir ? -1 : 1;
  const float* px = xp + (size_t)t0 * BATCH * HID + b * HID + dir * GH + g;
  float*       ph = hbuf + (size_t)t0 * BATCH * 256 + b * 256 + dir * LH + g;

  const long long xs = (long long)dt * BATCH * HID * 4;   // xp t-stride, bytes
  const long long hs = (long long)dt * BATCH * 256 * 4;   // hbuf t-stride, bytes
  const unsigned xslo = (unsigned)(xs & 0xffffffffll);
  const int      xshi = (int)(xs >> 32);
  const unsigned hslo = (unsigned)(hs & 0xffffffffll);
  const int      hshi = (int)(hs >> 32);
  const unsigned xlo = (unsigned)(uintptr_t)px, xhi = (unsigned)((uintptr_t)px >> 32);
  const unsigned hlo = (unsigned)(uintptr_t)ph, hhi = (unsigned)((uintptr_t)ph >> 32);
  // generic AS0 shared pointers: low 32 bits = LDS byte offset.
  const unsigned rd0 = (unsigned)(uintptr_t)(&hsp[0][q * 32]);
  const unsigned wr0 = (unsigned)(uintptr_t)(&hsp[1][g]);

  if (tid < 128) reinterpret_cast<unsigned*>(&hsp[0][0])[tid] = 0u;  // zero buf0
  BAR_LGKM();

  int cnt = T_LEN;
  asm volatile(
    // ---- prologue: stage f32 weights -> v[128:223], x(t0) -> v[107:109] ----
    "global_load_dwordx4 v[128:131], %[wg0], off\n\t"
    "global_load_dwordx4 v[132:135], %[wg0], off offset:16\n\t"
    "global_load_dwordx4 v[136:139], %[wg0], off offset:32\n\t"
    "global_load_dwordx4 v[140:143], %[wg0], off offset:48\n\t"
    "global_load_dwordx4 v[144:147], %[wg0], off offset:64\n\t"
    "global_load_dwordx4 v[148:151], %[wg0], off offset:80\n\t"
    "global_load_dwordx4 v[152:155], %[wg0], off offset:96\n\t"
    "global_load_dwordx4 v[156:159], %[wg0], off offset:112\n\t"
    "global_load_dwordx4 v[160:163], %[wg1], off\n\t"
    "global_load_dwordx4 v[164:167], %[wg1], off offset:16\n\t"
    "global_load_dwordx4 v[168:171], %[wg1], off offset:32\n\t"
    "global_load_dwordx4 v[172:175], %[wg1], off offset:48\n\t"
    "global_load_dwordx4 v[176:179], %[wg1], off offset:64\n\t"
    "global_load_dwordx4 v[180:183], %[wg1], off offset:80\n\t"
    "global_load_dwordx4 v[184:187], %[wg1], off offset:96\n\t"
    "global_load_dwordx4 v[188:191], %[wg1], off offset:112\n\t"
    "global_load_dwordx4 v[192:195], %[wg2], off\n\t"
    "global_load_dwordx4 v[196:199], %[wg2], off offset:16\n\t"
    "global_load_dwordx4 v[200:203], %[wg2], off offset:32\n\t"
    "global_load_dwordx4 v[204:207], %[wg2], off offset:48\n\t"
    "global_load_dwordx4 v[208:211], %[wg2], off offset:64\n\t"
    "global_load_dwordx4 v[212:215], %[wg2], off offset:80\n\t"
    "global_load_dwordx4 v[216:219], %[wg2], off offset:96\n\t"
    "global_load_dwordx4 v[220:223], %[wg2], off offset:112\n\t"
    "v_mov_b32 v96, %[xlo]\n\t"
    "v_mov_b32 v97, %[xhi]\n\t"
    "v_mov_b32 v98, %[hlo]\n\t"
    "v_mov_b32 v99, %[hhi]\n\t"
    "v_mov_b32 v100, %[rd0]\n\t"
    "v_mov_b32 v101, %[wr0]\n\t"
    "global_load_dword v107, v[96:97], off\n\t"
    "global_load_dword v108, v[96:97], off offset:512\n\t"
    "global_load_dword v109, v[96:97], off offset:1024\n\t"
    "s_waitcnt vmcnt(3)\n\t"           // all 24 weight loads retired
    // pack 96 f32 -> 48 f16-pair regs in place
    "v_cvt_pkrtz_f16_f32 v128, v128, v129\n\t"
    "v_cvt_pkrtz_f16_f32 v129, v130, v131\n\t"
    "v_cvt_pkrtz_f16_f32 v130, v132, v133\n\t"
    "v_cvt_pkrtz_f16_f32 v131, v134, v135\n\t"
    "v_cvt_pkrtz_f16_f32 v132, v136, v137\n\t"
    "v_cvt_pkrtz_f16_f32 v133, v138, v139\n\t"
    "v_cvt_pkrtz_f16_f32 v134, v140, v141\n\t"
    "v_cvt_pkrtz_f16_f32 v135, v142, v143\n\t"
    "v_cvt_pkrtz_f16_f32 v136, v144, v145\n\t"
    "v_cvt_pkrtz_f16_f32 v137, v146, v147\n\t"
    "v_cvt_pkrtz_f16_f32 v138, v148, v149\n\t"
    "v_cvt_pkrtz_f16_f32 v139, v150, v151\n\t"
    "v_cvt_pkrtz_f16_f32 v140, v152, v153\n\t"
    "v_cvt_pkrtz_f16_f32 v141, v154, v155\n\t"
    "v_cvt_pkrtz_f16_f32 v142, v156, v157\n\t"
    "v_cvt_pkrtz_f16_f32 v143, v158, v159\n\t"
    "v_cvt_pkrtz_f16_f32 v144, v160, v161\n\t"
    "v_cvt_pkrtz_f16_f32 v145, v162, v163\n\t"
    "v_cvt_pkrtz_f16_f32 v146, v164, v165\n\t"
    "v_cvt_pkrtz_f16_f32 v147, v166, v167\n\t"
    "v_cvt_pkrtz_f16_f32 v148, v168, v169\n\t"
    "v_cvt_pkrtz_f16_f32 v149, v170, v171\n\t"
    "v_cvt_pkrtz_f16_f32 v150, v172, v173\n\t"
    "v_cvt_pkrtz_f16_f32 v151, v174, v175\n\t"
    "v_cvt_pkrtz_f16_f32 v152, v176, v177\n\t"
    "v_cvt_pkrtz_f16_f32 v153, v178, v179\n\t"
    "v_cvt_pkrtz_f16_f32 v154, v180, v181\n\t"
    "v_cvt_pkrtz_f16_f32 v155, v182, v183\n\t"
    "v_cvt_pkrtz_f16_f32 v156, v184, v185\n\t"
    "v_cvt_pkrtz_f16_f32 v157, v186, v187\n\t"
    "v_cvt_pkrtz_f16_f32 v158, v188, v189\n\t"
    "v_cvt_pkrtz_f16_f32 v159, v190, v191\n\t"
    "v_cvt_pkrtz_f16_f32 v160, v192, v193\n\t"
    "v_cvt_pkrtz_f16_f32 v161, v194, v195\n\t"
    "v_cvt_pkrtz_f16_f32 v162, v196, v197\n\t"
    "v_cvt_pkrtz_f16_f32 v163, v198, v199\n\t"
    "v_cvt_pkrtz_f16_f32 v164, v200, v201\n\t"
    "v_cvt_pkrtz_f16_f32 v165, v202, v203\n\t"
    "v_cvt_pkrtz_f16_f32 v166, v204, v205\n\t"
    "v_cvt_pkrtz_f16_f32 v167, v206, v207\n\t"
    "v_cvt_pkrtz_f16_f32 v168, v208, v209\n\t"
    "v_cvt_pkrtz_f16_f32 v169, v210, v211\n\t"
    "v_cvt_pkrtz_f16_f32 v170, v212, v213\n\t"
    "v_cvt_pkrtz_f16_f32 v171, v214, v215\n\t"
    "v_cvt_pkrtz_f16_f32 v172, v216, v217\n\t"
    "v_cvt_pkrtz_f16_f32 v173, v218, v219\n\t"
    "v_cvt_pkrtz_f16_f32 v174, v220, v221\n\t"
    "v_cvt_pkrtz_f16_f32 v175, v222, v223\n\t"
    "v_mov_b32 v110, 0\n\t"
    "s_waitcnt vmcnt(0)\n\t"           // x(t0) trio arrived
    // ---- main loop: one step per iteration ----
    "0:\n\t"
    "s_waitcnt vmcnt(1)\n\t"           // prev-issued x trio retired (store may fly)
    "v_mov_b32 v104, v107\n\t"
    "v_mov_b32 v105, v108\n\t"
    "v_mov_b32 v106, v109\n\t"
    "ds_read_b128 v[176:179], v100\n\t"
    "ds_read_b128 v[180:183], v100 offset:16\n\t"
    "ds_read_b128 v[184:187], v100 offset:32\n\t"
    "ds_read_b128 v[188:191], v100 offset:48\n\t"
    "s_cmp_gt_u32 %[cnt], 1\n\t"       // skip pointer advance on last step
    "s_cbranch_scc0 3f\n\t"
    "v_add_co_u32 v96, vcc, %[xslo], v96\n\t"
    "v_addc_co_u32 v97, vcc, %[xshi], v97, vcc\n\t"
    "3:\n\t"
    "global_load_dword v107, v[96:97], off\n\t"
    "global_load_dword v108, v[96:97], off offset:512\n\t"
    "global_load_dword v109, v[96:97], off offset:1024\n\t"
    "s_waitcnt lgkmcnt(0)\n\t"
    // dot2 matvec: 48 v_dot2_f32_f16, 2 accs/gate, gates interleaved (ILP)
    "v_mov_b32 v116, 0\n\t"
    "v_mov_b32 v117, 0\n\t"
    "v_mov_b32 v118, 0\n\t"
    "v_mov_b32 v119, 0\n\t"
    "v_mov_b32 v120, 0\n\t"
    "v_mov_b32 v121, 0\n\t"
    "v_dot2_f32_f16 v116, v128, v176, v116\n\t"
    "v_dot2_f32_f16 v118, v144, v176, v118\n\t"
    "v_dot2_f32_f16 v120, v160, v176, v120\n\t"
    "v_dot2_f32_f16 v117, v129, v177, v117\n\t"
    "v_dot2_f32_f16 v119, v145, v177, v119\n\t"
    "v_dot2_f32_f16 v121, v161, v177, v121\n\t"
    "v_dot2_f32_f16 v116, v130, v178, v116\n\t"
    "v_dot2_f32_f16 v118, v146, v178, v118\n\t"
    "v_dot2_f32_f16 v120, v162, v178, v120\n\t"
    "v_dot2_f32_f16 v117, v131, v179, v117\n\t"
    "v_dot2_f32_f16 v119, v147, v179, v119\n\t"
    "v_dot2_f32_f16 v121, v163, v179, v121\n\t"
    "v_dot2_f32_f16 v116, v132, v180, v116\n\t"
    "v_dot2_f32_f16 v118, v148, v180, v118\n\t"
    "v_dot2_f32_f16 v120, v164, v180, v120\n\t"
    "v_dot2_f32_f16 v117, v133, v181, v117\n\t"
    "v_dot2_f32_f16 v119, v149, v181, v119\n\t"
    "v_dot2_f32_f16 v121, v165, v181, v121\n\t"
    "v_dot2_f32_f16 v116, v134, v182, v116\n\t"
    "v_dot2_f32_f16 v118, v150, v182, v118\n\t"
    "v_dot2_f32_f16 v120, v166, v182, v120\n\t"
    "v_dot2_f32_f16 v117, v135, v183, v117\n\t"
    "v_dot2_f32_f16 v119, v151, v183, v119\n\t"
    "v_dot2_f32_f16 v121, v167, v183, v121\n\t"
    "v_dot2_f32_f16 v116, v136, v184, v116\n\t"
    "v_dot2_f32_f16 v118, v152, v184, v118\n\t"
    "v_dot2_f32_f16 v120, v168, v184, v120\n\t"
    "v_dot2_f32_f16 v117, v137, v185, v117\n\t"
    "v_dot2_f32_f16 v119, v153, v185, v119\n\t"
    "v_dot2_f32_f16 v121, v169, v185, v121\n\t"
    "v_dot2_f32_f16 v116, v138, v186, v116\n\t"
    "v_dot2_f32_f16 v118, v154, v186, v118\n\t"
    "v_dot2_f32_f16 v120, v170, v186, v120\n\t"
    "v_dot2_f32_f16 v117, v139, v187, v117\n\t"
    "v_dot2_f32_f16 v119, v155, v187, v119\n\t"
    "v_dot2_f32_f16 v121, v171, v187, v121\n\t"
    "v_dot2_f32_f16 v116, v140, v188, v116\n\t"
    "v_dot2_f32_f16 v118, v156, v188, v118\n\t"
    "v_dot2_f32_f16 v120, v172, v188, v120\n\t"
    "v_dot2_f32_f16 v117, v141, v189, v117\n\t"
    "v_dot2_f32_f16 v119, v157, v189, v119\n\t"
    "v_dot2_f32_f16 v121, v173, v189, v121\n\t"
    "v_dot2_f32_f16 v116, v142, v190, v116\n\t"
    "v_dot2_f32_f16 v118, v158, v190, v118\n\t"
    "v_dot2_f32_f16 v120, v174, v190, v120\n\t"
    "v_dot2_f32_f16 v117, v143, v191, v117\n\t"
    "v_dot2_f32_f16 v119, v159, v191, v119\n\t"
    "v_dot2_f32_f16 v121, v175, v191, v121\n\t"
    // horizontal: r->v116, z->v118, n->v120
    "v_add_f32 v116, v116, v117\n\t"
    "v_add_f32 v118, v118, v119\n\t"
    "v_add_f32 v120, v120, v121\n\t"
    // quad butterfly: xor1, xor2 (proven v9 pattern)
    "ds_swizzle_b32 v111, v116 offset:0x041F\n\t"
    "ds_swizzle_b32 v112, v118 offset:0x041F\n\t"
    "ds_swizzle_b32 v113, v120 offset:0x041F\n\t"
    "s_waitcnt lgkmcnt(0)\n\t"
    "v_add_f32 v116, v116, v111\n\t"
    "v_add_f32 v118, v118, v112\n\t"
    "v_add_f32 v120, v120, v113\n\t"
    "ds_swizzle_b32 v111, v116 offset:0x081F\n\t"
    "ds_swizzle_b32 v112, v118 offset:0x081F\n\t"
    "ds_swizzle_b32 v113, v120 offset:0x081F\n\t"
    "s_waitcnt lgkmcnt(0)\n\t"
    "v_add_f32 v116, v116, v111\n\t"
    "v_add_f32 v118, v118, v112\n\t"
    "v_add_f32 v120, v120, v113\n\t"
    // ---- gates (v9 hazard-safe interleave; z=v118, n=v120) ----
    "v_add_f32 v111, v104, v116\n\t"
    "v_add_f32 v112, v105, v118\n\t"
    "v_add_f32 v113, v120, %[bn]\n\t"
    "v_add_f32 v111, v111, %[br]\n\t"
    "v_add_f32 v112, v112, %[bz]\n\t"
    "v_mul_f32 v111, 0xbfb8aa3b, v111\n\t"
    "v_mul_f32 v112, 0xbfb8aa3b, v112\n\t"
    "v_exp_f32 v111, v111\n\t"
    "v_exp_f32 v112, v112\n\t"
    "s_nop 0\n\t"
    "v_add_f32 v111, 1.0, v111\n\t"
    "v_add_f32 v112, 1.0, v112\n\t"
    "v_rcp_f32 v111, v111\n\t"
    "v_rcp_f32 v112, v112\n\t"
    "s_nop 0\n\t"
    "v_fmac_f32 v106, v111, v113\n\t"
    "v_mul_f32 v113, 0x4038aa3b, v106\n\t"
    "v_exp_f32 v113, v113\n\t"
    "v_sub_f32 v115, 1.0, v112\n\t"
    "s_nop 0\n\t"
    "v_add_f32 v114, -1.0, v113\n\t"
    "v_add_f32 v113, 1.0, v113\n\t"
    "v_rcp_f32 v113, v113\n\t"
    "s_nop 1\n\t"
    "v_mul_f32 v114, v114, v113\n\t"
    "v_mul_f32 v115, v115, v114\n\t"
    "v_fmac_f32 v115, v112, v110\n\t"
    "v_mov_b32 v110, v115\n\t"
    // store h: f16 -> LDS (next parity), f32 -> hbuf
    "v_cvt_f16_f32 v114, v115\n\t"
    "global_store_dword v[98:99], v115, off\n\t"
    "v_add_co_u32 v98, vcc, %[hslo], v98\n\t"
    "v_addc_co_u32 v99, vcc, %[hshi], v99, vcc\n\t"
    "ds_write_b16 v101, v114\n\t"
    "v_xor_b32 v100, 0x200, v100\n\t"
    "v_xor_b32 v101, 0x200, v101\n\t"
    "s_waitcnt lgkmcnt(0)\n\t"
    "s_barrier\n\t"
    "s_sub_u32 %[cnt], %[cnt], 1\n\t"
    "s_cmp_lg_u32 %[cnt], 0\n\t"
    "s_cbranch_scc1 0b\n\t"
    : [cnt]"+s"(cnt)
    : [wg0]"v"(wg0), [wg1]"v"(wg1), [wg2]"v"(wg2),
      [xlo]"v"(xlo), [xhi]"v"(xhi), [hlo]"v"(hlo), [hhi]"v"(hhi),
      [rd0]"v"(rd0), [wr0]"v"(wr0),
      [br]"v"(br), [bz]"v"(bz), [bn]"v"(bn),
      [xslo]"s"(xslo), [xshi]"v"(xshi), [hslo]"s"(hslo), [hshi]"v"(hshi)
    : "memory", "vcc", "scc",
      "v96","v97","v98","v99","v100","v101","v102","v103","v104","v105",
      "v106","v107","v108","v109","v110","v111","v112","v113","v114","v115",
      "v116","v117","v118","v119","v120","v121","v122","v123","v124","v125",
      "v126","v127","v128","v129","v130","v131","v132","v133","v134","v135",
      "v136","v137","v138","v139","v140","v141","v142","v143","v144","v145",
      "v146","v147","v148","v149","v150","v151","v152","v153","v154","v155",
      "v156","v157","v158","v159","v160","v161","v162","v163","v164","v165",
      "v166","v167","v168","v169","v170","v171","v172","v173","v174","v175",
      "v176","v177","v178","v179","v180","v181","v182","v183","v184","v185",
      "v186","v187","v188","v189","v190","v191","v192","v193","v194","v195",
      "v196","v197","v198","v199","v200","v201","v202","v203","v204","v205",
      "v206","v207","v208","v209","v210","v211","v212","v213","v214","v215",
      "v216","v217","v218","v219","v220","v221","v222","v223");
}

// ---------------- K3: fused emissions + Viterbi + CRF-LLH (v2) --------------
__global__ __launch_bounds__(256, 1) void k_crf_fused(
    const float* __restrict__ hbuf, const float* __restrict__ Wlin,
    const float* __restrict__ blin, const int* __restrict__ labels,
    const float* __restrict__ trans, const float* __restrict__ start,
    const float* __restrict__ endv, float* __restrict__ dec_out,
    float* __restrict__ lossp)
{
  __shared__ float el[T_LEN * 10];
  __shared__ __align__(16) unsigned char bp8[(T_LEN - 1) * 16];
  const int b    = blockIdx.x;
  const int tid  = threadIdx.x;
  const int lane = tid & 63, w = tid >> 6;
  const int sub  = lane >> 4, l16 = lane & 15;

  float4 wreg[NLAB][4];
#pragma unroll
  for (int j = 0; j < NLAB; ++j)
#pragma unroll
    for (int c = 0; c < 4; ++c)
      wreg[j][c] = *reinterpret_cast<const float4*>(Wlin + j * 256 + l16 * 16 + c * 4);

  // ---- phase 1: emissions ----
  for (int k = 0; k < 16; ++k) {
    const int t = w * 64 + k * 4 + sub;
    const float* hp = hbuf + ((size_t)t * BATCH + b) * 256 + l16 * 16;
    const float4 h0 = *reinterpret_cast<const float4*>(hp);
    const float4 h1 = *reinterpret_cast<const float4*>(hp + 4);
    const float4 h2 = *reinterpret_cast<const float4*>(hp + 8);
    const float4 h3 = *reinterpret_cast<const float4*>(hp + 12);
    float acc[NLAB];
#pragma unroll
    for (int j = 0; j < NLAB; ++j) {
      const float4 w0 = wreg[j][0], w1 = wreg[j][1], w2 = wreg[j][2], w3 = wreg[j][3];
      float s0 = h0.x*w0.x + h0.y*w0.y + h0.z*w0.z + h0.w*w0.w;
      float s1 = h1.x*w1.x + h1.y*w1.y + h1.z*w1.z + h1.w*w1.w;
      float s2 = h2.x*w2.x + h2.y*w2.y + h2.z*w2.z + h2.w*w2.w;
      float s3 = h3.x*w3.x + h3.y*w3.y + h3.z*w3.z + h3.w*w3.w;
      acc[j] = (s0 + s1) + (s2 + s3);
    }
#pragma unroll
    for (int j = 0; j < NLAB; ++j) {
#pragma unroll
      for (int off = 1; off < 16; off <<= 1)
        acc[j] += __shfl_xor(acc[j], off);
    }
    if (l16 < NLAB) {
      float v = acc[0];
#pragma unroll
      for (int j = 1; j < NLAB; ++j) v = (l16 == j) ? acc[j] : v;
      el[t * 10 + l16] = v + blin[l16];
    }
  }
  __syncthreads();

  if (w == 0) {
    // ---- Viterbi ----
    float tcol[NLAB];
#pragma unroll
    for (int i = 0; i < NLAB; ++i)
      tcol[i] = (lane < NLAB) ? trans[i * NLAB + lane] : 0.f;
    float alpha = (lane < NLAB) ? (start[lane] + el[lane]) : -3e38f;
    float et_next = (lane < NLAB) ? el[10 + lane] : 0.f;
    for (int s = 0; s < T_LEN - 1; ++s) {
      const float et = et_next;
      if (s < T_LEN - 2)
        et_next = (lane < NLAB) ? el[(s + 2) * 10 + lane] : 0.f;
      float v[NLAB];
      v[0] = BC(alpha, 0) + tcol[0];
      v[1] = BC(alpha, 1) + tcol[1];
      v[2] = BC(alpha, 2) + tcol[2];
      v[3] = BC(alpha, 3) + tcol[3];
      v[4] = BC(alpha, 4) + tcol[4];
      v[5] = BC(alpha, 5) + tcol[5];
      v[6] = BC(alpha, 6) + tcol[6];
      v[7] = BC(alpha, 7) + tcol[7];
      v[8] = BC(alpha, 8) + tcol[8];
      float v01 = (v[0] >= v[1]) ? v[0] : v[1];  int i01 = (v[0] >= v[1]) ? 0 : 1;
      float v23 = (v[2] >= v[3]) ? v[2] : v[3];  int i23 = (v[2] >= v[3]) ? 2 : 3;
      float v45 = (v[4] >= v[5]) ? v[4] : v[5];  int i45 = (v[4] >= v[5]) ? 4 : 5;
      float v67 = (v[6] >= v[7]) ? v[6] : v[7];  int i67 = (v[6] >= v[7]) ? 6 : 7;
      float va = (v01 >= v23) ? v01 : v23;       int ia = (v01 >= v23) ? i01 : i23;
      float vb = (v45 >= v67) ? v45 : v67;       int ib = (v45 >= v67) ? i45 : i67;
      float vc = (va >= vb) ? va : vb;           int ic = (va >= vb) ? ia : ib;
      float best = (vc >= v[8]) ? vc : v[8];     int bi = (vc >= v[8]) ? ic : 8;
      alpha = best + et;
      if (lane < NLAB) bp8[s * 16 + lane] = (unsigned char)bi;
    }
    float fin = alpha + ((lane < NLAB) ? endv[lane] : 0.f);
    float fv[NLAB];
    fv[0] = BC(fin, 0); fv[1] = BC(fin, 1); fv[2] = BC(fin, 2);
    fv[3] = BC(fin, 3); fv[4] = BC(fin, 4); fv[5] = BC(fin, 5);
    fv[6] = BC(fin, 6); fv[7] = BC(fin, 7); fv[8] = BC(fin, 8);
    float f01 = (fv[0] >= fv[1]) ? fv[0] : fv[1];  int j01 = (fv[0] >= fv[1]) ? 0 : 1;
    float f23 = (fv[2] >= fv[3]) ? fv[2] : fv[3];  int j23 = (fv[2] >= fv[3]) ? 2 : 3;
    float f45 = (fv[4] >= fv[5]) ? fv[4] : fv[5];  int j45 = (fv[4] >= fv[5]) ? 4 : 5;
    float f67 = (fv[6] >= fv[7]) ? fv[6] : fv[7];  int j67 = (fv[6] >= fv[7]) ? 6 : 7;
    float fa = (f01 >= f23) ? f01 : f23;           int ja = (f01 >= f23) ? j01 : j23;
    float fb = (f45 >= f67) ? f45 : f67;           int jb = (f45 >= f67) ? j45 : j67;
    float fc = (fa >= fb) ? fa : fb;               int jc = (fa >= fb) ? ja : jb;
    int last = (fc >= fv[8]) ? jc : 8;
    if (lane == 0) {
      int y = last;
      dec_out[b * T_LEN + (T_LEN - 1)] = (float)y;
      uint4 row = *reinterpret_cast<const uint4*>(&bp8[(T_LEN - 2) * 16]);
      for (int s = T_LEN - 2; s >= 0; --s) {
        uint4 nrow = row;
        if (s > 0) nrow = *reinterpret_cast<const uint4*>(&bp8[(s - 1) * 16]);
        unsigned wsel = (y < 4) ? row.x : ((y < 8) ? row.y : row.z);
        y = (int)((wsel >> ((y & 3) * 8)) & 0xffu);
        dec_out[b * T_LEN + s] = (float)y;
        row = nrow;
      }
    }
  } else if (w == 1) {
    // ---- CRF log-likelihood ----
    float tcol[NLAB];
#pragma unroll
    for (int i = 0; i < NLAB; ++i)
      tcol[i] = (lane < NLAB) ? trans[i * NLAB + lane] : 0.f;
    float ca = (lane < NLAB) ? (start[lane] + el[lane]) : -3e38f;
    float et_next = (lane < NLAB) ? el[10 + lane] : 0.f;
    for (int s = 0; s < T_LEN - 1; ++s) {
      const float et = et_next;
      if (s < T_LEN - 2)
        et_next = (lane < NLAB) ? el[(s + 2) * 10 + lane] : 0.f;
      float c[NLAB];
      c[0] = BC(ca, 0) + tcol[0];
      c[1] = BC(ca, 1) + tcol[1];
      c[2] = BC(ca, 2) + tcol[2];
      c[3] = BC(ca, 3) + tcol[3];
      c[4] = BC(ca, 4) + tcol[4];
      c[5] = BC(ca, 5) + tcol[5];
      c[6] = BC(ca, 6) + tcol[6];
      c[7] = BC(ca, 7) + tcol[7];
      c[8] = BC(ca, 8) + tcol[8];
      float m01 = fmaxf(c[0], c[1]), m23 = fmaxf(c[2], c[3]);
      float m45 = fmaxf(c[4], c[5]), m67 = fmaxf(c[6], c[7]);
      float m = fmaxf(fmaxf(fmaxf(m01, m23), fmaxf(m45, m67)), c[8]);
      float p0 = __expf(c[0]-m) + __expf(c[1]-m), p1 = __expf(c[2]-m) + __expf(c[3]-m);
      float p2 = __expf(c[4]-m) + __expf(c[5]-m), p3 = __expf(c[6]-m) + __expf(c[7]-m);
      float p = ((p0 + p1) + (p2 + p3)) + __expf(c[8]-m);
      ca = m + __logf(p) + et;
    }
    float fv[NLAB];
    fv[0] = BC(ca, 0) + endv[0];
    fv[1] = BC(ca, 1) + endv[1];
    fv[2] = BC(ca, 2) + endv[2];
    fv[3] = BC(ca, 3) + endv[3];
    fv[4] = BC(ca, 4) + endv[4];
    fv[5] = BC(ca, 5) + endv[5];
    fv[6] = BC(ca, 6) + endv[6];
    fv[7] = BC(ca, 7) + endv[7];
    fv[8] = BC(ca, 8) + endv[8];
    float mx = -3e38f;
#pragma unroll
    for (int j = 0; j < NLAB; ++j) mx = fmaxf(mx, fv[j]);
    float ps = 0.f;
#pragma unroll
    for (int j = 0; j < NLAB; ++j) ps += __expf(fv[j] - mx);
    float denom = mx + __logf(ps);

    const int* lb = labels + b * T_LEN;
    float part = 0.f;
    for (int t4 = 0; t4 < 4; ++t4) {
      int t = lane * 4 + t4;
      int l = lb[t];
      part += el[t * 10 + l];
      if (t > 0) part += trans[lb[t - 1] * NLAB + l];
    }
#pragma unroll
    for (int off = 32; off > 0; off >>= 1) part += __shfl_xor(part, off);
    if (lane == 0) {
      float num = part + start[lb[0]] + endv[lb[T_LEN - 1]];
      float llh = num - denom;
      atomicAdd(lossp, -llh * (1.0f / BATCH));
    }
  }
}

extern "C" void kernel_launch(void* const* d_in, const int* in_sizes, int n_in,
                              void* d_out, int out_size, void* d_ws, size_t ws_size,
                              hipStream_t stream) {
  const int*   ids    = (const int*)d_in[0];
  const int*   labels = (const int*)d_in[2];
  const float* emb    = (const float*)d_in[3];
  const float* Wihf   = (const float*)d_in[4];
  const float* Whhf   = (const float*)d_in[5];
  const float* bihf   = (const float*)d_in[6];
  const float* bhhf   = (const float*)d_in[7];
  const float* Wihb   = (const float*)d_in[8];
  const float* Whhb   = (const float*)d_in[9];
  const float* bihb   = (const float*)d_in[10];
  const float* bhhb   = (const float*)d_in[11];
  const float* Wlin   = (const float*)d_in[12];
  const float* blin   = (const float*)d_in[13];
  const float* trans  = (const float*)d_in[14];
  const float* start  = (const float*)d_in[15];
  const float* endv   = (const float*)d_in[16];

  float* xp    = (float*)d_ws;                       // [T][B][768]
  float* hbuf  = xp + (size_t)M_TOT * HID;           // [T][B][256]
  float* out   = (float*)d_out;                      // decoded as floats
  float* lossp = out + M_TOT;                        // loss scalar

  k_gemm_xp<<<dim3(6, 64), 256, 0, stream>>>(ids, emb, Wihf, Wihb, bihf, bihb, xp);
  k_gru<<<64, 512, 0, stream>>>(xp, Whhf, Whhb, bhhf, bhhb, hbuf, lossp);
  k_crf_fused<<<BATCH, 256, 0, stream>>>(hbuf, Wlin, blin, labels, trans,
                                         start, endv, out, lossp);
}

// Round 10
// 359.996 us; speedup vs baseline: 1.1246x; 1.0426x over previous
//
#include <hip/hip_runtime.h>
#include <math.h>

#define T_LEN 256
#define BATCH 32
#define HID   768
#define GH    384   // 3*LSTM_H
#define LH    128   // LSTM_H
#define NLAB  9
#define M_TOT (T_LEN*BATCH)  // 8192

typedef float v2f __attribute__((ext_vector_type(2)));
typedef _Float16 h8 __attribute__((ext_vector_type(8)));
typedef float f4 __attribute__((ext_vector_type(4)));

// Immediate-pattern lane broadcast within 32-lane half: every lane reads lane i.
#define BC(x, i) __int_as_float(__builtin_amdgcn_ds_swizzle(__float_as_int(x), (i) << 5))

// Raw barrier with LDS-only drain (no vmcnt stall on in-flight prefetch/stores).
#define BAR_LGKM() do {                                   \
    asm volatile("s_waitcnt lgkmcnt(0)" ::: "memory");    \
    __builtin_amdgcn_s_barrier();                         \
    asm volatile("" ::: "memory");                        \
  } while (0)

// ---------------- K1: xp = emb[ids] @ [Wih_f;Wih_b]^T + bias  (v7 pure f16) -
// Pure f16 single-MFMA path (r9: hi/lo split removed; measured -9µs, passed
// absmax 0.0 — K1 is now ~10-25µs total). Frozen.
__global__ __launch_bounds__(256, 2) void k_gemm_xp(
    const int* __restrict__ ids, const float* __restrict__ emb,
    const float* __restrict__ Wf, const float* __restrict__ Wb,
    const float* __restrict__ bihf, const float* __restrict__ bihb,
    float* __restrict__ xp)
{
  __shared__ __align__(16) _Float16 Ah[128*40];
  __shared__ __align__(16) _Float16 Bh[128*40];

  const int tid  = threadIdx.x;
  const int lane = tid & 63, w = tid >> 6;
  const int m0 = blockIdx.y * 128, n0 = blockIdx.x * 128;

  const int srow = tid >> 1, sk = (tid & 1) * 16;
  const int gm = m0 + srow;
  const int tok = ids[(gm & 31) * T_LEN + (gm >> 5)];
  const float* aG = emb + (size_t)tok * HID + sk;
  const int gn = n0 + srow;
  const float* bG = (gn < GH ? Wf + (size_t)gn * HID
                             : Wb + (size_t)(gn - GH) * HID) + sk;

  const int fr = lane & 15, fq = lane >> 4;
  const int mrow = (w & 1) * 64;
  const int ncol = (w >> 1) * 64;

  f4 acc[4][4];
#pragma unroll
  for (int i = 0; i < 4; ++i)
#pragma unroll
    for (int j = 0; j < 4; ++j) acc[i][j] = f4{0,0,0,0};

  const int sb = srow * 40 + sk;

  float4 ra[4], rb[4];
#pragma unroll
  for (int c = 0; c < 4; ++c) {
    ra[c] = *reinterpret_cast<const float4*>(aG + 4 * c);
    rb[c] = *reinterpret_cast<const float4*>(bG + 4 * c);
  }

  for (int kt = 0; kt < HID / 32; ++kt) {
    BAR_LGKM();
    // convert current regs -> LDS (f16, round-to-nearest via cast)
#pragma unroll
    for (int m = 0; m < 2; ++m) {
      const float4* src = m ? rb : ra;
      _Float16* dsth = m ? Bh : Ah;
#pragma unroll
      for (int seg = 0; seg < 2; ++seg) {
        float xs[8] = {src[2*seg].x, src[2*seg].y, src[2*seg].z, src[2*seg].w,
                       src[2*seg+1].x, src[2*seg+1].y, src[2*seg+1].z, src[2*seg+1].w};
        h8 hi;
#pragma unroll
        for (int c = 0; c < 8; ++c) hi[c] = (_Float16)xs[c];
        *reinterpret_cast<h8*>(&dsth[sb + seg * 8]) = hi;
      }
    }
    // prefetch next tile — stays in flight across BAR_LGKM (no vmcnt drain)
    if (kt + 1 < HID / 32) {
      const float* pa = aG + (kt + 1) * 32;
      const float* pb = bG + (kt + 1) * 32;
#pragma unroll
      for (int c = 0; c < 4; ++c) {
        ra[c] = *reinterpret_cast<const float4*>(pa + 4 * c);
        rb[c] = *reinterpret_cast<const float4*>(pb + 4 * c);
      }
    }
    BAR_LGKM();

    h8 fbh[4];
#pragma unroll
    for (int j = 0; j < 4; ++j) {
      const int off = (ncol + j * 16 + fr) * 40 + fq * 8;
      fbh[j] = *reinterpret_cast<const h8*>(&Bh[off]);
    }
#pragma unroll
    for (int i = 0; i < 4; ++i) {
      const int off = (mrow + i * 16 + fr) * 40 + fq * 8;
      h8 fah = *reinterpret_cast<const h8*>(&Ah[off]);
#pragma unroll
      for (int j = 0; j < 4; ++j)
        acc[i][j] = __builtin_amdgcn_mfma_f32_16x16x32_f16(fah, fbh[j], acc[i][j], 0, 0, 0);
    }
  }

  float bcol[4];
#pragma unroll
  for (int j = 0; j < 4; ++j) {
    const int c = n0 + ncol + j * 16 + fr;
    bcol[j] = (c < GH) ? bihf[c] : bihb[c - GH];
  }
#pragma unroll
  for (int i = 0; i < 4; ++i)
#pragma unroll
    for (int j = 0; j < 4; ++j) {
      const int col = n0 + ncol + j * 16 + fr;
#pragma unroll
      for (int r = 0; r < 4; ++r) {
        const int row = m0 + mrow + i * 16 + fq * 4 + r;
        xp[(size_t)row * HID + col] = acc[i][j][r] + bcol[j];
      }
    }
}

// ---------------- K2: bidirectional GRU recurrence (v12 — DPP reduce) -------
// v11 chain accounting (1430 cy/step measured, ~550 busy): barrier ->
// ds_read wait (~120) -> dot2 (~100) -> TWO ds_swizzle reduce waits (~240)
// -> trans gate chain (~110) -> write -> barrier. v12 replaces the two
// swizzle levels with fused DPP quad_perm adds (VALU-speed, no lgkm wait),
// cutting ~240-300 cy of LDS latency from the serial chain. DPP hazard
// (VALU-write -> DPP-read needs 2 wait states) is covered by interleaving
// r/z/n plus s_nop 1 at every producer->consumer edge (r5 lesson: manual
// wait states are real). Everything else is byte-identical to v11.
__global__ __attribute__((amdgpu_flat_work_group_size(512, 512),
                          amdgpu_waves_per_eu(2, 2)))
void k_gru(
    const float* __restrict__ xp,
    const float* __restrict__ Whhf, const float* __restrict__ Whhb,
    const float* __restrict__ bhhf, const float* __restrict__ bhhb,
    float* __restrict__ hbuf, float* __restrict__ lossp)
{
  __shared__ __align__(1024) _Float16 hsp[2][256];
  const int tid = threadIdx.x;
  const int g   = tid >> 2;       // hidden unit 0..127
  const int q   = tid & 3;        // 32-elem segment 0..3
  const int bd  = blockIdx.x;
  const int dir = bd >> 5, b = bd & 31;
  const float* Whh = dir ? Whhb : Whhf;
  const float* bhh = dir ? bhhb : bhhf;

  if (bd == 0 && tid == 0) *lossp = 0.f;

  const float br = bhh[g], bz = bhh[g + LH], bn = bhh[g + 2*LH];
  const float* wg0 = Whh + (size_t)(0*LH + g) * LH + q * 32;
  const float* wg1 = Whh + (size_t)(1*LH + g) * LH + q * 32;
  const float* wg2 = Whh + (size_t)(2*LH + g) * LH + q * 32;

  const int t0 = dir ? (T_LEN - 1) : 0;
  const int dt = dir ? -1 : 1;
  const float* px = xp + (size_t)t0 * BATCH * HID + b * HID + dir * GH + g;
  float*       ph = hbuf + (size_t)t0 * BATCH * 256 + b * 256 + dir * LH + g;

  const long long xs = (long long)dt * BATCH * HID * 4;   // xp t-stride, bytes
  const long long hs = (long long)dt * BATCH * 256 * 4;   // hbuf t-stride, bytes
  const unsigned xslo = (unsigned)(xs & 0xffffffffll);
  const int      xshi = (int)(xs >> 32);
  const unsigned hslo = (unsigned)(hs & 0xffffffffll);
  const int      hshi = (int)(hs >> 32);
  const unsigned xlo = (unsigned)(uintptr_t)px, xhi = (unsigned)((uintptr_t)px >> 32);
  const unsigned hlo = (unsigned)(uintptr_t)ph, hhi = (unsigned)((uintptr_t)ph >> 32);
  // generic AS0 shared pointers: low 32 bits = LDS byte offset.
  const unsigned rd0 = (unsigned)(uintptr_t)(&hsp[0][q * 32]);
  const unsigned wr0 = (unsigned)(uintptr_t)(&hsp[1][g]);

  if (tid < 128) reinterpret_cast<unsigned*>(&hsp[0][0])[tid] = 0u;  // zero buf0
  BAR_LGKM();

  int cnt = T_LEN;
  asm volatile(
    // ---- prologue: stage f32 weights -> v[128:223], x(t0) -> v[107:109] ----
    "global_load_dwordx4 v[128:131], %[wg0], off\n\t"
    "global_load_dwordx4 v[132:135], %[wg0], off offset:16\n\t"
    "global_load_dwordx4 v[136:139], %[wg0], off offset:32\n\t"
    "global_load_dwordx4 v[140:143], %[wg0], off offset:48\n\t"
    "global_load_dwordx4 v[144:147], %[wg0], off offset:64\n\t"
    "global_load_dwordx4 v[148:151], %[wg0], off offset:80\n\t"
    "global_load_dwordx4 v[152:155], %[wg0], off offset:96\n\t"
    "global_load_dwordx4 v[156:159], %[wg0], off offset:112\n\t"
    "global_load_dwordx4 v[160:163], %[wg1], off\n\t"
    "global_load_dwordx4 v[164:167], %[wg1], off offset:16\n\t"
    "global_load_dwordx4 v[168:171], %[wg1], off offset:32\n\t"
    "global_load_dwordx4 v[172:175], %[wg1], off offset:48\n\t"
    "global_load_dwordx4 v[176:179], %[wg1], off offset:64\n\t"
    "global_load_dwordx4 v[180:183], %[wg1], off offset:80\n\t"
    "global_load_dwordx4 v[184:187], %[wg1], off offset:96\n\t"
    "global_load_dwordx4 v[188:191], %[wg1], off offset:112\n\t"
    "global_load_dwordx4 v[192:195], %[wg2], off\n\t"
    "global_load_dwordx4 v[196:199], %[wg2], off offset:16\n\t"
    "global_load_dwordx4 v[200:203], %[wg2], off offset:32\n\t"
    "global_load_dwordx4 v[204:207], %[wg2], off offset:48\n\t"
    "global_load_dwordx4 v[208:211], %[wg2], off offset:64\n\t"
    "global_load_dwordx4 v[212:215], %[wg2], off offset:80\n\t"
    "global_load_dwordx4 v[216:219], %[wg2], off offset:96\n\t"
    "global_load_dwordx4 v[220:223], %[wg2], off offset:112\n\t"
    "v_mov_b32 v96, %[xlo]\n\t"
    "v_mov_b32 v97, %[xhi]\n\t"
    "v_mov_b32 v98, %[hlo]\n\t"
    "v_mov_b32 v99, %[hhi]\n\t"
    "v_mov_b32 v100, %[rd0]\n\t"
    "v_mov_b32 v101, %[wr0]\n\t"
    "global_load_dword v107, v[96:97], off\n\t"
    "global_load_dword v108, v[96:97], off offset:512\n\t"
    "global_load_dword v109, v[96:97], off offset:1024\n\t"
    "s_waitcnt vmcnt(3)\n\t"           // all 24 weight loads retired
    // pack 96 f32 -> 48 f16-pair regs in place
    "v_cvt_pkrtz_f16_f32 v128, v128, v129\n\t"
    "v_cvt_pkrtz_f16_f32 v129, v130, v131\n\t"
    "v_cvt_pkrtz_f16_f32 v130, v132, v133\n\t"
    "v_cvt_pkrtz_f16_f32 v131, v134, v135\n\t"
    "v_cvt_pkrtz_f16_f32 v132, v136, v137\n\t"
    "v_cvt_pkrtz_f16_f32 v133, v138, v139\n\t"
    "v_cvt_pkrtz_f16_f32 v134, v140, v141\n\t"
    "v_cvt_pkrtz_f16_f32 v135, v142, v143\n\t"
    "v_cvt_pkrtz_f16_f32 v136, v144, v145\n\t"
    "v_cvt_pkrtz_f16_f32 v137, v146, v147\n\t"
    "v_cvt_pkrtz_f16_f32 v138, v148, v149\n\t"
    "v_cvt_pkrtz_f16_f32 v139, v150, v151\n\t"
    "v_cvt_pkrtz_f16_f32 v140, v152, v153\n\t"
    "v_cvt_pkrtz_f16_f32 v141, v154, v155\n\t"
    "v_cvt_pkrtz_f16_f32 v142, v156, v157\n\t"
    "v_cvt_pkrtz_f16_f32 v143, v158, v159\n\t"
    "v_cvt_pkrtz_f16_f32 v144, v160, v161\n\t"
    "v_cvt_pkrtz_f16_f32 v145, v162, v163\n\t"
    "v_cvt_pkrtz_f16_f32 v146, v164, v165\n\t"
    "v_cvt_pkrtz_f16_f32 v147, v166, v167\n\t"
    "v_cvt_pkrtz_f16_f32 v148, v168, v169\n\t"
    "v_cvt_pkrtz_f16_f32 v149, v170, v171\n\t"
    "v_cvt_pkrtz_f16_f32 v150, v172, v173\n\t"
    "v_cvt_pkrtz_f16_f32 v151, v174, v175\n\t"
    "v_cvt_pkrtz_f16_f32 v152, v176, v177\n\t"
    "v_cvt_pkrtz_f16_f32 v153, v178, v179\n\t"
    "v_cvt_pkrtz_f16_f32 v154, v180, v181\n\t"
    "v_cvt_pkrtz_f16_f32 v155, v182, v183\n\t"
    "v_cvt_pkrtz_f16_f32 v156, v184, v185\n\t"
    "v_cvt_pkrtz_f16_f32 v157, v186, v187\n\t"
    "v_cvt_pkrtz_f16_f32 v158, v188, v189\n\t"
    "v_cvt_pkrtz_f16_f32 v159, v190, v191\n\t"
    "v_cvt_pkrtz_f16_f32 v160, v192, v193\n\t"
    "v_cvt_pkrtz_f16_f32 v161, v194, v195\n\t"
    "v_cvt_pkrtz_f16_f32 v162, v196, v197\n\t"
    "v_cvt_pkrtz_f16_f32 v163, v198, v199\n\t"
    "v_cvt_pkrtz_f16_f32 v164, v200, v201\n\t"
    "v_cvt_pkrtz_f16_f32 v165, v202, v203\n\t"
    "v_cvt_pkrtz_f16_f32 v166, v204, v205\n\t"
    "v_cvt_pkrtz_f16_f32 v167, v206, v207\n\t"
    "v_cvt_pkrtz_f16_f32 v168, v208, v209\n\t"
    "v_cvt_pkrtz_f16_f32 v169, v210, v211\n\t"
    "v_cvt_pkrtz_f16_f32 v170, v212, v213\n\t"
    "v_cvt_pkrtz_f16_f32 v171, v214, v215\n\t"
    "v_cvt_pkrtz_f16_f32 v172, v216, v217\n\t"
    "v_cvt_pkrtz_f16_f32 v173, v218, v219\n\t"
    "v_cvt_pkrtz_f16_f32 v174, v220, v221\n\t"
    "v_cvt_pkrtz_f16_f32 v175, v222, v223\n\t"
    "v_mov_b32 v110, 0\n\t"
    "s_waitcnt vmcnt(0)\n\t"           // x(t0) trio arrived
    // ---- main loop: one step per iteration ----
    "0:\n\t"
    "s_waitcnt vmcnt(1)\n\t"           // prev-issued x trio retired (store may fly)
    "v_mov_b32 v104, v107\n\t"
    "v_mov_b32 v105, v108\n\t"
    "v_mov_b32 v106, v109\n\t"
    "ds_read_b128 v[176:179], v100\n\t"
    "ds_read_b128 v[180:183], v100 offset:16\n\t"
    "ds_read_b128 v[184:187], v100 offset:32\n\t"
    "ds_read_b128 v[188:191], v100 offset:48\n\t"
    "s_cmp_gt_u32 %[cnt], 1\n\t"       // skip pointer advance on last step
    "s_cbranch_scc0 3f\n\t"
    "v_add_co_u32 v96, vcc, %[xslo], v96\n\t"
    "v_addc_co_u32 v97, vcc, %[xshi], v97, vcc\n\t"
    "3:\n\t"
    "global_load_dword v107, v[96:97], off\n\t"
    "global_load_dword v108, v[96:97], off offset:512\n\t"
    "global_load_dword v109, v[96:97], off offset:1024\n\t"
    "s_waitcnt lgkmcnt(0)\n\t"
    // dot2 matvec: 48 v_dot2_f32_f16, 2 accs/gate, gates interleaved (ILP)
    "v_mov_b32 v116, 0\n\t"
    "v_mov_b32 v117, 0\n\t"
    "v_mov_b32 v118, 0\n\t"
    "v_mov_b32 v119, 0\n\t"
    "v_mov_b32 v120, 0\n\t"
    "v_mov_b32 v121, 0\n\t"
    "v_dot2_f32_f16 v116, v128, v176, v116\n\t"
    "v_dot2_f32_f16 v118, v144, v176, v118\n\t"
    "v_dot2_f32_f16 v120, v160, v176, v120\n\t"
    "v_dot2_f32_f16 v117, v129, v177, v117\n\t"
    "v_dot2_f32_f16 v119, v145, v177, v119\n\t"
    "v_dot2_f32_f16 v121, v161, v177, v121\n\t"
    "v_dot2_f32_f16 v116, v130, v178, v116\n\t"
    "v_dot2_f32_f16 v118, v146, v178, v118\n\t"
    "v_dot2_f32_f16 v120, v162, v178, v120\n\t"
    "v_dot2_f32_f16 v117, v131, v179, v117\n\t"
    "v_dot2_f32_f16 v119, v147, v179, v119\n\t"
    "v_dot2_f32_f16 v121, v163, v179, v121\n\t"
    "v_dot2_f32_f16 v116, v132, v180, v116\n\t"
    "v_dot2_f32_f16 v118, v148, v180, v118\n\t"
    "v_dot2_f32_f16 v120, v164, v180, v120\n\t"
    "v_dot2_f32_f16 v117, v133, v181, v117\n\t"
    "v_dot2_f32_f16 v119, v149, v181, v119\n\t"
    "v_dot2_f32_f16 v121, v165, v181, v121\n\t"
    "v_dot2_f32_f16 v116, v134, v182, v116\n\t"
    "v_dot2_f32_f16 v118, v150, v182, v118\n\t"
    "v_dot2_f32_f16 v120, v166, v182, v120\n\t"
    "v_dot2_f32_f16 v117, v135, v183, v117\n\t"
    "v_dot2_f32_f16 v119, v151, v183, v119\n\t"
    "v_dot2_f32_f16 v121, v167, v183, v121\n\t"
    "v_dot2_f32_f16 v116, v136, v184, v116\n\t"
    "v_dot2_f32_f16 v118, v152, v184, v118\n\t"
    "v_dot2_f32_f16 v120, v168, v184, v120\n\t"
    "v_dot2_f32_f16 v117, v137, v185, v117\n\t"
    "v_dot2_f32_f16 v119, v153, v185, v119\n\t"
    "v_dot2_f32_f16 v121, v169, v185, v121\n\t"
    "v_dot2_f32_f16 v116, v138, v186, v116\n\t"
    "v_dot2_f32_f16 v118, v154, v186, v118\n\t"
    "v_dot2_f32_f16 v120, v170, v186, v120\n\t"
    "v_dot2_f32_f16 v117, v139, v187, v117\n\t"
    "v_dot2_f32_f16 v119, v155, v187, v119\n\t"
    "v_dot2_f32_f16 v121, v171, v187, v121\n\t"
    "v_dot2_f32_f16 v116, v140, v188, v116\n\t"
    "v_dot2_f32_f16 v118, v156, v188, v118\n\t"
    "v_dot2_f32_f16 v120, v172, v188, v120\n\t"
    "v_dot2_f32_f16 v117, v141, v189, v117\n\t"
    "v_dot2_f32_f16 v119, v157, v189, v119\n\t"
    "v_dot2_f32_f16 v121, v173, v189, v121\n\t"
    "v_dot2_f32_f16 v116, v142, v190, v116\n\t"
    "v_dot2_f32_f16 v118, v158, v190, v118\n\t"
    "v_dot2_f32_f16 v120, v174, v190, v120\n\t"
    "v_dot2_f32_f16 v117, v143, v191, v117\n\t"
    "v_dot2_f32_f16 v119, v159, v191, v119\n\t"
    "v_dot2_f32_f16 v121, v175, v191, v121\n\t"
    // horizontal: r->v116, z->v118, n->v120
    "v_add_f32 v116, v116, v117\n\t"
    "v_add_f32 v118, v118, v119\n\t"
    "v_add_f32 v120, v120, v121\n\t"
    // quad butterfly via fused DPP adds (no LDS pipe, no lgkm wait).
    // s_nop 1 = 2 wait states covers the VALU-write -> DPP-read hazard.
    "s_nop 1\n\t"
    "v_add_f32 v116, v116, v116 quad_perm:[1,0,3,2] row_mask:0xf bank_mask:0xf\n\t"
    "v_add_f32 v118, v118, v118 quad_perm:[1,0,3,2] row_mask:0xf bank_mask:0xf\n\t"
    "v_add_f32 v120, v120, v120 quad_perm:[1,0,3,2] row_mask:0xf bank_mask:0xf\n\t"
    "s_nop 1\n\t"
    "v_add_f32 v116, v116, v116 quad_perm:[2,3,0,1] row_mask:0xf bank_mask:0xf\n\t"
    "v_add_f32 v118, v118, v118 quad_perm:[2,3,0,1] row_mask:0xf bank_mask:0xf\n\t"
    "v_add_f32 v120, v120, v120 quad_perm:[2,3,0,1] row_mask:0xf bank_mask:0xf\n\t"
    "s_nop 1\n\t"
    // ---- gates (v9 hazard-safe interleave; z=v118, n=v120) ----
    "v_add_f32 v111, v104, v116\n\t"
    "v_add_f32 v112, v105, v118\n\t"
    "v_add_f32 v113, v120, %[bn]\n\t"
    "v_add_f32 v111, v111, %[br]\n\t"
    "v_add_f32 v112, v112, %[bz]\n\t"
    "v_mul_f32 v111, 0xbfb8aa3b, v111\n\t"
    "v_mul_f32 v112, 0xbfb8aa3b, v112\n\t"
    "v_exp_f32 v111, v111\n\t"
    "v_exp_f32 v112, v112\n\t"
    "s_nop 0\n\t"
    "v_add_f32 v111, 1.0, v111\n\t"
    "v_add_f32 v112, 1.0, v112\n\t"
    "v_rcp_f32 v111, v111\n\t"
    "v_rcp_f32 v112, v112\n\t"
    "s_nop 0\n\t"
    "v_fmac_f32 v106, v111, v113\n\t"
    "v_mul_f32 v113, 0x4038aa3b, v106\n\t"
    "v_exp_f32 v113, v113\n\t"
    "v_sub_f32 v115, 1.0, v112\n\t"
    "s_nop 0\n\t"
    "v_add_f32 v114, -1.0, v113\n\t"
    "v_add_f32 v113, 1.0, v113\n\t"
    "v_rcp_f32 v113, v113\n\t"
    "s_nop 1\n\t"
    "v_mul_f32 v114, v114, v113\n\t"
    "v_mul_f32 v115, v115, v114\n\t"
    "v_fmac_f32 v115, v112, v110\n\t"
    "v_mov_b32 v110, v115\n\t"
    // store h: f16 -> LDS (next parity), f32 -> hbuf
    "v_cvt_f16_f32 v114, v115\n\t"
    "global_store_dword v[98:99], v115, off\n\t"
    "v_add_co_u32 v98, vcc, %[hslo], v98\n\t"
    "v_addc_co_u32 v99, vcc, %[hshi], v99, vcc\n\t"
    "ds_write_b16 v101, v114\n\t"
    "v_xor_b32 v100, 0x200, v100\n\t"
    "v_xor_b32 v101, 0x200, v101\n\t"
    "s_waitcnt lgkmcnt(0)\n\t"
    "s_barrier\n\t"
    "s_sub_u32 %[cnt], %[cnt], 1\n\t"
    "s_cmp_lg_u32 %[cnt], 0\n\t"
    "s_cbranch_scc1 0b\n\t"
    : [cnt]"+s"(cnt)
    : [wg0]"v"(wg0), [wg1]"v"(wg1), [wg2]"v"(wg2),
      [xlo]"v"(xlo), [xhi]"v"(xhi), [hlo]"v"(hlo), [hhi]"v"(hhi),
      [rd0]"v"(rd0), [wr0]"v"(wr0),
      [br]"v"(br), [bz]"v"(bz), [bn]"v"(bn),
      [xslo]"s"(xslo), [xshi]"v"(xshi), [hslo]"s"(hslo), [hshi]"v"(hshi)
    : "memory", "vcc", "scc",
      "v96","v97","v98","v99","v100","v101","v102","v103","v104","v105",
      "v106","v107","v108","v109","v110","v111","v112","v113","v114","v115",
      "v116","v117","v118","v119","v120","v121","v122","v123","v124","v125",
      "v126","v127","v128","v129","v130","v131","v132","v133","v134","v135",
      "v136","v137","v138","v139","v140","v141","v142","v143","v144","v145",
      "v146","v147","v148","v149","v150","v151","v152","v153","v154","v155",
      "v156","v157","v158","v159","v160","v161","v162","v163","v164","v165",
      "v166","v167","v168","v169","v170","v171","v172","v173","v174","v175",
      "v176","v177","v178","v179","v180","v181","v182","v183","v184","v185",
      "v186","v187","v188","v189","v190","v191","v192","v193","v194","v195",
      "v196","v197","v198","v199","v200","v201","v202","v203","v204","v205",
      "v206","v207","v208","v209","v210","v211","v212","v213","v214","v215",
      "v216","v217","v218","v219","v220","v221","v222","v223");
}

// ---------------- K3: fused emissions + Viterbi + CRF-LLH (v2) --------------
__global__ __launch_bounds__(256, 1) void k_crf_fused(
    const float* __restrict__ hbuf, const float* __restrict__ Wlin,
    const float* __restrict__ blin, const int* __restrict__ labels,
    const float* __restrict__ trans, const float* __restrict__ start,
    const float* __restrict__ endv, float* __restrict__ dec_out,
    float* __restrict__ lossp)
{
  __shared__ float el[T_LEN * 10];
  __shared__ __align__(16) unsigned char bp8[(T_LEN - 1) * 16];
  const int b    = blockIdx.x;
  const int tid  = threadIdx.x;
  const int lane = tid & 63, w = tid >> 6;
  const int sub  = lane >> 4, l16 = lane & 15;

  float4 wreg[NLAB][4];
#pragma unroll
  for (int j = 0; j < NLAB; ++j)
#pragma unroll
    for (int c = 0; c < 4; ++c)
      wreg[j][c] = *reinterpret_cast<const float4*>(Wlin + j * 256 + l16 * 16 + c * 4);

  // ---- phase 1: emissions ----
  for (int k = 0; k < 16; ++k) {
    const int t = w * 64 + k * 4 + sub;
    const float* hp = hbuf + ((size_t)t * BATCH + b) * 256 + l16 * 16;
    const float4 h0 = *reinterpret_cast<const float4*>(hp);
    const float4 h1 = *reinterpret_cast<const float4*>(hp + 4);
    const float4 h2 = *reinterpret_cast<const float4*>(hp + 8);
    const float4 h3 = *reinterpret_cast<const float4*>(hp + 12);
    float acc[NLAB];
#pragma unroll
    for (int j = 0; j < NLAB; ++j) {
      const float4 w0 = wreg[j][0], w1 = wreg[j][1], w2 = wreg[j][2], w3 = wreg[j][3];
      float s0 = h0.x*w0.x + h0.y*w0.y + h0.z*w0.z + h0.w*w0.w;
      float s1 = h1.x*w1.x + h1.y*w1.y + h1.z*w1.z + h1.w*w1.w;
      float s2 = h2.x*w2.x + h2.y*w2.y + h2.z*w2.z + h2.w*w2.w;
      float s3 = h3.x*w3.x + h3.y*w3.y + h3.z*w3.z + h3.w*w3.w;
      acc[j] = (s0 + s1) + (s2 + s3);
    }
#pragma unroll
    for (int j = 0; j < NLAB; ++j) {
#pragma unroll
      for (int off = 1; off < 16; off <<= 1)
        acc[j] += __shfl_xor(acc[j], off);
    }
    if (l16 < NLAB) {
      float v = acc[0];
#pragma unroll
      for (int j = 1; j < NLAB; ++j) v = (l16 == j) ? acc[j] : v;
      el[t * 10 + l16] = v + blin[l16];
    }
  }
  __syncthreads();

  if (w == 0) {
    // ---- Viterbi ----
    float tcol[NLAB];
#pragma unroll
    for (int i = 0; i < NLAB; ++i)
      tcol[i] = (lane < NLAB) ? trans[i * NLAB + lane] : 0.f;
    float alpha = (lane < NLAB) ? (start[lane] + el[lane]) : -3e38f;
    float et_next = (lane < NLAB) ? el[10 + lane] : 0.f;
    for (int s = 0; s < T_LEN - 1; ++s) {
      const float et = et_next;
      if (s < T_LEN - 2)
        et_next = (lane < NLAB) ? el[(s + 2) * 10 + lane] : 0.f;
      float v[NLAB];
      v[0] = BC(alpha, 0) + tcol[0];
      v[1] = BC(alpha, 1) + tcol[1];
      v[2] = BC(alpha, 2) + tcol[2];
      v[3] = BC(alpha, 3) + tcol[3];
      v[4] = BC(alpha, 4) + tcol[4];
      v[5] = BC(alpha, 5) + tcol[5];
      v[6] = BC(alpha, 6) + tcol[6];
      v[7] = BC(alpha, 7) + tcol[7];
      v[8] = BC(alpha, 8) + tcol[8];
      float v01 = (v[0] >= v[1]) ? v[0] : v[1];  int i01 = (v[0] >= v[1]) ? 0 : 1;
      float v23 = (v[2] >= v[3]) ? v[2] : v[3];  int i23 = (v[2] >= v[3]) ? 2 : 3;
      float v45 = (v[4] >= v[5]) ? v[4] : v[5];  int i45 = (v[4] >= v[5]) ? 4 : 5;
      float v67 = (v[6] >= v[7]) ? v[6] : v[7];  int i67 = (v[6] >= v[7]) ? 6 : 7;
      float va = (v01 >= v23) ? v01 : v23;       int ia = (v01 >= v23) ? i01 : i23;
      float vb = (v45 >= v67) ? v45 : v67;       int ib = (v45 >= v67) ? i45 : i67;
      float vc = (va >= vb) ? va : vb;           int ic = (va >= vb) ? ia : ib;
      float best = (vc >= v[8]) ? vc : v[8];     int bi = (vc >= v[8]) ? ic : 8;
      alpha = best + et;
      if (lane < NLAB) bp8[s * 16 + lane] = (unsigned char)bi;
    }
    float fin = alpha + ((lane < NLAB) ? endv[lane] : 0.f);
    float fv[NLAB];
    fv[0] = BC(fin, 0); fv[1] = BC(fin, 1); fv[2] = BC(fin, 2);
    fv[3] = BC(fin, 3); fv[4] = BC(fin, 4); fv[5] = BC(fin, 5);
    fv[6] = BC(fin, 6); fv[7] = BC(fin, 7); fv[8] = BC(fin, 8);
    float f01 = (fv[0] >= fv[1]) ? fv[0] : fv[1];  int j01 = (fv[0] >= fv[1]) ? 0 : 1;
    float f23 = (fv[2] >= fv[3]) ? fv[2] : fv[3];  int j23 = (fv[2] >= fv[3]) ? 2 : 3;
    float f45 = (fv[4] >= fv[5]) ? fv[4] : fv[5];  int j45 = (fv[4] >= fv[5]) ? 4 : 5;
    float f67 = (fv[6] >= fv[7]) ? fv[6] : fv[7];  int j67 = (fv[6] >= fv[7]) ? 6 : 7;
    float fa = (f01 >= f23) ? f01 : f23;           int ja = (f01 >= f23) ? j01 : j23;
    float fb = (f45 >= f67) ? f45 : f67;           int jb = (f45 >= f67) ? j45 : j67;
    float fc = (fa >= fb) ? fa : fb;               int jc = (fa >= fb) ? ja : jb;
    int last = (fc >= fv[8]) ? jc : 8;
    if (lane == 0) {
      int y = last;
      dec_out[b * T_LEN + (T_LEN - 1)] = (float)y;
      uint4 row = *reinterpret_cast<const uint4*>(&bp8[(T_LEN - 2) * 16]);
      for (int s = T_LEN - 2; s >= 0; --s) {
        uint4 nrow = row;
        if (s > 0) nrow = *reinterpret_cast<const uint4*>(&bp8[(s - 1) * 16]);
        unsigned wsel = (y < 4) ? row.x : ((y < 8) ? row.y : row.z);
        y = (int)((wsel >> ((y & 3) * 8)) & 0xffu);
        dec_out[b * T_LEN + s] = (float)y;
        row = nrow;
      }
    }
  } else if (w == 1) {
    // ---- CRF log-likelihood ----
    float tcol[NLAB];
#pragma unroll
    for (int i = 0; i < NLAB; ++i)
      tcol[i] = (lane < NLAB) ? trans[i * NLAB + lane] : 0.f;
    float ca = (lane < NLAB) ? (start[lane] + el[lane]) : -3e38f;
    float et_next = (lane < NLAB) ? el[10 + lane] : 0.f;
    for (int s = 0; s < T_LEN - 1; ++s) {
      const float et = et_next;
      if (s < T_LEN - 2)
        et_next = (lane < NLAB) ? el[(s + 2) * 10 + lane] : 0.f;
      float c[NLAB];
      c[0] = BC(ca, 0) + tcol[0];
      c[1] = BC(ca, 1) + tcol[1];
      c[2] = BC(ca, 2) + tcol[2];
      c[3] = BC(ca, 3) + tcol[3];
      c[4] = BC(ca, 4) + tcol[4];
      c[5] = BC(ca, 5) + tcol[5];
      c[6] = BC(ca, 6) + tcol[6];
      c[7] = BC(ca, 7) + tcol[7];
      c[8] = BC(ca, 8) + tcol[8];
      float m01 = fmaxf(c[0], c[1]), m23 = fmaxf(c[2], c[3]);
      float m45 = fmaxf(c[4], c[5]), m67 = fmaxf(c[6], c[7]);
      float m = fmaxf(fmaxf(fmaxf(m01, m23), fmaxf(m45, m67)), c[8]);
      float p0 = __expf(c[0]-m) + __expf(c[1]-m), p1 = __expf(c[2]-m) + __expf(c[3]-m);
      float p2 = __expf(c[4]-m) + __expf(c[5]-m), p3 = __expf(c[6]-m) + __expf(c[7]-m);
      float p = ((p0 + p1) + (p2 + p3)) + __expf(c[8]-m);
      ca = m + __logf(p) + et;
    }
    float fv[NLAB];
    fv[0] = BC(ca, 0) + endv[0];
    fv[1] = BC(ca, 1) + endv[1];
    fv[2] = BC(ca, 2) + endv[2];
    fv[3] = BC(ca, 3) + endv[3];
    fv[4] = BC(ca, 4) + endv[4];
    fv[5] = BC(ca, 5) + endv[5];
    fv[6] = BC(ca, 6) + endv[6];
    fv[7] = BC(ca, 7) + endv[7];
    fv[8] = BC(ca, 8) + endv[8];
    float mx = -3e38f;
#pragma unroll
    for (int j = 0; j < NLAB; ++j) mx = fmaxf(mx, fv[j]);
    float ps = 0.f;
#pragma unroll
    for (int j = 0; j < NLAB; ++j) ps += __expf(fv[j] - mx);
    float denom = mx + __logf(ps);

    const int* lb = labels + b * T_LEN;
    float part = 0.f;
    for (int t4 = 0; t4 < 4; ++t4) {
      int t = lane * 4 + t4;
      int l = lb[t];
      part += el[t * 10 + l];
      if (t > 0) part += trans[lb[t - 1] * NLAB + l];
    }
#pragma unroll
    for (int off = 32; off > 0; off >>= 1) part += __shfl_xor(part, off);
    if (lane == 0) {
      float num = part + start[lb[0]] + endv[lb[T_LEN - 1]];
      float llh = num - denom;
      atomicAdd(lossp, -llh * (1.0f / BATCH));
    }
  }
}

extern "C" void kernel_launch(void* const* d_in, const int* in_sizes, int n_in,
                              void* d_out, int out_size, void* d_ws, size_t ws_size,
                              hipStream_t stream) {
  const int*   ids    = (const int*)d_in[0];
  const int*   labels = (const int*)d_in[2];
  const float* emb    = (const float*)d_in[3];
  const float* Wihf   = (const float*)d_in[4];
  const float* Whhf   = (const float*)d_in[5];
  const float* bihf   = (const float*)d_in[6];
  const float* bhhf   = (const float*)d_in[7];
  const float* Wihb   = (const float*)d_in[8];
  const float* Whhb   = (const float*)d_in[9];
  const float* bihb   = (const float*)d_in[10];
  const float* bhhb   = (const float*)d_in[11];
  const float* Wlin   = (const float*)d_in[12];
  const float* blin   = (const float*)d_in[13];
  const float* trans  = (const float*)d_in[14];
  const float* start  = (const float*)d_in[15];
  const float* endv   = (const float*)d_in[16];

  float* xp    = (float*)d_ws;                       // [T][B][768]
  float* hbuf  = xp + (size_t)M_TOT * HID;           // [T][B][256]
  float* out   = (float*)d_out;                      // decoded as floats
  float* lossp = out + M_TOT;                        // loss scalar

  k_gemm_xp<<<dim3(6, 64), 256, 0, stream>>>(ids, emb, Wihf, Wihb, bihf, bihb, xp);
  k_gru<<<64, 512, 0, stream>>>(xp, Whhf, Whhb, bhhf, bhhb, hbuf, lossp);
  k_crf_fused<<<BATCH, 256, 0, stream>>>(hbuf, Wlin, blin, labels, trans,
                                         start, endv, out, lossp);
}

// Round 11
// 355.096 us; speedup vs baseline: 1.1401x; 1.0138x over previous
//
#include <hip/hip_runtime.h>
#include <math.h>

#define T_LEN 256
#define BATCH 32
#define HID   768
#define GH    384   // 3*LSTM_H
#define LH    128   // LSTM_H
#define NLAB  9
#define M_TOT (T_LEN*BATCH)  // 8192

typedef float v2f __attribute__((ext_vector_type(2)));
typedef _Float16 h8 __attribute__((ext_vector_type(8)));
typedef float f4 __attribute__((ext_vector_type(4)));

// Immediate-pattern lane broadcast within 32-lane half: every lane reads lane i.
#define BC(x, i) __int_as_float(__builtin_amdgcn_ds_swizzle(__float_as_int(x), (i) << 5))

// Raw barrier with LDS-only drain (no vmcnt stall on in-flight prefetch/stores).
#define BAR_LGKM() do {                                   \
    asm volatile("s_waitcnt lgkmcnt(0)" ::: "memory");    \
    __builtin_amdgcn_s_barrier();                         \
    asm volatile("" ::: "memory");                        \
  } while (0)

// ---------------- K1: xp = emb[ids] @ [Wih_f;Wih_b]^T + bias  (v7 pure f16) -
__global__ __launch_bounds__(256, 2) void k_gemm_xp(
    const int* __restrict__ ids, const float* __restrict__ emb,
    const float* __restrict__ Wf, const float* __restrict__ Wb,
    const float* __restrict__ bihf, const float* __restrict__ bihb,
    float* __restrict__ xp)
{
  __shared__ __align__(16) _Float16 Ah[128*40];
  __shared__ __align__(16) _Float16 Bh[128*40];

  const int tid  = threadIdx.x;
  const int lane = tid & 63, w = tid >> 6;
  const int m0 = blockIdx.y * 128, n0 = blockIdx.x * 128;

  const int srow = tid >> 1, sk = (tid & 1) * 16;
  const int gm = m0 + srow;
  const int tok = ids[(gm & 31) * T_LEN + (gm >> 5)];
  const float* aG = emb + (size_t)tok * HID + sk;
  const int gn = n0 + srow;
  const float* bG = (gn < GH ? Wf + (size_t)gn * HID
                             : Wb + (size_t)(gn - GH) * HID) + sk;

  const int fr = lane & 15, fq = lane >> 4;
  const int mrow = (w & 1) * 64;
  const int ncol = (w >> 1) * 64;

  f4 acc[4][4];
#pragma unroll
  for (int i = 0; i < 4; ++i)
#pragma unroll
    for (int j = 0; j < 4; ++j) acc[i][j] = f4{0,0,0,0};

  const int sb = srow * 40 + sk;

  float4 ra[4], rb[4];
#pragma unroll
  for (int c = 0; c < 4; ++c) {
    ra[c] = *reinterpret_cast<const float4*>(aG + 4 * c);
    rb[c] = *reinterpret_cast<const float4*>(bG + 4 * c);
  }

  for (int kt = 0; kt < HID / 32; ++kt) {
    BAR_LGKM();
#pragma unroll
    for (int m = 0; m < 2; ++m) {
      const float4* src = m ? rb : ra;
      _Float16* dsth = m ? Bh : Ah;
#pragma unroll
      for (int seg = 0; seg < 2; ++seg) {
        float xs[8] = {src[2*seg].x, src[2*seg].y, src[2*seg].z, src[2*seg].w,
                       src[2*seg+1].x, src[2*seg+1].y, src[2*seg+1].z, src[2*seg+1].w};
        h8 hi;
#pragma unroll
        for (int c = 0; c < 8; ++c) hi[c] = (_Float16)xs[c];
        *reinterpret_cast<h8*>(&dsth[sb + seg * 8]) = hi;
      }
    }
    if (kt + 1 < HID / 32) {
      const float* pa = aG + (kt + 1) * 32;
      const float* pb = bG + (kt + 1) * 32;
#pragma unroll
      for (int c = 0; c < 4; ++c) {
        ra[c] = *reinterpret_cast<const float4*>(pa + 4 * c);
        rb[c] = *reinterpret_cast<const float4*>(pb + 4 * c);
      }
    }
    BAR_LGKM();

    h8 fbh[4];
#pragma unroll
    for (int j = 0; j < 4; ++j) {
      const int off = (ncol + j * 16 + fr) * 40 + fq * 8;
      fbh[j] = *reinterpret_cast<const h8*>(&Bh[off]);
    }
#pragma unroll
    for (int i = 0; i < 4; ++i) {
      const int off = (mrow + i * 16 + fr) * 40 + fq * 8;
      h8 fah = *reinterpret_cast<const h8*>(&Ah[off]);
#pragma unroll
      for (int j = 0; j < 4; ++j)
        acc[i][j] = __builtin_amdgcn_mfma_f32_16x16x32_f16(fah, fbh[j], acc[i][j], 0, 0, 0);
    }
  }

  float bcol[4];
#pragma unroll
  for (int j = 0; j < 4; ++j) {
    const int c = n0 + ncol + j * 16 + fr;
    bcol[j] = (c < GH) ? bihf[c] : bihb[c - GH];
  }
#pragma unroll
  for (int i = 0; i < 4; ++i)
#pragma unroll
    for (int j = 0; j < 4; ++j) {
      const int col = n0 + ncol + j * 16 + fr;
#pragma unroll
      for (int r = 0; r < 4; ++r) {
        const int row = m0 + mrow + i * 16 + fq * 4 + r;
        xp[(size_t)row * HID + col] = acc[i][j][r] + bcol[j];
      }
    }
}

// ---------------- K2: bidirectional GRU recurrence (v13 — 4 waves) ----------
// r10 confirmed the chain is latency/sync-bound (DPP-for-swizzle: -147cy/step,
// matching model). Remaining unexplained cost scales with wave count (8 waves
// all serializing on the same barrier + round-robin issue). v13: 256 threads,
// 2 lanes/unit (tid>>1 = unit, tid&1 = half of the h vector):
//   - barrier participants 8 -> 4 waves
//   - reduce: ONE DPP xor1 level (was 2)
//   - per-lane: 96 dot2 (issue ~192cy, still below the latency floor),
//     8x ds_read_b128 (same block-total LDS traffic), 96 packed f16 weight
//     regs in v[128:223] (staged f32 + overlap-safe in-place cvt_pkrtz).
// Gate section, parity XOR 0x200, vmcnt discipline verbatim from v12.
__global__ __attribute__((amdgpu_flat_work_group_size(256, 256),
                          amdgpu_waves_per_eu(1, 1)))
void k_gru(
    const float* __restrict__ xp,
    const float* __restrict__ Whhf, const float* __restrict__ Whhb,
    const float* __restrict__ bhhf, const float* __restrict__ bhhb,
    float* __restrict__ hbuf, float* __restrict__ lossp)
{
  __shared__ __align__(1024) _Float16 hsp[2][256];
  const int tid = threadIdx.x;
  const int g   = tid >> 1;       // hidden unit 0..127
  const int hf  = tid & 1;        // 64-elem half 0..1
  const int bd  = blockIdx.x;
  const int dir = bd >> 5, b = bd & 31;
  const float* Whh = dir ? Whhb : Whhf;
  const float* bhh = dir ? bhhb : bhhf;

  if (bd == 0 && tid == 0) *lossp = 0.f;

  const float br = bhh[g], bz = bhh[g + LH], bn = bhh[g + 2*LH];
  const float* wg0 = Whh + (size_t)(0*LH + g) * LH + hf * 64;
  const float* wg1 = Whh + (size_t)(1*LH + g) * LH + hf * 64;
  const float* wg2 = Whh + (size_t)(2*LH + g) * LH + hf * 64;

  const int t0 = dir ? (T_LEN - 1) : 0;
  const int dt = dir ? -1 : 1;
  const float* px = xp + (size_t)t0 * BATCH * HID + b * HID + dir * GH + g;
  float*       ph = hbuf + (size_t)t0 * BATCH * 256 + b * 256 + dir * LH + g;

  const long long xs = (long long)dt * BATCH * HID * 4;   // xp t-stride, bytes
  const long long hs = (long long)dt * BATCH * 256 * 4;   // hbuf t-stride, bytes
  const unsigned xslo = (unsigned)(xs & 0xffffffffll);
  const int      xshi = (int)(xs >> 32);
  const unsigned hslo = (unsigned)(hs & 0xffffffffll);
  const int      hshi = (int)(hs >> 32);
  const unsigned xlo = (unsigned)(uintptr_t)px, xhi = (unsigned)((uintptr_t)px >> 32);
  const unsigned hlo = (unsigned)(uintptr_t)ph, hhi = (unsigned)((uintptr_t)ph >> 32);
  // generic AS0 shared pointers: low 32 bits = LDS byte offset.
  // read base: buf0 + hf*128B (64 f16 = 8x b128); write: buf1 + g*2B.
  const unsigned rd0 = (unsigned)(uintptr_t)(&hsp[0][hf * 64]);
  const unsigned wr0 = (unsigned)(uintptr_t)(&hsp[1][g]);

  if (tid < 128) reinterpret_cast<unsigned*>(&hsp[0][0])[tid] = 0u;  // zero buf0
  BAR_LGKM();

  int cnt = T_LEN;
  asm volatile(
    // ---- prologue ----
    // stage gate0 f32 -> v[128:191], gate1 f32 -> v[192:255]
    "global_load_dwordx4 v[128:131], %[wg0], off\n\t"
    "global_load_dwordx4 v[132:135], %[wg0], off offset:16\n\t"
    "global_load_dwordx4 v[136:139], %[wg0], off offset:32\n\t"
    "global_load_dwordx4 v[140:143], %[wg0], off offset:48\n\t"
    "global_load_dwordx4 v[144:147], %[wg0], off offset:64\n\t"
    "global_load_dwordx4 v[148:151], %[wg0], off offset:80\n\t"
    "global_load_dwordx4 v[152:155], %[wg0], off offset:96\n\t"
    "global_load_dwordx4 v[156:159], %[wg0], off offset:112\n\t"
    "global_load_dwordx4 v[160:163], %[wg0], off offset:128\n\t"
    "global_load_dwordx4 v[164:167], %[wg0], off offset:144\n\t"
    "global_load_dwordx4 v[168:171], %[wg0], off offset:160\n\t"
    "global_load_dwordx4 v[172:175], %[wg0], off offset:176\n\t"
    "global_load_dwordx4 v[176:179], %[wg0], off offset:192\n\t"
    "global_load_dwordx4 v[180:183], %[wg0], off offset:208\n\t"
    "global_load_dwordx4 v[184:187], %[wg0], off offset:224\n\t"
    "global_load_dwordx4 v[188:191], %[wg0], off offset:240\n\t"
    "global_load_dwordx4 v[192:195], %[wg1], off\n\t"
    "global_load_dwordx4 v[196:199], %[wg1], off offset:16\n\t"
    "global_load_dwordx4 v[200:203], %[wg1], off offset:32\n\t"
    "global_load_dwordx4 v[204:207], %[wg1], off offset:48\n\t"
    "global_load_dwordx4 v[208:211], %[wg1], off offset:64\n\t"
    "global_load_dwordx4 v[212:215], %[wg1], off offset:80\n\t"
    "global_load_dwordx4 v[216:219], %[wg1], off offset:96\n\t"
    "global_load_dwordx4 v[220:223], %[wg1], off offset:112\n\t"
    "global_load_dwordx4 v[224:227], %[wg1], off offset:128\n\t"
    "global_load_dwordx4 v[228:231], %[wg1], off offset:144\n\t"
    "global_load_dwordx4 v[232:235], %[wg1], off offset:160\n\t"
    "global_load_dwordx4 v[236:239], %[wg1], off offset:176\n\t"
    "global_load_dwordx4 v[240:243], %[wg1], off offset:192\n\t"
    "global_load_dwordx4 v[244:247], %[wg1], off offset:208\n\t"
    "global_load_dwordx4 v[248:251], %[wg1], off offset:224\n\t"
    "global_load_dwordx4 v[252:255], %[wg1], off offset:240\n\t"
    "v_mov_b32 v96, %[xlo]\n\t"
    "v_mov_b32 v97, %[xhi]\n\t"
    "v_mov_b32 v98, %[hlo]\n\t"
    "v_mov_b32 v99, %[hhi]\n\t"
    "v_mov_b32 v100, %[rd0]\n\t"
    "v_mov_b32 v101, %[wr0]\n\t"
    "s_waitcnt vmcnt(0)\n\t"
    // convert gate0 in-place forward: v(128+i) = pk(v(128+2i), v(129+2i))
    "v_cvt_pkrtz_f16_f32 v128, v128, v129\n\t"
    "v_cvt_pkrtz_f16_f32 v129, v130, v131\n\t"
    "v_cvt_pkrtz_f16_f32 v130, v132, v133\n\t"
    "v_cvt_pkrtz_f16_f32 v131, v134, v135\n\t"
    "v_cvt_pkrtz_f16_f32 v132, v136, v137\n\t"
    "v_cvt_pkrtz_f16_f32 v133, v138, v139\n\t"
    "v_cvt_pkrtz_f16_f32 v134, v140, v141\n\t"
    "v_cvt_pkrtz_f16_f32 v135, v142, v143\n\t"
    "v_cvt_pkrtz_f16_f32 v136, v144, v145\n\t"
    "v_cvt_pkrtz_f16_f32 v137, v146, v147\n\t"
    "v_cvt_pkrtz_f16_f32 v138, v148, v149\n\t"
    "v_cvt_pkrtz_f16_f32 v139, v150, v151\n\t"
    "v_cvt_pkrtz_f16_f32 v140, v152, v153\n\t"
    "v_cvt_pkrtz_f16_f32 v141, v154, v155\n\t"
    "v_cvt_pkrtz_f16_f32 v142, v156, v157\n\t"
    "v_cvt_pkrtz_f16_f32 v143, v158, v159\n\t"
    "v_cvt_pkrtz_f16_f32 v144, v160, v161\n\t"
    "v_cvt_pkrtz_f16_f32 v145, v162, v163\n\t"
    "v_cvt_pkrtz_f16_f32 v146, v164, v165\n\t"
    "v_cvt_pkrtz_f16_f32 v147, v166, v167\n\t"
    "v_cvt_pkrtz_f16_f32 v148, v168, v169\n\t"
    "v_cvt_pkrtz_f16_f32 v149, v170, v171\n\t"
    "v_cvt_pkrtz_f16_f32 v150, v172, v173\n\t"
    "v_cvt_pkrtz_f16_f32 v151, v174, v175\n\t"
    "v_cvt_pkrtz_f16_f32 v152, v176, v177\n\t"
    "v_cvt_pkrtz_f16_f32 v153, v178, v179\n\t"
    "v_cvt_pkrtz_f16_f32 v154, v180, v181\n\t"
    "v_cvt_pkrtz_f16_f32 v155, v182, v183\n\t"
    "v_cvt_pkrtz_f16_f32 v156, v184, v185\n\t"
    "v_cvt_pkrtz_f16_f32 v157, v186, v187\n\t"
    "v_cvt_pkrtz_f16_f32 v158, v188, v189\n\t"
    "v_cvt_pkrtz_f16_f32 v159, v190, v191\n\t"
    // convert gate1: v(160+i) = pk(v(192+2i), v(193+2i))  (disjoint ranges)
    "v_cvt_pkrtz_f16_f32 v160, v192, v193\n\t"
    "v_cvt_pkrtz_f16_f32 v161, v194, v195\n\t"
    "v_cvt_pkrtz_f16_f32 v162, v196, v197\n\t"
    "v_cvt_pkrtz_f16_f32 v163, v198, v199\n\t"
    "v_cvt_pkrtz_f16_f32 v164, v200, v201\n\t"
    "v_cvt_pkrtz_f16_f32 v165, v202, v203\n\t"
    "v_cvt_pkrtz_f16_f32 v166, v204, v205\n\t"
    "v_cvt_pkrtz_f16_f32 v167, v206, v207\n\t"
    "v_cvt_pkrtz_f16_f32 v168, v208, v209\n\t"
    "v_cvt_pkrtz_f16_f32 v169, v210, v211\n\t"
    "v_cvt_pkrtz_f16_f32 v170, v212, v213\n\t"
    "v_cvt_pkrtz_f16_f32 v171, v214, v215\n\t"
    "v_cvt_pkrtz_f16_f32 v172, v216, v217\n\t"
    "v_cvt_pkrtz_f16_f32 v173, v218, v219\n\t"
    "v_cvt_pkrtz_f16_f32 v174, v220, v221\n\t"
    "v_cvt_pkrtz_f16_f32 v175, v222, v223\n\t"
    "v_cvt_pkrtz_f16_f32 v176, v224, v225\n\t"
    "v_cvt_pkrtz_f16_f32 v177, v226, v227\n\t"
    "v_cvt_pkrtz_f16_f32 v178, v228, v229\n\t"
    "v_cvt_pkrtz_f16_f32 v179, v230, v231\n\t"
    "v_cvt_pkrtz_f16_f32 v180, v232, v233\n\t"
    "v_cvt_pkrtz_f16_f32 v181, v234, v235\n\t"
    "v_cvt_pkrtz_f16_f32 v182, v236, v237\n\t"
    "v_cvt_pkrtz_f16_f32 v183, v238, v239\n\t"
    "v_cvt_pkrtz_f16_f32 v184, v240, v241\n\t"
    "v_cvt_pkrtz_f16_f32 v185, v242, v243\n\t"
    "v_cvt_pkrtz_f16_f32 v186, v244, v245\n\t"
    "v_cvt_pkrtz_f16_f32 v187, v246, v247\n\t"
    "v_cvt_pkrtz_f16_f32 v188, v248, v249\n\t"
    "v_cvt_pkrtz_f16_f32 v189, v250, v251\n\t"
    "v_cvt_pkrtz_f16_f32 v190, v252, v253\n\t"
    "v_cvt_pkrtz_f16_f32 v191, v254, v255\n\t"
    // stage gate2 f32 -> v[192:255]; prime x(t0) -> v[107:109]
    "global_load_dwordx4 v[192:195], %[wg2], off\n\t"
    "global_load_dwordx4 v[196:199], %[wg2], off offset:16\n\t"
    "global_load_dwordx4 v[200:203], %[wg2], off offset:32\n\t"
    "global_load_dwordx4 v[204:207], %[wg2], off offset:48\n\t"
    "global_load_dwordx4 v[208:211], %[wg2], off offset:64\n\t"
    "global_load_dwordx4 v[212:215], %[wg2], off offset:80\n\t"
    "global_load_dwordx4 v[216:219], %[wg2], off offset:96\n\t"
    "global_load_dwordx4 v[220:223], %[wg2], off offset:112\n\t"
    "global_load_dwordx4 v[224:227], %[wg2], off offset:128\n\t"
    "global_load_dwordx4 v[228:231], %[wg2], off offset:144\n\t"
    "global_load_dwordx4 v[232:235], %[wg2], off offset:160\n\t"
    "global_load_dwordx4 v[236:239], %[wg2], off offset:176\n\t"
    "global_load_dwordx4 v[240:243], %[wg2], off offset:192\n\t"
    "global_load_dwordx4 v[244:247], %[wg2], off offset:208\n\t"
    "global_load_dwordx4 v[248:251], %[wg2], off offset:224\n\t"
    "global_load_dwordx4 v[252:255], %[wg2], off offset:240\n\t"
    "global_load_dword v107, v[96:97], off\n\t"
    "global_load_dword v108, v[96:97], off offset:512\n\t"
    "global_load_dword v109, v[96:97], off offset:1024\n\t"
    "s_waitcnt vmcnt(3)\n\t"           // gate2 staging retired; x may fly
    // convert gate2 in-place forward: v(192+i) = pk(v(192+2i), v(193+2i))
    "v_cvt_pkrtz_f16_f32 v192, v192, v193\n\t"
    "v_cvt_pkrtz_f16_f32 v193, v194, v195\n\t"
    "v_cvt_pkrtz_f16_f32 v194, v196, v197\n\t"
    "v_cvt_pkrtz_f16_f32 v195, v198, v199\n\t"
    "v_cvt_pkrtz_f16_f32 v196, v200, v201\n\t"
    "v_cvt_pkrtz_f16_f32 v197, v202, v203\n\t"
    "v_cvt_pkrtz_f16_f32 v198, v204, v205\n\t"
    "v_cvt_pkrtz_f16_f32 v199, v206, v207\n\t"
    "v_cvt_pkrtz_f16_f32 v200, v208, v209\n\t"
    "v_cvt_pkrtz_f16_f32 v201, v210, v211\n\t"
    "v_cvt_pkrtz_f16_f32 v202, v212, v213\n\t"
    "v_cvt_pkrtz_f16_f32 v203, v214, v215\n\t"
    "v_cvt_pkrtz_f16_f32 v204, v216, v217\n\t"
    "v_cvt_pkrtz_f16_f32 v205, v218, v219\n\t"
    "v_cvt_pkrtz_f16_f32 v206, v220, v221\n\t"
    "v_cvt_pkrtz_f16_f32 v207, v222, v223\n\t"
    "v_cvt_pkrtz_f16_f32 v208, v224, v225\n\t"
    "v_cvt_pkrtz_f16_f32 v209, v226, v227\n\t"
    "v_cvt_pkrtz_f16_f32 v210, v228, v229\n\t"
    "v_cvt_pkrtz_f16_f32 v211, v230, v231\n\t"
    "v_cvt_pkrtz_f16_f32 v212, v232, v233\n\t"
    "v_cvt_pkrtz_f16_f32 v213, v234, v235\n\t"
    "v_cvt_pkrtz_f16_f32 v214, v236, v237\n\t"
    "v_cvt_pkrtz_f16_f32 v215, v238, v239\n\t"
    "v_cvt_pkrtz_f16_f32 v216, v240, v241\n\t"
    "v_cvt_pkrtz_f16_f32 v217, v242, v243\n\t"
    "v_cvt_pkrtz_f16_f32 v218, v244, v245\n\t"
    "v_cvt_pkrtz_f16_f32 v219, v246, v247\n\t"
    "v_cvt_pkrtz_f16_f32 v220, v248, v249\n\t"
    "v_cvt_pkrtz_f16_f32 v221, v250, v251\n\t"
    "v_cvt_pkrtz_f16_f32 v222, v252, v253\n\t"
    "v_cvt_pkrtz_f16_f32 v223, v254, v255\n\t"
    "v_mov_b32 v110, 0\n\t"
    "s_waitcnt vmcnt(0)\n\t"           // x(t0) trio arrived
    // ---- main loop: one step per iteration ----
    "0:\n\t"
    "s_waitcnt vmcnt(1)\n\t"           // prev-issued x trio retired (store may fly)
    "v_mov_b32 v104, v107\n\t"
    "v_mov_b32 v105, v108\n\t"
    "v_mov_b32 v106, v109\n\t"
    "ds_read_b128 v[224:227], v100\n\t"
    "ds_read_b128 v[228:231], v100 offset:16\n\t"
    "ds_read_b128 v[232:235], v100 offset:32\n\t"
    "ds_read_b128 v[236:239], v100 offset:48\n\t"
    "ds_read_b128 v[240:243], v100 offset:64\n\t"
    "ds_read_b128 v[244:247], v100 offset:80\n\t"
    "ds_read_b128 v[248:251], v100 offset:96\n\t"
    "ds_read_b128 v[252:255], v100 offset:112\n\t"
    "s_cmp_gt_u32 %[cnt], 1\n\t"       // skip pointer advance on last step
    "s_cbranch_scc0 3f\n\t"
    "v_add_co_u32 v96, vcc, %[xslo], v96\n\t"
    "v_addc_co_u32 v97, vcc, %[xshi], v97, vcc\n\t"
    "3:\n\t"
    "global_load_dword v107, v[96:97], off\n\t"
    "global_load_dword v108, v[96:97], off offset:512\n\t"
    "global_load_dword v109, v[96:97], off offset:1024\n\t"
    "s_waitcnt lgkmcnt(0)\n\t"
    // 96 dot2, 6 accs, gates interleaved (r z n per k)
    "v_mov_b32 v116, 0\n\t"
    "v_mov_b32 v117, 0\n\t"
    "v_mov_b32 v118, 0\n\t"
    "v_mov_b32 v119, 0\n\t"
    "v_mov_b32 v120, 0\n\t"
    "v_mov_b32 v121, 0\n\t"
    "v_dot2_f32_f16 v116, v128, v224, v116\n\t"
    "v_dot2_f32_f16 v118, v160, v224, v118\n\t"
    "v_dot2_f32_f16 v120, v192, v224, v120\n\t"
    "v_dot2_f32_f16 v117, v129, v225, v117\n\t"
    "v_dot2_f32_f16 v119, v161, v225, v119\n\t"
    "v_dot2_f32_f16 v121, v193, v225, v121\n\t"
    "v_dot2_f32_f16 v116, v130, v226, v116\n\t"
    "v_dot2_f32_f16 v118, v162, v226, v118\n\t"
    "v_dot2_f32_f16 v120, v194, v226, v120\n\t"
    "v_dot2_f32_f16 v117, v131, v227, v117\n\t"
    "v_dot2_f32_f16 v119, v163, v227, v119\n\t"
    "v_dot2_f32_f16 v121, v195, v227, v121\n\t"
    "v_dot2_f32_f16 v116, v132, v228, v116\n\t"
    "v_dot2_f32_f16 v118, v164, v228, v118\n\t"
    "v_dot2_f32_f16 v120, v196, v228, v120\n\t"
    "v_dot2_f32_f16 v117, v133, v229, v117\n\t"
    "v_dot2_f32_f16 v119, v165, v229, v119\n\t"
    "v_dot2_f32_f16 v121, v197, v229, v121\n\t"
    "v_dot2_f32_f16 v116, v134, v230, v116\n\t"
    "v_dot2_f32_f16 v118, v166, v230, v118\n\t"
    "v_dot2_f32_f16 v120, v198, v230, v120\n\t"
    "v_dot2_f32_f16 v117, v135, v231, v117\n\t"
    "v_dot2_f32_f16 v119, v167, v231, v119\n\t"
    "v_dot2_f32_f16 v121, v199, v231, v121\n\t"
    "v_dot2_f32_f16 v116, v136, v232, v116\n\t"
    "v_dot2_f32_f16 v118, v168, v232, v118\n\t"
    "v_dot2_f32_f16 v120, v200, v232, v120\n\t"
    "v_dot2_f32_f16 v117, v137, v233, v117\n\t"
    "v_dot2_f32_f16 v119, v169, v233, v119\n\t"
    "v_dot2_f32_f16 v121, v201, v233, v121\n\t"
    "v_dot2_f32_f16 v116, v138, v234, v116\n\t"
    "v_dot2_f32_f16 v118, v170, v234, v118\n\t"
    "v_dot2_f32_f16 v120, v202, v234, v120\n\t"
    "v_dot2_f32_f16 v117, v139, v235, v117\n\t"
    "v_dot2_f32_f16 v119, v171, v235, v119\n\t"
    "v_dot2_f32_f16 v121, v203, v235, v121\n\t"
    "v_dot2_f32_f16 v116, v140, v236, v116\n\t"
    "v_dot2_f32_f16 v118, v172, v236, v118\n\t"
    "v_dot2_f32_f16 v120, v204, v236, v120\n\t"
    "v_dot2_f32_f16 v117, v141, v237, v117\n\t"
    "v_dot2_f32_f16 v119, v173, v237, v119\n\t"
    "v_dot2_f32_f16 v121, v205, v237, v121\n\t"
    "v_dot2_f32_f16 v116, v142, v238, v116\n\t"
    "v_dot2_f32_f16 v118, v174, v238, v118\n\t"
    "v_dot2_f32_f16 v120, v206, v238, v120\n\t"
    "v_dot2_f32_f16 v117, v143, v239, v117\n\t"
    "v_dot2_f32_f16 v119, v175, v239, v119\n\t"
    "v_dot2_f32_f16 v121, v207, v239, v121\n\t"
    "v_dot2_f32_f16 v116, v144, v240, v116\n\t"
    "v_dot2_f32_f16 v118, v176, v240, v118\n\t"
    "v_dot2_f32_f16 v120, v208, v240, v120\n\t"
    "v_dot2_f32_f16 v117, v145, v241, v117\n\t"
    "v_dot2_f32_f16 v119, v177, v241, v119\n\t"
    "v_dot2_f32_f16 v121, v209, v241, v121\n\t"
    "v_dot2_f32_f16 v116, v146, v242, v116\n\t"
    "v_dot2_f32_f16 v118, v178, v242, v118\n\t"
    "v_dot2_f32_f16 v120, v210, v242, v120\n\t"
    "v_dot2_f32_f16 v117, v147, v243, v117\n\t"
    "v_dot2_f32_f16 v119, v179, v243, v119\n\t"
    "v_dot2_f32_f16 v121, v211, v243, v121\n\t"
    "v_dot2_f32_f16 v116, v148, v244, v116\n\t"
    "v_dot2_f32_f16 v118, v180, v244, v118\n\t"
    "v_dot2_f32_f16 v120, v212, v244, v120\n\t"
    "v_dot2_f32_f16 v117, v149, v245, v117\n\t"
    "v_dot2_f32_f16 v119, v181, v245, v119\n\t"
    "v_dot2_f32_f16 v121, v213, v245, v121\n\t"
    "v_dot2_f32_f16 v116, v150, v246, v116\n\t"
    "v_dot2_f32_f16 v118, v182, v246, v118\n\t"
    "v_dot2_f32_f16 v120, v214, v246, v120\n\t"
    "v_dot2_f32_f16 v117, v151, v247, v117\n\t"
    "v_dot2_f32_f16 v119, v183, v247, v119\n\t"
    "v_dot2_f32_f16 v121, v215, v247, v121\n\t"
    "v_dot2_f32_f16 v116, v152, v248, v116\n\t"
    "v_dot2_f32_f16 v118, v184, v248, v118\n\t"
    "v_dot2_f32_f16 v120, v216, v248, v120\n\t"
    "v_dot2_f32_f16 v117, v153, v249, v117\n\t"
    "v_dot2_f32_f16 v119, v185, v249, v119\n\t"
    "v_dot2_f32_f16 v121, v217, v249, v121\n\t"
    "v_dot2_f32_f16 v116, v154, v250, v116\n\t"
    "v_dot2_f32_f16 v118, v186, v250, v118\n\t"
    "v_dot2_f32_f16 v120, v218, v250, v120\n\t"
    "v_dot2_f32_f16 v117, v155, v251, v117\n\t"
    "v_dot2_f32_f16 v119, v187, v251, v119\n\t"
    "v_dot2_f32_f16 v121, v219, v251, v121\n\t"
    "v_dot2_f32_f16 v116, v156, v252, v116\n\t"
    "v_dot2_f32_f16 v118, v188, v252, v118\n\t"
    "v_dot2_f32_f16 v120, v220, v252, v120\n\t"
    "v_dot2_f32_f16 v117, v157, v253, v117\n\t"
    "v_dot2_f32_f16 v119, v189, v253, v119\n\t"
    "v_dot2_f32_f16 v121, v221, v253, v121\n\t"
    "v_dot2_f32_f16 v116, v158, v254, v116\n\t"
    "v_dot2_f32_f16 v118, v190, v254, v118\n\t"
    "v_dot2_f32_f16 v120, v222, v254, v120\n\t"
    "v_dot2_f32_f16 v117, v159, v255, v117\n\t"
    "v_dot2_f32_f16 v119, v191, v255, v119\n\t"
    "v_dot2_f32_f16 v121, v223, v255, v121\n\t"
    // horizontal: r->v116, z->v118, n->v120
    "v_add_f32 v116, v116, v117\n\t"
    "v_add_f32 v118, v118, v119\n\t"
    "v_add_f32 v120, v120, v121\n\t"
    // ONE DPP xor1 level (2 lanes per unit). s_nop 1 covers the DPP hazard.
    "s_nop 1\n\t"
    "v_add_f32 v116, v116, v116 quad_perm:[1,0,3,2] row_mask:0xf bank_mask:0xf\n\t"
    "v_add_f32 v118, v118, v118 quad_perm:[1,0,3,2] row_mask:0xf bank_mask:0xf\n\t"
    "v_add_f32 v120, v120, v120 quad_perm:[1,0,3,2] row_mask:0xf bank_mask:0xf\n\t"
    "s_nop 1\n\t"
    // ---- gates (v12-verbatim hazard-safe interleave; z=v118, n=v120) ----
    "v_add_f32 v111, v104, v116\n\t"
    "v_add_f32 v112, v105, v118\n\t"
    "v_add_f32 v113, v120, %[bn]\n\t"
    "v_add_f32 v111, v111, %[br]\n\t"
    "v_add_f32 v112, v112, %[bz]\n\t"
    "v_mul_f32 v111, 0xbfb8aa3b, v111\n\t"
    "v_mul_f32 v112, 0xbfb8aa3b, v112\n\t"
    "v_exp_f32 v111, v111\n\t"
    "v_exp_f32 v112, v112\n\t"
    "s_nop 0\n\t"
    "v_add_f32 v111, 1.0, v111\n\t"
    "v_add_f32 v112, 1.0, v112\n\t"
    "v_rcp_f32 v111, v111\n\t"
    "v_rcp_f32 v112, v112\n\t"
    "s_nop 0\n\t"
    "v_fmac_f32 v106, v111, v113\n\t"
    "v_mul_f32 v113, 0x4038aa3b, v106\n\t"
    "v_exp_f32 v113, v113\n\t"
    "v_sub_f32 v115, 1.0, v112\n\t"
    "s_nop 0\n\t"
    "v_add_f32 v114, -1.0, v113\n\t"
    "v_add_f32 v113, 1.0, v113\n\t"
    "v_rcp_f32 v113, v113\n\t"
    "s_nop 1\n\t"
    "v_mul_f32 v114, v114, v113\n\t"
    "v_mul_f32 v115, v115, v114\n\t"
    "v_fmac_f32 v115, v112, v110\n\t"
    "v_mov_b32 v110, v115\n\t"
    // store h: f16 -> LDS (next parity), f32 -> hbuf
    "v_cvt_f16_f32 v114, v115\n\t"
    "global_store_dword v[98:99], v115, off\n\t"
    "v_add_co_u32 v98, vcc, %[hslo], v98\n\t"
    "v_addc_co_u32 v99, vcc, %[hshi], v99, vcc\n\t"
    "ds_write_b16 v101, v114\n\t"
    "v_xor_b32 v100, 0x200, v100\n\t"
    "v_xor_b32 v101, 0x200, v101\n\t"
    "s_waitcnt lgkmcnt(0)\n\t"
    "s_barrier\n\t"
    "s_sub_u32 %[cnt], %[cnt], 1\n\t"
    "s_cmp_lg_u32 %[cnt], 0\n\t"
    "s_cbranch_scc1 0b\n\t"
    : [cnt]"+s"(cnt)
    : [wg0]"v"(wg0), [wg1]"v"(wg1), [wg2]"v"(wg2),
      [xlo]"v"(xlo), [xhi]"v"(xhi), [hlo]"v"(hlo), [hhi]"v"(hhi),
      [rd0]"v"(rd0), [wr0]"v"(wr0),
      [br]"v"(br), [bz]"v"(bz), [bn]"v"(bn),
      [xslo]"s"(xslo), [xshi]"v"(xshi), [hslo]"s"(hslo), [hshi]"v"(hshi)
    : "memory", "vcc", "scc",
      "v96","v97","v98","v99","v100","v101","v102","v103","v104","v105",
      "v106","v107","v108","v109","v110","v111","v112","v113","v114","v115",
      "v116","v117","v118","v119","v120","v121","v122","v123","v124","v125",
      "v126","v127","v128","v129","v130","v131","v132","v133","v134","v135",
      "v136","v137","v138","v139","v140","v141","v142","v143","v144","v145",
      "v146","v147","v148","v149","v150","v151","v152","v153","v154","v155",
      "v156","v157","v158","v159","v160","v161","v162","v163","v164","v165",
      "v166","v167","v168","v169","v170","v171","v172","v173","v174","v175",
      "v176","v177","v178","v179","v180","v181","v182","v183","v184","v185",
      "v186","v187","v188","v189","v190","v191","v192","v193","v194","v195",
      "v196","v197","v198","v199","v200","v201","v202","v203","v204","v205",
      "v206","v207","v208","v209","v210","v211","v212","v213","v214","v215",
      "v216","v217","v218","v219","v220","v221","v222","v223","v224","v225",
      "v226","v227","v228","v229","v230","v231","v232","v233","v234","v235",
      "v236","v237","v238","v239","v240","v241","v242","v243","v244","v245",
      "v246","v247","v248","v249","v250","v251","v252","v253","v254","v255");
}

// ---------------- K3: fused emissions + Viterbi + CRF-LLH (v2) --------------
__global__ __launch_bounds__(256, 1) void k_crf_fused(
    const float* __restrict__ hbuf, const float* __restrict__ Wlin,
    const float* __restrict__ blin, const int* __restrict__ labels,
    const float* __restrict__ trans, const float* __restrict__ start,
    const float* __restrict__ endv, float* __restrict__ dec_out,
    float* __restrict__ lossp)
{
  __shared__ float el[T_LEN * 10];
  __shared__ __align__(16) unsigned char bp8[(T_LEN - 1) * 16];
  const int b    = blockIdx.x;
  const int tid  = threadIdx.x;
  const int lane = tid & 63, w = tid >> 6;
  const int sub  = lane >> 4, l16 = lane & 15;

  float4 wreg[NLAB][4];
#pragma unroll
  for (int j = 0; j < NLAB; ++j)
#pragma unroll
    for (int c = 0; c < 4; ++c)
      wreg[j][c] = *reinterpret_cast<const float4*>(Wlin + j * 256 + l16 * 16 + c * 4);

  // ---- phase 1: emissions ----
  for (int k = 0; k < 16; ++k) {
    const int t = w * 64 + k * 4 + sub;
    const float* hp = hbuf + ((size_t)t * BATCH + b) * 256 + l16 * 16;
    const float4 h0 = *reinterpret_cast<const float4*>(hp);
    const float4 h1 = *reinterpret_cast<const float4*>(hp + 4);
    const float4 h2 = *reinterpret_cast<const float4*>(hp + 8);
    const float4 h3 = *reinterpret_cast<const float4*>(hp + 12);
    float acc[NLAB];
#pragma unroll
    for (int j = 0; j < NLAB; ++j) {
      const float4 w0 = wreg[j][0], w1 = wreg[j][1], w2 = wreg[j][2], w3 = wreg[j][3];
      float s0 = h0.x*w0.x + h0.y*w0.y + h0.z*w0.z + h0.w*w0.w;
      float s1 = h1.x*w1.x + h1.y*w1.y + h1.z*w1.z + h1.w*w1.w;
      float s2 = h2.x*w2.x + h2.y*w2.y + h2.z*w2.z + h2.w*w2.w;
      float s3 = h3.x*w3.x + h3.y*w3.y + h3.z*w3.z + h3.w*w3.w;
      acc[j] = (s0 + s1) + (s2 + s3);
    }
#pragma unroll
    for (int j = 0; j < NLAB; ++j) {
#pragma unroll
      for (int off = 1; off < 16; off <<= 1)
        acc[j] += __shfl_xor(acc[j], off);
    }
    if (l16 < NLAB) {
      float v = acc[0];
#pragma unroll
      for (int j = 1; j < NLAB; ++j) v = (l16 == j) ? acc[j] : v;
      el[t * 10 + l16] = v + blin[l16];
    }
  }
  __syncthreads();

  if (w == 0) {
    // ---- Viterbi ----
    float tcol[NLAB];
#pragma unroll
    for (int i = 0; i < NLAB; ++i)
      tcol[i] = (lane < NLAB) ? trans[i * NLAB + lane] : 0.f;
    float alpha = (lane < NLAB) ? (start[lane] + el[lane]) : -3e38f;
    float et_next = (lane < NLAB) ? el[10 + lane] : 0.f;
    for (int s = 0; s < T_LEN - 1; ++s) {
      const float et = et_next;
      if (s < T_LEN - 2)
        et_next = (lane < NLAB) ? el[(s + 2) * 10 + lane] : 0.f;
      float v[NLAB];
      v[0] = BC(alpha, 0) + tcol[0];
      v[1] = BC(alpha, 1) + tcol[1];
      v[2] = BC(alpha, 2) + tcol[2];
      v[3] = BC(alpha, 3) + tcol[3];
      v[4] = BC(alpha, 4) + tcol[4];
      v[5] = BC(alpha, 5) + tcol[5];
      v[6] = BC(alpha, 6) + tcol[6];
      v[7] = BC(alpha, 7) + tcol[7];
      v[8] = BC(alpha, 8) + tcol[8];
      float v01 = (v[0] >= v[1]) ? v[0] : v[1];  int i01 = (v[0] >= v[1]) ? 0 : 1;
      float v23 = (v[2] >= v[3]) ? v[2] : v[3];  int i23 = (v[2] >= v[3]) ? 2 : 3;
      float v45 = (v[4] >= v[5]) ? v[4] : v[5];  int i45 = (v[4] >= v[5]) ? 4 : 5;
      float v67 = (v[6] >= v[7]) ? v[6] : v[7];  int i67 = (v[6] >= v[7]) ? 6 : 7;
      float va = (v01 >= v23) ? v01 : v23;       int ia = (v01 >= v23) ? i01 : i23;
      float vb = (v45 >= v67) ? v45 : v67;       int ib = (v45 >= v67) ? i45 : i67;
      float vc = (va >= vb) ? va : vb;           int ic = (va >= vb) ? ia : ib;
      float best = (vc >= v[8]) ? vc : v[8];     int bi = (vc >= v[8]) ? ic : 8;
      alpha = best + et;
      if (lane < NLAB) bp8[s * 16 + lane] = (unsigned char)bi;
    }
    float fin = alpha + ((lane < NLAB) ? endv[lane] : 0.f);
    float fv[NLAB];
    fv[0] = BC(fin, 0); fv[1] = BC(fin, 1); fv[2] = BC(fin, 2);
    fv[3] = BC(fin, 3); fv[4] = BC(fin, 4); fv[5] = BC(fin, 5);
    fv[6] = BC(fin, 6); fv[7] = BC(fin, 7); fv[8] = BC(fin, 8);
    float f01 = (fv[0] >= fv[1]) ? fv[0] : fv[1];  int j01 = (fv[0] >= fv[1]) ? 0 : 1;
    float f23 = (fv[2] >= fv[3]) ? fv[2] : fv[3];  int j23 = (fv[2] >= fv[3]) ? 2 : 3;
    float f45 = (fv[4] >= fv[5]) ? fv[4] : fv[5];  int j45 = (fv[4] >= fv[5]) ? 4 : 5;
    float f67 = (fv[6] >= fv[7]) ? fv[6] : fv[7];  int j67 = (fv[6] >= fv[7]) ? 6 : 7;
    float fa = (f01 >= f23) ? f01 : f23;           int ja = (f01 >= f23) ? j01 : j23;
    float fb = (f45 >= f67) ? f45 : f67;           int jb = (f45 >= f67) ? j45 : j67;
    float fc = (fa >= fb) ? fa : fb;               int jc = (fa >= fb) ? ja : jb;
    int last = (fc >= fv[8]) ? jc : 8;
    if (lane == 0) {
      int y = last;
      dec_out[b * T_LEN + (T_LEN - 1)] = (float)y;
      uint4 row = *reinterpret_cast<const uint4*>(&bp8[(T_LEN - 2) * 16]);
      for (int s = T_LEN - 2; s >= 0; --s) {
        uint4 nrow = row;
        if (s > 0) nrow = *reinterpret_cast<const uint4*>(&bp8[(s - 1) * 16]);
        unsigned wsel = (y < 4) ? row.x : ((y < 8) ? row.y : row.z);
        y = (int)((wsel >> ((y & 3) * 8)) & 0xffu);
        dec_out[b * T_LEN + s] = (float)y;
        row = nrow;
      }
    }
  } else if (w == 1) {
    // ---- CRF log-likelihood ----
    float tcol[NLAB];
#pragma unroll
    for (int i = 0; i < NLAB; ++i)
      tcol[i] = (lane < NLAB) ? trans[i * NLAB + lane] : 0.f;
    float ca = (lane < NLAB) ? (start[lane] + el[lane]) : -3e38f;
    float et_next = (lane < NLAB) ? el[10 + lane] : 0.f;
    for (int s = 0; s < T_LEN - 1; ++s) {
      const float et = et_next;
      if (s < T_LEN - 2)
        et_next = (lane < NLAB) ? el[(s + 2) * 10 + lane] : 0.f;
      float c[NLAB];
      c[0] = BC(ca, 0) + tcol[0];
      c[1] = BC(ca, 1) + tcol[1];
      c[2] = BC(ca, 2) + tcol[2];
      c[3] = BC(ca, 3) + tcol[3];
      c[4] = BC(ca, 4) + tcol[4];
      c[5] = BC(ca, 5) + tcol[5];
      c[6] = BC(ca, 6) + tcol[6];
      c[7] = BC(ca, 7) + tcol[7];
      c[8] = BC(ca, 8) + tcol[8];
      float m01 = fmaxf(c[0], c[1]), m23 = fmaxf(c[2], c[3]);
      float m45 = fmaxf(c[4], c[5]), m67 = fmaxf(c[6], c[7]);
      float m = fmaxf(fmaxf(fmaxf(m01, m23), fmaxf(m45, m67)), c[8]);
      float p0 = __expf(c[0]-m) + __expf(c[1]-m), p1 = __expf(c[2]-m) + __expf(c[3]-m);
      float p2 = __expf(c[4]-m) + __expf(c[5]-m), p3 = __expf(c[6]-m) + __expf(c[7]-m);
      float p = ((p0 + p1) + (p2 + p3)) + __expf(c[8]-m);
      ca = m + __logf(p) + et;
    }
    float fv[NLAB];
    fv[0] = BC(ca, 0) + endv[0];
    fv[1] = BC(ca, 1) + endv[1];
    fv[2] = BC(ca, 2) + endv[2];
    fv[3] = BC(ca, 3) + endv[3];
    fv[4] = BC(ca, 4) + endv[4];
    fv[5] = BC(ca, 5) + endv[5];
    fv[6] = BC(ca, 6) + endv[6];
    fv[7] = BC(ca, 7) + endv[7];
    fv[8] = BC(ca, 8) + endv[8];
    float mx = -3e38f;
#pragma unroll
    for (int j = 0; j < NLAB; ++j) mx = fmaxf(mx, fv[j]);
    float ps = 0.f;
#pragma unroll
    for (int j = 0; j < NLAB; ++j) ps += __expf(fv[j] - mx);
    float denom = mx + __logf(ps);

    const int* lb = labels + b * T_LEN;
    float part = 0.f;
    for (int t4 = 0; t4 < 4; ++t4) {
      int t = lane * 4 + t4;
      int l = lb[t];
      part += el[t * 10 + l];
      if (t > 0) part += trans[lb[t - 1] * NLAB + l];
    }
#pragma unroll
    for (int off = 32; off > 0; off >>= 1) part += __shfl_xor(part, off);
    if (lane == 0) {
      float num = part + start[lb[0]] + endv[lb[T_LEN - 1]];
      float llh = num - denom;
      atomicAdd(lossp, -llh * (1.0f / BATCH));
    }
  }
}

extern "C" void kernel_launch(void* const* d_in, const int* in_sizes, int n_in,
                              void* d_out, int out_size, void* d_ws, size_t ws_size,
                              hipStream_t stream) {
  const int*   ids    = (const int*)d_in[0];
  const int*   labels = (const int*)d_in[2];
  const float* emb    = (const float*)d_in[3];
  const float* Wihf   = (const float*)d_in[4];
  const float* Whhf   = (const float*)d_in[5];
  const float* bihf   = (const float*)d_in[6];
  const float* bhhf   = (const float*)d_in[7];
  const float* Wihb   = (const float*)d_in[8];
  const float* Whhb   = (const float*)d_in[9];
  const float* bihb   = (const float*)d_in[10];
  const float* bhhb   = (const float*)d_in[11];
  const float* Wlin   = (const float*)d_in[12];
  const float* blin   = (const float*)d_in[13];
  const float* trans  = (const float*)d_in[14];
  const float* start  = (const float*)d_in[15];
  const float* endv   = (const float*)d_in[16];

  float* xp    = (float*)d_ws;                       // [T][B][768]
  float* hbuf  = xp + (size_t)M_TOT * HID;           // [T][B][256]
  float* out   = (float*)d_out;                      // decoded as floats
  float* lossp = out + M_TOT;                        // loss scalar

  k_gemm_xp<<<dim3(6, 64), 256, 0, stream>>>(ids, emb, Wihf, Wihb, bihf, bihb, xp);
  k_gru<<<64, 256, 0, stream>>>(xp, Whhf, Whhb, bhhf, bhhb, hbuf, lossp);
  k_crf_fused<<<BATCH, 256, 0, stream>>>(hbuf, Wlin, blin, labels, trans,
                                         start, endv, out, lossp);
}